// Round 1
// baseline (4018.946 us; speedup 1.0000x reference)
//
#include <hip/hip_runtime.h>
#include <math.h>

#define NB 32
#define NL 1024
#define NG 3
#define ND 384
#define NH 96
#define NDG 192
#define SEQR 3073   // 1 + NG*NL

// ---------------------------------------------------------------- helpers
__device__ __forceinline__ float blockSum192(float v, volatile float* red) {
#pragma unroll
  for (int off = 32; off > 0; off >>= 1) v += __shfl_xor(v, off, 64);
  int wid = threadIdx.x >> 6;
  __syncthreads();                       // protect red reuse from prior call
  if ((threadIdx.x & 63) == 0) red[wid] = v;
  __syncthreads();
  return red[0] + red[1] + red[2];
}

// ---------------------------------------------------------------- prep
// Wt[(kh*384 + i)*384 + o] = convW[(o*384 + i)*3 + kh]; twiddles; cls copy
__global__ __launch_bounds__(256) void k_prep(const float* __restrict__ convW,
                                              const float* __restrict__ x,
                                              float* __restrict__ Wt,
                                              float* __restrict__ twid,
                                              float* __restrict__ outp) {
  int id = blockIdx.x * 256 + threadIdx.x;
  if (id < 384 * 384 * 3) {
    int o = id % 384; int rest = id / 384; int i = rest % 384; int kh = rest / 384;
    Wt[id] = convW[(o * 384 + i) * 3 + kh];
    return;
  }
  int id2 = id - 384 * 384 * 3;
  if (id2 < 512) {
    float ang = -6.283185307179586f * (float)id2 / 1024.0f;
    float s, c; sincosf(ang, &s, &c);
    twid[2 * id2] = c; twid[2 * id2 + 1] = s;
    return;
  }
  int id3 = id2 - 512;
  if (id3 < NB * ND) {
    int b = id3 / ND, d = id3 % ND;
    outp[(size_t)b * SEQR * ND + d] = x[(size_t)b * SEQR * ND + d];
  }
}

// ---------------------------------------------------------------- gate MLP + mix
// one block = (b, pair of l); computes glob on the fly; writes gated xg to bufA
__global__ __launch_bounds__(192) void k_gate(const float* __restrict__ x,
    const float* __restrict__ W1, const float* __restrict__ b1,
    const float* __restrict__ gam, const float* __restrict__ bet,
    const float* __restrict__ W2, const float* __restrict__ b2,
    float* __restrict__ bufA) {
  int bid = blockIdx.x;
  int b = bid >> 9; int l0 = (bid & 511) * 2;
  int tid = threadIdx.x;
  __shared__ float xr[2][NG][ND];
  __shared__ float gl[2][ND];
  __shared__ float red[8];
  for (int idx = tid; idx < 2 * NG * ND; idx += NDG) {
    int lp = idx / (NG * ND); int rr = idx % (NG * ND); int gg = rr / ND; int d = rr % ND;
    xr[lp][gg][d] = x[((size_t)b * SEQR + 1 + gg * NL + l0 + lp) * ND + d];
  }
  __syncthreads();
  for (int idx = tid; idx < 2 * ND; idx += NDG) {
    int lp = idx / ND; int d = idx % ND;
    gl[lp][d] = (xr[lp][0][d] + xr[lp][1][d] + xr[lp][2][d]) * (1.0f / 3.0f);
  }
  __syncthreads();
  float acc[2][3];
  float accG[2];
  float bb = b1[tid];
#pragma unroll
  for (int lp = 0; lp < 2; lp++) { acc[lp][0] = bb; acc[lp][1] = bb; acc[lp][2] = bb; accG[lp] = 0.f; }
  for (int i = 0; i < ND; i += 4) {
    float w0 = W1[(i+0)*NDG+tid], w1 = W1[(i+1)*NDG+tid], w2 = W1[(i+2)*NDG+tid], w3 = W1[(i+3)*NDG+tid];
#pragma unroll
    for (int lp = 0; lp < 2; lp++) {
#pragma unroll
      for (int gg = 0; gg < 3; gg++) {
        float4 v = *reinterpret_cast<const float4*>(&xr[lp][gg][i]);
        acc[lp][gg] += v.x*w0 + v.y*w1 + v.z*w2 + v.w*w3;
      }
    }
  }
  for (int i = 0; i < ND; i += 4) {
    float w0 = W1[(ND+i+0)*NDG+tid], w1 = W1[(ND+i+1)*NDG+tid], w2 = W1[(ND+i+2)*NDG+tid], w3 = W1[(ND+i+3)*NDG+tid];
#pragma unroll
    for (int lp = 0; lp < 2; lp++) {
      float4 v = *reinterpret_cast<const float4*>(&gl[lp][i]);
      accG[lp] += v.x*w0 + v.y*w1 + v.z*w2 + v.w*w3;
    }
  }
  float gamv = gam[tid], betv = bet[tid], w2v = W2[tid], b2v = b2[0];
#pragma unroll
  for (int lp = 0; lp < 2; lp++) {
#pragma unroll
    for (int gg = 0; gg < 3; gg++) {
      float h = acc[lp][gg] + accG[lp];
      float s = blockSum192(h, red);
      float sq = blockSum192(h * h, red);
      float m = s * (1.0f / NDG);
      float var = sq * (1.0f / NDG) - m * m;
      float hn = fmaxf((h - m) * rsqrtf(var + 1e-5f) * gamv + betv, 0.0f);
      float dot = blockSum192(hn * w2v, red);
      float gate = 1.0f / (1.0f + expf(-(dot + b2v)));
      for (int d = tid; d < ND; d += NDG) {
        bufA[(((size_t)b * NG + gg) * NL + l0 + lp) * ND + d] =
            xr[lp][gg][d] * gate + gl[lp][d] * (1.0f - gate);
      }
    }
  }
}

// ---------------------------------------------------------------- conv (G-dim k=3)
// block = (b, g, 16 l); kh passes staged in LDS; thread owns d0 and d0+192
__global__ __launch_bounds__(192) void k_conv(const float* __restrict__ bufA,
    const float* __restrict__ Wt, const float* __restrict__ cb,
    float* __restrict__ outp) {
  int bid = blockIdx.x;
  int b = bid / 192; int r = bid % 192; int gg = r / 64; int l0 = (r % 64) * 16;
  int tid = threadIdx.x;
  __shared__ float in_s[16][ND];
  int d0 = tid, d1 = tid + 192;
  float acc0[16], acc1[16];
  float cb0 = cb[d0], cb1 = cb[d1];
#pragma unroll
  for (int lt = 0; lt < 16; lt++) { acc0[lt] = cb0; acc1[lt] = cb1; }
  for (int kh = 0; kh < 3; kh++) {
    int gs = gg + kh - 1;
    if (gs < 0 || gs >= NG) continue;         // block-uniform
    __syncthreads();
    for (int idx = tid; idx < 16 * ND; idx += 192) {
      int lt = idx / ND; int i = idx % ND;
      in_s[lt][i] = bufA[(((size_t)b * NG + gs) * NL + l0 + lt) * ND + i];
    }
    __syncthreads();
    const float* Wk = Wt + (size_t)kh * 384 * 384;
    for (int j = 0; j < 384; j += 4) {
      float w00 = Wk[(j+0)*384+d0], w01 = Wk[(j+1)*384+d0], w02 = Wk[(j+2)*384+d0], w03 = Wk[(j+3)*384+d0];
      float w10 = Wk[(j+0)*384+d1], w11 = Wk[(j+1)*384+d1], w12 = Wk[(j+2)*384+d1], w13 = Wk[(j+3)*384+d1];
#pragma unroll
      for (int lt = 0; lt < 16; lt++) {
        float4 v = *reinterpret_cast<const float4*>(&in_s[lt][j]);
        acc0[lt] += v.x*w00 + v.y*w01 + v.z*w02 + v.w*w03;
        acc1[lt] += v.x*w10 + v.y*w11 + v.z*w12 + v.w*w13;
      }
    }
  }
#pragma unroll
  for (int lt = 0; lt < 16; lt++) {
    size_t row = (size_t)b * SEQR + 1 + gg * NL + l0 + lt;
    outp[row * ND + d0] = acc0[lt];
    outp[row * ND + d1] = acc1[lt];
  }
}

// ---------------------------------------------------------------- FFT / IFFT
// radix-2 DIT in LDS; 4 d-lines per block. Fwd: re in/out = outp, im out = bufA.
// Inv: reads both, writes real/1024 to outp.
template <int INV>
__global__ __launch_bounds__(256) void k_fft_t(const float* __restrict__ twid,
                                               float* reb, float* imb) {
  int bid = blockIdx.x;
  int b = bid / 288; int r = bid % 288; int gg = r / 96; int d0 = (r % 96) * 4;
  int tid = threadIdx.x;
  __shared__ float sre[4][1028];
  __shared__ float sim[4][1028];
  size_t baseR = ((size_t)b * SEQR + 1 + (size_t)gg * NL) * ND + d0;
  size_t baseI = (((size_t)b * NG + gg) * NL) * ND + d0;
  for (int idx = tid; idx < 4096; idx += 256) {
    int dd = idx & 3; int l = idx >> 2;
    int rv = (int)(__brev((unsigned)l) >> 22);
    sre[dd][rv] = reb[baseR + (size_t)l * ND + dd];
    sim[dd][rv] = INV ? imb[baseI + (size_t)l * ND + dd] : 0.0f;
  }
  __syncthreads();
  for (int s = 0; s < 10; s++) {
    int m = 1 << s;
    for (int bt = tid; bt < 2048; bt += 256) {
      int line = bt >> 9; int j = bt & 511;
      int jj = j & (m - 1); int grp = j >> s;
      int p0 = (grp << (s + 1)) + jj; int p1 = p0 + m;
      int ti = jj << (9 - s);
      float twr = twid[2 * ti];
      float twi = twid[2 * ti + 1];
      if (INV) twi = -twi;
      float re1 = sre[line][p1], im1 = sim[line][p1];
      float tr = re1 * twr - im1 * twi;
      float tq = re1 * twi + im1 * twr;
      float re0 = sre[line][p0], im0 = sim[line][p0];
      sre[line][p1] = re0 - tr; sim[line][p1] = im0 - tq;
      sre[line][p0] = re0 + tr; sim[line][p0] = im0 + tq;
    }
    __syncthreads();
  }
  if (INV) {
    const float sc = 1.0f / 1024.0f;
    for (int idx = tid; idx < 4096; idx += 256) {
      int dd = idx & 3; int k = idx >> 2;
      reb[baseR + (size_t)k * ND + dd] = sre[dd][k] * sc;
    }
  } else {
    for (int idx = tid; idx < 4096; idx += 256) {
      int dd = idx & 3; int k = idx >> 2;
      reb[baseR + (size_t)k * ND + dd] = sre[dd][k];
      imb[baseI + (size_t)k * ND + dd] = sim[dd][k];
    }
  }
}

// ---------------------------------------------------------------- band MLP
// reads FFT DC bin (= sum over l) for the mean
__global__ __launch_bounds__(96) void k_bd(const float* __restrict__ outp,
    const float* __restrict__ W1, const float* __restrict__ b1,
    const float* __restrict__ gam, const float* __restrict__ bet,
    const float* __restrict__ W2, const float* __restrict__ b2,
    float* __restrict__ bwout) {
  int bid = blockIdx.x;
  int b = bid / NG, gg = bid % NG;
  int tid = threadIdx.x;
  __shared__ float xm[ND];
  __shared__ float hs[NH];
  __shared__ float o3[3];
  size_t dcrow = ((size_t)b * SEQR + 1 + (size_t)gg * NL) * ND;
  for (int i = tid; i < ND; i += NH) xm[i] = outp[dcrow + i] * (1.0f / NL);
  __syncthreads();
  float acc = b1[tid];
  for (int i = 0; i < ND; i++) acc += xm[i] * W1[i * NH + tid];
  hs[tid] = acc;
  __syncthreads();
  float s = 0, sq = 0;
  for (int i = 0; i < NH; i++) { float v = hs[i]; s += v; sq += v * v; }
  float m = s * (1.0f / NH), var = sq * (1.0f / NH) - m * m;
  float hn = fmaxf((acc - m) * rsqrtf(var + 1e-5f) * gam[tid] + bet[tid], 0.0f);
  __syncthreads();
  hs[tid] = hn;
  __syncthreads();
  if (tid < 3) {
    float o = b2[tid];
    for (int k = 0; k < NH; k++) o += hs[k] * W2[k * 3 + tid];
    o3[tid] = o;
  }
  __syncthreads();
  if (tid < 3) {
    float mx = fmaxf(o3[0], fmaxf(o3[1], o3[2]));
    float ssum = expf(o3[0] - mx) + expf(o3[1] - mx) + expf(o3[2] - mx);
    bwout[bid * 3 + tid] = expf(o3[tid] - mx) / ssum;
  }
}

// ---------------------------------------------------------------- mag/phase MLPs + modulate
#define LP 4
__global__ __launch_bounds__(192) void k_att(
    float* rebuf, float* imbuf,
    const float* __restrict__ mgW1, const float* __restrict__ mgb1,
    const float* __restrict__ mgg, const float* __restrict__ mgbe,
    const float* __restrict__ mgW2, const float* __restrict__ mgb2,
    const float* __restrict__ phW1, const float* __restrict__ phb1,
    const float* __restrict__ phg, const float* __restrict__ phbe,
    const float* __restrict__ phW2, const float* __restrict__ phb2,
    const float* __restrict__ bwp) {
  int bid = blockIdx.x;
  int b = bid / 768; int r = bid % 768; int gg = r / 256; int l0 = (r % 256) * LP;
  int tid = threadIdx.x;
  __shared__ float smag[LP][ND];
  __shared__ float sph[LP][ND];
  __shared__ float hbuf[2][LP][NH];
  size_t baseR = ((size_t)b * SEQR + 1 + (size_t)gg * NL + l0) * ND;
  size_t baseI = (((size_t)b * NG + gg) * NL + l0) * ND;
  for (int idx = tid; idx < LP * ND; idx += NDG) {
    int lp = idx / ND, d = idx % ND;
    float re = rebuf[baseR + (size_t)lp * ND + d];
    float im = imbuf[baseI + (size_t)lp * ND + d];
    smag[lp][d] = sqrtf(re * re + im * im);
    sph[lp][d] = atan2f(im, re);
  }
  __syncthreads();
  int br = tid / NH;
  int t = tid % NH;
  const float* W1 = br ? phW1 : mgW1;
  const float* b1p = br ? phb1 : mgb1;
  const float* gmp = br ? phg : mgg;
  const float* bep = br ? phbe : mgbe;
  const float(*sin_)[ND] = br ? sph : smag;
  float acc1[LP];
  {
    float bb = b1p[t];
#pragma unroll
    for (int lp = 0; lp < LP; lp++) acc1[lp] = bb;
  }
  for (int i = 0; i < ND; i += 4) {
    float w0 = W1[(i+0)*NH+t], w1 = W1[(i+1)*NH+t], w2 = W1[(i+2)*NH+t], w3 = W1[(i+3)*NH+t];
#pragma unroll
    for (int lp = 0; lp < LP; lp++) {
      float4 v = *reinterpret_cast<const float4*>(&sin_[lp][i]);
      acc1[lp] += v.x*w0 + v.y*w1 + v.z*w2 + v.w*w3;
    }
  }
#pragma unroll
  for (int lp = 0; lp < LP; lp++) hbuf[br][lp][t] = acc1[lp];
  __syncthreads();
  float gmv = gmp[t], bev = bep[t];
  float hnv[LP];
#pragma unroll
  for (int lp = 0; lp < LP; lp++) {
    float s = 0, sq = 0;
    for (int i = 0; i < NH; i += 4) {
      float4 v = *reinterpret_cast<const float4*>(&hbuf[br][lp][i]);
      s += v.x + v.y + v.z + v.w;
      sq += v.x*v.x + v.y*v.y + v.z*v.z + v.w*v.w;
    }
    float m = s * (1.0f / NH), var = sq * (1.0f / NH) - m * m;
    hnv[lp] = fmaxf((acc1[lp] - m) * rsqrtf(var + 1e-5f) * gmv + bev, 0.0f);
  }
  __syncthreads();
#pragma unroll
  for (int lp = 0; lp < LP; lp++) hbuf[br][lp][t] = hnv[lp];
  __syncthreads();
  float accM[2][LP], accP[2][LP];
#pragma unroll
  for (int di = 0; di < 2; di++) {
    float bm = mgb2[tid + di * NDG];
    float bp = phb2[tid + di * NDG];
#pragma unroll
    for (int lp = 0; lp < LP; lp++) { accM[di][lp] = bm; accP[di][lp] = bp; }
  }
  for (int k = 0; k < NH; k += 4) {
    float4 hm[LP], hp[LP];
#pragma unroll
    for (int lp = 0; lp < LP; lp++) {
      hm[lp] = *reinterpret_cast<const float4*>(&hbuf[0][lp][k]);
      hp[lp] = *reinterpret_cast<const float4*>(&hbuf[1][lp][k]);
    }
#pragma unroll
    for (int di = 0; di < 2; di++) {
      int d = tid + di * NDG;
      float wm0 = mgW2[(k+0)*ND+d], wm1 = mgW2[(k+1)*ND+d], wm2 = mgW2[(k+2)*ND+d], wm3 = mgW2[(k+3)*ND+d];
      float wp0 = phW2[(k+0)*ND+d], wp1 = phW2[(k+1)*ND+d], wp2 = phW2[(k+2)*ND+d], wp3 = phW2[(k+3)*ND+d];
#pragma unroll
      for (int lp = 0; lp < LP; lp++) {
        accM[di][lp] += hm[lp].x*wm0 + hm[lp].y*wm1 + hm[lp].z*wm2 + hm[lp].w*wm3;
        accP[di][lp] += hp[lp].x*wp0 + hp[lp].y*wp1 + hp[lp].z*wp2 + hp[lp].w*wp3;
      }
    }
  }
  int bwbase = (b * NG + gg) * 3;
  float bw0 = bwp[bwbase], bw1 = bwp[bwbase + 1], bw2 = bwp[bwbase + 2];
#pragma unroll
  for (int di = 0; di < 2; di++) {
    int d = tid + di * NDG;
#pragma unroll
    for (int lp = 0; lp < LP; lp++) {
      int l = l0 + lp;
      int fr = (l <= 512) ? l : (1024 - l);
      float wmv = (fr <= 128) ? bw0 : ((fr <= 256) ? bw1 : bw2);
      float ma = 1.0f / (1.0f + expf(-accM[di][lp]));
      float pa = tanhf(accP[di][lp]);
      float mago = smag[lp][d] * wmv * ma;
      float pho = sph[lp][d] * wmv + pa;
      float sn, cs;
      sincosf(pho, &sn, &cs);
      rebuf[baseR + (size_t)lp * ND + d] = mago * cs;
      imbuf[baseI + (size_t)lp * ND + d] = mago * sn;
    }
  }
}

// ---------------------------------------------------------------- launch
extern "C" void kernel_launch(void* const* d_in, const int* in_sizes, int n_in,
                              void* d_out, int out_size, void* d_ws, size_t ws_size,
                              hipStream_t stream) {
  (void)in_sizes; (void)n_in; (void)out_size; (void)ws_size;
  const float* x     = (const float*)d_in[0];
  const float* mgW1  = (const float*)d_in[1];
  const float* mgb1  = (const float*)d_in[2];
  const float* mgg   = (const float*)d_in[3];
  const float* mgbe  = (const float*)d_in[4];
  const float* mgW2  = (const float*)d_in[5];
  const float* mgb2  = (const float*)d_in[6];
  const float* phW1  = (const float*)d_in[7];
  const float* phb1  = (const float*)d_in[8];
  const float* phg   = (const float*)d_in[9];
  const float* phbe  = (const float*)d_in[10];
  const float* phW2  = (const float*)d_in[11];
  const float* phb2  = (const float*)d_in[12];
  const float* bdW1  = (const float*)d_in[13];
  const float* bdb1  = (const float*)d_in[14];
  const float* bdg   = (const float*)d_in[15];
  const float* bdbe  = (const float*)d_in[16];
  const float* bdW2  = (const float*)d_in[17];
  const float* bdb2  = (const float*)d_in[18];
  const float* cgW1  = (const float*)d_in[19];
  const float* cgb1  = (const float*)d_in[20];
  const float* cgg   = (const float*)d_in[21];
  const float* cgbe  = (const float*)d_in[22];
  const float* cgW2  = (const float*)d_in[23];
  const float* cgb2  = (const float*)d_in[24];
  const float* convW = (const float*)d_in[25];
  const float* convB = (const float*)d_in[26];

  float* outp = (float*)d_out;
  float* wsf  = (float*)d_ws;
  float* bufA = wsf;                                  // NB*NG*NL*ND floats (gated xg, then imag)
  float* Wt   = bufA + (size_t)NB * NG * NL * ND;     // 442368 floats
  float* twid = Wt + 384 * 384 * 3;                   // 1024 floats
  float* bwp  = twid + 1024;                          // 288 floats

  k_prep<<<dim3(1778), dim3(256), 0, stream>>>(convW, x, Wt, twid, outp);
  k_gate<<<dim3(NB * 512), dim3(192), 0, stream>>>(x, cgW1, cgb1, cgg, cgbe, cgW2, cgb2, bufA);
  k_conv<<<dim3(NB * NG * 64), dim3(192), 0, stream>>>(bufA, Wt, convB, outp);
  k_fft_t<0><<<dim3(NB * NG * 96), dim3(256), 0, stream>>>(twid, outp, bufA);
  k_bd<<<dim3(NB * NG), dim3(96), 0, stream>>>(outp, bdW1, bdb1, bdg, bdbe, bdW2, bdb2, bwp);
  k_att<<<dim3(NB * NG * 256), dim3(192), 0, stream>>>(outp, bufA,
      mgW1, mgb1, mgg, mgbe, mgW2, mgb2,
      phW1, phb1, phg, phbe, phW2, phb2, bwp);
  k_fft_t<1><<<dim3(NB * NG * 96), dim3(256), 0, stream>>>(twid, outp, bufA);
}

// Round 2
// 2792.068 us; speedup vs baseline: 1.4394x; 1.4394x over previous
//
#include <hip/hip_runtime.h>
#include <hip/hip_bf16.h>
#include <math.h>

#define NB 32
#define NL 1024
#define NG 3
#define ND 384
#define NH 96
#define NDG 192
#define SEQR 3073   // 1 + NG*NL

typedef __attribute__((ext_vector_type(8))) short short8n;
typedef __attribute__((ext_vector_type(4))) float f32x4;

// ---------------------------------------------------------------- helpers
__device__ __forceinline__ float blockSum192(float v, volatile float* red) {
#pragma unroll
  for (int off = 32; off > 0; off >>= 1) v += __shfl_xor(v, off, 64);
  int wid = threadIdx.x >> 6;
  __syncthreads();                       // protect red reuse from prior call
  if ((threadIdx.x & 63) == 0) red[wid] = v;
  __syncthreads();
  return red[0] + red[1] + red[2];
}

// ---------------------------------------------------------------- prep
// Wt2[kh][o][i] (bf16) = convW[(o*384+i)*3+kh]; twiddles; cls copy
__global__ __launch_bounds__(256) void k_prep(const float* __restrict__ convW,
                                              const float* __restrict__ x,
                                              __hip_bfloat16* __restrict__ Wt2,
                                              float* __restrict__ twid,
                                              float* __restrict__ outp) {
  int id = blockIdx.x * 256 + threadIdx.x;
  if (id < 384 * 384 * 3) {
    int i = id % 384; int rest = id / 384; int o = rest % 384; int kh = rest / 384;
    Wt2[id] = __float2bfloat16(convW[(o * 384 + i) * 3 + kh]);
    return;
  }
  int id2 = id - 384 * 384 * 3;
  if (id2 < 512) {
    float ang = -6.283185307179586f * (float)id2 / 1024.0f;
    float s, c; sincosf(ang, &s, &c);
    twid[2 * id2] = c; twid[2 * id2 + 1] = s;
    return;
  }
  int id3 = id2 - 512;
  if (id3 < NB * ND) {
    int b = id3 / ND, d = id3 % ND;
    outp[(size_t)b * SEQR * ND + d] = x[(size_t)b * SEQR * ND + d];
  }
}

// ---------------------------------------------------------------- gate MLP + mix
// one block = (b, pair of l); computes glob on the fly; writes gated xg (bf16)
__global__ __launch_bounds__(192) void k_gate(const float* __restrict__ x,
    const float* __restrict__ W1, const float* __restrict__ b1,
    const float* __restrict__ gam, const float* __restrict__ bet,
    const float* __restrict__ W2, const float* __restrict__ b2,
    __hip_bfloat16* __restrict__ gatedA) {
  int bid = blockIdx.x;
  int b = bid >> 9; int l0 = (bid & 511) * 2;
  int tid = threadIdx.x;
  __shared__ float xr[2][NG][ND];
  __shared__ float gl[2][ND];
  __shared__ float red[8];
  for (int idx = tid; idx < 2 * NG * ND; idx += NDG) {
    int lp = idx / (NG * ND); int rr = idx % (NG * ND); int gg = rr / ND; int d = rr % ND;
    xr[lp][gg][d] = x[((size_t)b * SEQR + 1 + gg * NL + l0 + lp) * ND + d];
  }
  __syncthreads();
  for (int idx = tid; idx < 2 * ND; idx += NDG) {
    int lp = idx / ND; int d = idx % ND;
    gl[lp][d] = (xr[lp][0][d] + xr[lp][1][d] + xr[lp][2][d]) * (1.0f / 3.0f);
  }
  __syncthreads();
  float acc[2][3];
  float accG[2];
  float bb = b1[tid];
#pragma unroll
  for (int lp = 0; lp < 2; lp++) { acc[lp][0] = bb; acc[lp][1] = bb; acc[lp][2] = bb; accG[lp] = 0.f; }
  for (int i = 0; i < ND; i += 4) {
    float w0 = W1[(i+0)*NDG+tid], w1 = W1[(i+1)*NDG+tid], w2 = W1[(i+2)*NDG+tid], w3 = W1[(i+3)*NDG+tid];
#pragma unroll
    for (int lp = 0; lp < 2; lp++) {
#pragma unroll
      for (int gg = 0; gg < 3; gg++) {
        float4 v = *reinterpret_cast<const float4*>(&xr[lp][gg][i]);
        acc[lp][gg] += v.x*w0 + v.y*w1 + v.z*w2 + v.w*w3;
      }
    }
  }
  for (int i = 0; i < ND; i += 4) {
    float w0 = W1[(ND+i+0)*NDG+tid], w1 = W1[(ND+i+1)*NDG+tid], w2 = W1[(ND+i+2)*NDG+tid], w3 = W1[(ND+i+3)*NDG+tid];
#pragma unroll
    for (int lp = 0; lp < 2; lp++) {
      float4 v = *reinterpret_cast<const float4*>(&gl[lp][i]);
      accG[lp] += v.x*w0 + v.y*w1 + v.z*w2 + v.w*w3;
    }
  }
  float gamv = gam[tid], betv = bet[tid], w2v = W2[tid], b2v = b2[0];
#pragma unroll
  for (int lp = 0; lp < 2; lp++) {
#pragma unroll
    for (int gg = 0; gg < 3; gg++) {
      float h = acc[lp][gg] + accG[lp];
      float s = blockSum192(h, red);
      float sq = blockSum192(h * h, red);
      float m = s * (1.0f / NDG);
      float var = sq * (1.0f / NDG) - m * m;
      float hn = fmaxf((h - m) * rsqrtf(var + 1e-5f) * gamv + betv, 0.0f);
      float dot = blockSum192(hn * w2v, red);
      float gate = 1.0f / (1.0f + expf(-(dot + b2v)));
      for (int d = tid; d < ND; d += NDG) {
        gatedA[(((size_t)b * NG + gg) * NL + l0 + lp) * ND + d] =
            __float2bfloat16(xr[lp][gg][d] * gate + gl[lp][d] * (1.0f - gate));
      }
    }
  }
}

// ---------------------------------------------------------------- conv as bf16 MFMA GEMM
// out[b,g,l,o] = sum_{kh,i} gated[b,g+kh-1,l,i] * Wt2[kh,o,i] + cb[o]
// grid: (b,g) x 8 row-tiles(128 l) x 3 col-tiles(128 o); 256 thr = 4 waves of 64x64
#define BKC 64
__global__ __launch_bounds__(256) void k_conv_mfma(
    const __hip_bfloat16* __restrict__ Abuf,
    const __hip_bfloat16* __restrict__ Wt2,
    const float* __restrict__ cb,
    float* __restrict__ outp) {
  int bid = blockIdx.x;
  int ct = bid % 3; int rest = bid / 3;
  int rt = rest % 8; int bg = rest / 8;
  int b = bg / NG, gg = bg % NG;
  int l0 = rt * 128;
  int n0 = ct * 128;
  int tid = threadIdx.x;
  int lane = tid & 63, wid = tid >> 6;
  int wr = wid >> 1, wc = wid & 1;
  int r15 = lane & 15, kc = lane >> 4;

  __shared__ short As[128 * BKC];   // [row][k], 128B rows, chunk XOR-swizzled
  __shared__ short Bs[128 * BKC];

  f32x4 acc[4][4];
#pragma unroll
  for (int m = 0; m < 4; m++)
#pragma unroll
    for (int n = 0; n < 4; n++) acc[m][n] = (f32x4){0.f, 0.f, 0.f, 0.f};

  for (int kh = 0; kh < 3; kh++) {
    int gs = gg + kh - 1;
    if (gs < 0 || gs >= NG) continue;   // block-uniform
    const __hip_bfloat16* Ag = Abuf + (((size_t)b * NG + gs) * NL + l0) * ND;
    const __hip_bfloat16* Bg = Wt2 + ((size_t)kh * 384 + n0) * 384;
    for (int k0 = 0; k0 < 384; k0 += BKC) {
      __syncthreads();
#pragma unroll
      for (int p = 0; p < 4; p++) {
        int idx = p * 256 + tid;        // 0..1023
        int row = idx >> 3, c = idx & 7;
        int csrc = c ^ (row & 7);
        __builtin_amdgcn_global_load_lds(
            (const __attribute__((address_space(1))) void*)(Ag + (size_t)row * ND + k0 + csrc * 8),
            (__attribute__((address_space(3))) void*)(&As[idx * 8]), 16, 0, 0);
      }
#pragma unroll
      for (int p = 0; p < 4; p++) {
        int idx = p * 256 + tid;
        int row = idx >> 3, c = idx & 7;
        int csrc = c ^ (row & 7);
        __builtin_amdgcn_global_load_lds(
            (const __attribute__((address_space(1))) void*)(Bg + (size_t)row * 384 + k0 + csrc * 8),
            (__attribute__((address_space(3))) void*)(&Bs[idx * 8]), 16, 0, 0);
      }
      __syncthreads();                  // compiler drains vmcnt before barrier
#pragma unroll
      for (int ks = 0; ks < 2; ks++) {
        short8n af[4], bfr[4];
        int cdata = ks * 4 + kc;
#pragma unroll
        for (int m = 0; m < 4; m++) {
          int row = wr * 64 + m * 16 + r15;
          af[m] = *reinterpret_cast<const short8n*>(&As[row * 64 + (cdata ^ (row & 7)) * 8]);
          int col = wc * 64 + m * 16 + r15;
          bfr[m] = *reinterpret_cast<const short8n*>(&Bs[col * 64 + (cdata ^ (col & 7)) * 8]);
        }
#pragma unroll
        for (int m = 0; m < 4; m++)
#pragma unroll
          for (int n = 0; n < 4; n++)
            acc[m][n] = __builtin_amdgcn_mfma_f32_16x16x32_bf16(af[m], bfr[n], acc[m][n], 0, 0, 0);
      }
    }
  }
  // epilogue: D col=lane&15, row=(lane>>4)*4+reg
  float cbv[4];
#pragma unroll
  for (int n = 0; n < 4; n++) cbv[n] = cb[n0 + wc * 64 + n * 16 + r15];
  size_t orow = (size_t)b * SEQR + 1 + (size_t)gg * NL + l0 + wr * 64;
#pragma unroll
  for (int m = 0; m < 4; m++) {
#pragma unroll
    for (int j = 0; j < 4; j++) {
      size_t grow = orow + m * 16 + kc * 4 + j;
#pragma unroll
      for (int n = 0; n < 4; n++) {
        outp[grow * ND + n0 + wc * 64 + n * 16 + r15] = acc[m][n][j] + cbv[n];
      }
    }
  }
}

// ---------------------------------------------------------------- FFT / IFFT
template <int INV>
__global__ __launch_bounds__(256) void k_fft_t(const float* __restrict__ twid,
                                               float* reb, float* imb) {
  int bid = blockIdx.x;
  int b = bid / 288; int r = bid % 288; int gg = r / 96; int d0 = (r % 96) * 4;
  int tid = threadIdx.x;
  __shared__ float sre[4][1028];
  __shared__ float sim[4][1028];
  size_t baseR = ((size_t)b * SEQR + 1 + (size_t)gg * NL) * ND + d0;
  size_t baseI = (((size_t)b * NG + gg) * NL) * ND + d0;
  for (int idx = tid; idx < 4096; idx += 256) {
    int dd = idx & 3; int l = idx >> 2;
    int rv = (int)(__brev((unsigned)l) >> 22);
    sre[dd][rv] = reb[baseR + (size_t)l * ND + dd];
    sim[dd][rv] = INV ? imb[baseI + (size_t)l * ND + dd] : 0.0f;
  }
  __syncthreads();
  for (int s = 0; s < 10; s++) {
    int m = 1 << s;
    for (int bt = tid; bt < 2048; bt += 256) {
      int line = bt >> 9; int j = bt & 511;
      int jj = j & (m - 1); int grp = j >> s;
      int p0 = (grp << (s + 1)) + jj; int p1 = p0 + m;
      int ti = jj << (9 - s);
      float twr = twid[2 * ti];
      float twi = twid[2 * ti + 1];
      if (INV) twi = -twi;
      float re1 = sre[line][p1], im1 = sim[line][p1];
      float tr = re1 * twr - im1 * twi;
      float tq = re1 * twi + im1 * twr;
      float re0 = sre[line][p0], im0 = sim[line][p0];
      sre[line][p1] = re0 - tr; sim[line][p1] = im0 - tq;
      sre[line][p0] = re0 + tr; sim[line][p0] = im0 + tq;
    }
    __syncthreads();
  }
  if (INV) {
    const float sc = 1.0f / 1024.0f;
    for (int idx = tid; idx < 4096; idx += 256) {
      int dd = idx & 3; int k = idx >> 2;
      reb[baseR + (size_t)k * ND + dd] = sre[dd][k] * sc;
    }
  } else {
    for (int idx = tid; idx < 4096; idx += 256) {
      int dd = idx & 3; int k = idx >> 2;
      reb[baseR + (size_t)k * ND + dd] = sre[dd][k];
      imb[baseI + (size_t)k * ND + dd] = sim[dd][k];
    }
  }
}

// ---------------------------------------------------------------- band MLP
__global__ __launch_bounds__(96) void k_bd(const float* __restrict__ outp,
    const float* __restrict__ W1, const float* __restrict__ b1,
    const float* __restrict__ gam, const float* __restrict__ bet,
    const float* __restrict__ W2, const float* __restrict__ b2,
    float* __restrict__ bwout) {
  int bid = blockIdx.x;
  int b = bid / NG, gg = bid % NG;
  int tid = threadIdx.x;
  __shared__ float xm[ND];
  __shared__ float hs[NH];
  __shared__ float o3[3];
  size_t dcrow = ((size_t)b * SEQR + 1 + (size_t)gg * NL) * ND;
  for (int i = tid; i < ND; i += NH) xm[i] = outp[dcrow + i] * (1.0f / NL);
  __syncthreads();
  float acc = b1[tid];
  for (int i = 0; i < ND; i++) acc += xm[i] * W1[i * NH + tid];
  hs[tid] = acc;
  __syncthreads();
  float s = 0, sq = 0;
  for (int i = 0; i < NH; i++) { float v = hs[i]; s += v; sq += v * v; }
  float m = s * (1.0f / NH), var = sq * (1.0f / NH) - m * m;
  float hn = fmaxf((acc - m) * rsqrtf(var + 1e-5f) * gam[tid] + bet[tid], 0.0f);
  __syncthreads();
  hs[tid] = hn;
  __syncthreads();
  if (tid < 3) {
    float o = b2[tid];
    for (int k = 0; k < NH; k++) o += hs[k] * W2[k * 3 + tid];
    o3[tid] = o;
  }
  __syncthreads();
  if (tid < 3) {
    float mx = fmaxf(o3[0], fmaxf(o3[1], o3[2]));
    float ssum = expf(o3[0] - mx) + expf(o3[1] - mx) + expf(o3[2] - mx);
    bwout[bid * 3 + tid] = expf(o3[tid] - mx) / ssum;
  }
}

// ---------------------------------------------------------------- mag/phase MLPs + modulate
#define LP 4
__global__ __launch_bounds__(192) void k_att(
    float* rebuf, float* imbuf,
    const float* __restrict__ mgW1, const float* __restrict__ mgb1,
    const float* __restrict__ mgg, const float* __restrict__ mgbe,
    const float* __restrict__ mgW2, const float* __restrict__ mgb2,
    const float* __restrict__ phW1, const float* __restrict__ phb1,
    const float* __restrict__ phg, const float* __restrict__ phbe,
    const float* __restrict__ phW2, const float* __restrict__ phb2,
    const float* __restrict__ bwp) {
  int bid = blockIdx.x;
  int b = bid / 768; int r = bid % 768; int gg = r / 256; int l0 = (r % 256) * LP;
  int tid = threadIdx.x;
  __shared__ float smag[LP][ND];
  __shared__ float sph[LP][ND];
  __shared__ float hbuf[2][LP][NH];
  size_t baseR = ((size_t)b * SEQR + 1 + (size_t)gg * NL + l0) * ND;
  size_t baseI = (((size_t)b * NG + gg) * NL + l0) * ND;
  for (int idx = tid; idx < LP * ND; idx += NDG) {
    int lp = idx / ND, d = idx % ND;
    float re = rebuf[baseR + (size_t)lp * ND + d];
    float im = imbuf[baseI + (size_t)lp * ND + d];
    smag[lp][d] = sqrtf(re * re + im * im);
    sph[lp][d] = atan2f(im, re);
  }
  __syncthreads();
  int br = tid / NH;
  int t = tid % NH;
  const float* W1 = br ? phW1 : mgW1;
  const float* b1p = br ? phb1 : mgb1;
  const float* gmp = br ? phg : mgg;
  const float* bep = br ? phbe : mgbe;
  const float(*sin_)[ND] = br ? sph : smag;
  float acc1[LP];
  {
    float bb = b1p[t];
#pragma unroll
    for (int lp = 0; lp < LP; lp++) acc1[lp] = bb;
  }
  for (int i = 0; i < ND; i += 4) {
    float w0 = W1[(i+0)*NH+t], w1 = W1[(i+1)*NH+t], w2 = W1[(i+2)*NH+t], w3 = W1[(i+3)*NH+t];
#pragma unroll
    for (int lp = 0; lp < LP; lp++) {
      float4 v = *reinterpret_cast<const float4*>(&sin_[lp][i]);
      acc1[lp] += v.x*w0 + v.y*w1 + v.z*w2 + v.w*w3;
    }
  }
#pragma unroll
  for (int lp = 0; lp < LP; lp++) hbuf[br][lp][t] = acc1[lp];
  __syncthreads();
  float gmv = gmp[t], bev = bep[t];
  float hnv[LP];
#pragma unroll
  for (int lp = 0; lp < LP; lp++) {
    float s = 0, sq = 0;
    for (int i = 0; i < NH; i += 4) {
      float4 v = *reinterpret_cast<const float4*>(&hbuf[br][lp][i]);
      s += v.x + v.y + v.z + v.w;
      sq += v.x*v.x + v.y*v.y + v.z*v.z + v.w*v.w;
    }
    float m = s * (1.0f / NH), var = sq * (1.0f / NH) - m * m;
    hnv[lp] = fmaxf((acc1[lp] - m) * rsqrtf(var + 1e-5f) * gmv + bev, 0.0f);
  }
  __syncthreads();
#pragma unroll
  for (int lp = 0; lp < LP; lp++) hbuf[br][lp][t] = hnv[lp];
  __syncthreads();
  float accM[2][LP], accP[2][LP];
#pragma unroll
  for (int di = 0; di < 2; di++) {
    float bm = mgb2[tid + di * NDG];
    float bp = phb2[tid + di * NDG];
#pragma unroll
    for (int lp = 0; lp < LP; lp++) { accM[di][lp] = bm; accP[di][lp] = bp; }
  }
  for (int k = 0; k < NH; k += 4) {
    float4 hm[LP], hp[LP];
#pragma unroll
    for (int lp = 0; lp < LP; lp++) {
      hm[lp] = *reinterpret_cast<const float4*>(&hbuf[0][lp][k]);
      hp[lp] = *reinterpret_cast<const float4*>(&hbuf[1][lp][k]);
    }
#pragma unroll
    for (int di = 0; di < 2; di++) {
      int d = tid + di * NDG;
      float wm0 = mgW2[(k+0)*ND+d], wm1 = mgW2[(k+1)*ND+d], wm2 = mgW2[(k+2)*ND+d], wm3 = mgW2[(k+3)*ND+d];
      float wp0 = phW2[(k+0)*ND+d], wp1 = phW2[(k+1)*ND+d], wp2 = phW2[(k+2)*ND+d], wp3 = phW2[(k+3)*ND+d];
#pragma unroll
      for (int lp = 0; lp < LP; lp++) {
        accM[di][lp] += hm[lp].x*wm0 + hm[lp].y*wm1 + hm[lp].z*wm2 + hm[lp].w*wm3;
        accP[di][lp] += hp[lp].x*wp0 + hp[lp].y*wp1 + hp[lp].z*wp2 + hp[lp].w*wp3;
      }
    }
  }
  int bwbase = (b * NG + gg) * 3;
  float bw0 = bwp[bwbase], bw1 = bwp[bwbase + 1], bw2 = bwp[bwbase + 2];
#pragma unroll
  for (int di = 0; di < 2; di++) {
    int d = tid + di * NDG;
#pragma unroll
    for (int lp = 0; lp < LP; lp++) {
      int l = l0 + lp;
      int fr = (l <= 512) ? l : (1024 - l);
      float wmv = (fr <= 128) ? bw0 : ((fr <= 256) ? bw1 : bw2);
      float ma = 1.0f / (1.0f + expf(-accM[di][lp]));
      float pa = tanhf(accP[di][lp]);
      float mago = smag[lp][d] * wmv * ma;
      float pho = sph[lp][d] * wmv + pa;
      float sn, cs;
      sincosf(pho, &sn, &cs);
      rebuf[baseR + (size_t)lp * ND + d] = mago * cs;
      imbuf[baseI + (size_t)lp * ND + d] = mago * sn;
    }
  }
}

// ---------------------------------------------------------------- launch
extern "C" void kernel_launch(void* const* d_in, const int* in_sizes, int n_in,
                              void* d_out, int out_size, void* d_ws, size_t ws_size,
                              hipStream_t stream) {
  (void)in_sizes; (void)n_in; (void)out_size; (void)ws_size;
  const float* x     = (const float*)d_in[0];
  const float* mgW1  = (const float*)d_in[1];
  const float* mgb1  = (const float*)d_in[2];
  const float* mgg   = (const float*)d_in[3];
  const float* mgbe  = (const float*)d_in[4];
  const float* mgW2  = (const float*)d_in[5];
  const float* mgb2  = (const float*)d_in[6];
  const float* phW1  = (const float*)d_in[7];
  const float* phb1  = (const float*)d_in[8];
  const float* phg   = (const float*)d_in[9];
  const float* phbe  = (const float*)d_in[10];
  const float* phW2  = (const float*)d_in[11];
  const float* phb2  = (const float*)d_in[12];
  const float* bdW1  = (const float*)d_in[13];
  const float* bdb1  = (const float*)d_in[14];
  const float* bdg   = (const float*)d_in[15];
  const float* bdbe  = (const float*)d_in[16];
  const float* bdW2  = (const float*)d_in[17];
  const float* bdb2  = (const float*)d_in[18];
  const float* cgW1  = (const float*)d_in[19];
  const float* cgb1  = (const float*)d_in[20];
  const float* cgg   = (const float*)d_in[21];
  const float* cgbe  = (const float*)d_in[22];
  const float* cgW2  = (const float*)d_in[23];
  const float* cgb2  = (const float*)d_in[24];
  const float* convW = (const float*)d_in[25];
  const float* convB = (const float*)d_in[26];

  float* outp = (float*)d_out;
  float* wsf  = (float*)d_ws;
  // region0: gated activations (bf16, 75.5MB) then FFT imag (fp32, 151MB) — disjoint lifetimes
  float* bufA = wsf;
  __hip_bfloat16* gatedA = (__hip_bfloat16*)wsf;
  __hip_bfloat16* Wt2 = (__hip_bfloat16*)(wsf + (size_t)NB * NG * NL * ND);
  float* twid = (float*)((char*)Wt2 + (size_t)384 * 384 * 3 * 2);
  float* bwp  = twid + 1024;

  k_prep<<<dim3(1778), dim3(256), 0, stream>>>(convW, x, Wt2, twid, outp);
  k_gate<<<dim3(NB * 512), dim3(192), 0, stream>>>(x, cgW1, cgb1, cgg, cgbe, cgW2, cgb2, gatedA);
  k_conv_mfma<<<dim3(NB * NG * 8 * 3), dim3(256), 0, stream>>>(gatedA, Wt2, convB, outp);
  k_fft_t<0><<<dim3(NB * NG * 96), dim3(256), 0, stream>>>(twid, outp, bufA);
  k_bd<<<dim3(NB * NG), dim3(96), 0, stream>>>(outp, bdW1, bdb1, bdg, bdbe, bdW2, bdb2, bwp);
  k_att<<<dim3(NB * NG * 256), dim3(192), 0, stream>>>(outp, bufA,
      mgW1, mgb1, mgg, mgbe, mgW2, mgb2,
      phW1, phb1, phg, phbe, phW2, phb2, bwp);
  k_fft_t<1><<<dim3(NB * NG * 96), dim3(256), 0, stream>>>(twid, outp, bufA);
}

// Round 3
// 2175.013 us; speedup vs baseline: 1.8478x; 1.2837x over previous
//
#include <hip/hip_runtime.h>
#include <hip/hip_bf16.h>
#include <math.h>

#define NB 32
#define NL 1024
#define NG 3
#define ND 384
#define NH 96
#define NDG 192
#define SEQR 3073   // 1 + NG*NL

typedef __attribute__((ext_vector_type(8))) short short8n;
typedef __attribute__((ext_vector_type(4))) short short4n;
typedef __attribute__((ext_vector_type(4))) float f32x4;

__device__ __forceinline__ short bfx(float f) {
  __hip_bfloat16 h = __float2bfloat16(f);
  return *reinterpret_cast<short*>(&h);
}

// fast atan2, abs err <= ~1e-5 rad
__device__ __forceinline__ float fast_atan2f(float y, float x) {
  float ax = fabsf(x), ay = fabsf(y);
  float mx = fmaxf(ax, ay), mn = fminf(ax, ay);
  float r = (mx == 0.0f) ? 0.0f : __fdividef(mn, mx);
  float s = r * r;
  float p = fmaf(s, 0.0208351f, -0.0851330f);
  p = fmaf(s, p, 0.1801410f);
  p = fmaf(s, p, -0.3302995f);
  p = fmaf(s, p, 0.9998660f);
  p = r * p;
  float a = (ay > ax) ? (1.5707963267948966f - p) : p;
  a = (x < 0.0f) ? (3.14159265358979323846f - a) : a;
  return (y < 0.0f) ? -a : a;
}

__device__ __forceinline__ float fast_sigmoid(float x) {
  return __fdividef(1.0f, 1.0f + __expf(-x));
}
__device__ __forceinline__ float fast_tanh(float x) {
  return 1.0f - __fdividef(2.0f, 1.0f + __expf(2.0f * x));
}

// ---------------------------------------------------------------- helpers
__device__ __forceinline__ float blockSum192(float v, volatile float* red) {
#pragma unroll
  for (int off = 32; off > 0; off >>= 1) v += __shfl_xor(v, off, 64);
  int wid = threadIdx.x >> 6;
  __syncthreads();
  if ((threadIdx.x & 63) == 0) red[wid] = v;
  __syncthreads();
  return red[0] + red[1] + red[2];
}

// ---------------------------------------------------------------- prep
// Wt2[kh][o][i] bf16; twiddles; cls copy; W1A/W2A MFMA-frag-packed bf16 weights
__global__ __launch_bounds__(256) void k_prep(const float* __restrict__ convW,
                                              const float* __restrict__ x,
                                              const float* __restrict__ mgW1s,
                                              const float* __restrict__ phW1s,
                                              const float* __restrict__ mgW2s,
                                              const float* __restrict__ phW2s,
                                              __hip_bfloat16* __restrict__ Wt2,
                                              float* __restrict__ twid,
                                              __hip_bfloat16* __restrict__ W1Ao,
                                              __hip_bfloat16* __restrict__ W2Ao,
                                              float* __restrict__ outp) {
  int id = blockIdx.x * 256 + threadIdx.x;
  if (id < 384 * 384 * 3) {
    int i = id % 384; int rest = id / 384; int o = rest % 384; int kh = rest / 384;
    Wt2[id] = __float2bfloat16(convW[(o * 384 + i) * 3 + kh]);
    return;
  }
  int id2 = id - 384 * 384 * 3;
  if (id2 < 512) {
    float ang = -6.283185307179586f * (float)id2 / 1024.0f;
    float s, c; sincosf(ang, &s, &c);
    twid[2 * id2] = c; twid[2 * id2 + 1] = s;
    return;
  }
  int id3 = id2 - 512;
  if (id3 < NB * ND) {
    int b = id3 / ND, d = id3 % ND;
    outp[(size_t)b * SEQR * ND + d] = x[(size_t)b * SEQR * ND + d];
    return;
  }
  int id4 = id3 - NB * ND;
  if (id4 < 2 * 36864) {   // W1A: [br][kk(12)][f(6)][lane(64)][8]
    int br = id4 / 36864, idx = id4 % 36864;
    int j = idx & 7, ln = (idx >> 3) & 63, rest = idx >> 9;
    int f = rest % 6, kk = rest / 6;
    int m = f * 16 + (ln & 15), k = kk * 32 + (ln >> 4) * 8 + j;
    const float* W = br ? phW1s : mgW1s;
    W1Ao[id4] = __float2bfloat16(W[k * NH + m]);
    return;
  }
  int id5 = id4 - 2 * 36864;
  if (id5 < 2 * 36864) {   // W2A: [br][kk(3)][f(24)][lane(64)][8]
    int br = id5 / 36864, idx = id5 % 36864;
    int j = idx & 7, ln = (idx >> 3) & 63, rest = idx >> 9;
    int f = rest % 24, kk = rest / 24;
    int d = f * 16 + (ln & 15), k = kk * 32 + (ln >> 4) * 8 + j;
    const float* W = br ? phW2s : mgW2s;
    W2Ao[id5] = __float2bfloat16(W[k * ND + d]);
  }
}

// ---------------------------------------------------------------- gate MLP + mix
__global__ __launch_bounds__(192) void k_gate(const float* __restrict__ x,
    const float* __restrict__ W1, const float* __restrict__ b1,
    const float* __restrict__ gam, const float* __restrict__ bet,
    const float* __restrict__ W2, const float* __restrict__ b2,
    __hip_bfloat16* __restrict__ gatedA) {
  int bid = blockIdx.x;
  int b = bid >> 9; int l0 = (bid & 511) * 2;
  int tid = threadIdx.x;
  __shared__ float xr[2][NG][ND];
  __shared__ float gl[2][ND];
  __shared__ float red[8];
  for (int idx = tid; idx < 2 * NG * ND; idx += NDG) {
    int lp = idx / (NG * ND); int rr = idx % (NG * ND); int gg = rr / ND; int d = rr % ND;
    xr[lp][gg][d] = x[((size_t)b * SEQR + 1 + gg * NL + l0 + lp) * ND + d];
  }
  __syncthreads();
  for (int idx = tid; idx < 2 * ND; idx += NDG) {
    int lp = idx / ND; int d = idx % ND;
    gl[lp][d] = (xr[lp][0][d] + xr[lp][1][d] + xr[lp][2][d]) * (1.0f / 3.0f);
  }
  __syncthreads();
  float acc[2][3];
  float accG[2];
  float bb = b1[tid];
#pragma unroll
  for (int lp = 0; lp < 2; lp++) { acc[lp][0] = bb; acc[lp][1] = bb; acc[lp][2] = bb; accG[lp] = 0.f; }
  for (int i = 0; i < ND; i += 4) {
    float w0 = W1[(i+0)*NDG+tid], w1 = W1[(i+1)*NDG+tid], w2 = W1[(i+2)*NDG+tid], w3 = W1[(i+3)*NDG+tid];
#pragma unroll
    for (int lp = 0; lp < 2; lp++) {
#pragma unroll
      for (int gg = 0; gg < 3; gg++) {
        float4 v = *reinterpret_cast<const float4*>(&xr[lp][gg][i]);
        acc[lp][gg] += v.x*w0 + v.y*w1 + v.z*w2 + v.w*w3;
      }
    }
  }
  for (int i = 0; i < ND; i += 4) {
    float w0 = W1[(ND+i+0)*NDG+tid], w1 = W1[(ND+i+1)*NDG+tid], w2 = W1[(ND+i+2)*NDG+tid], w3 = W1[(ND+i+3)*NDG+tid];
#pragma unroll
    for (int lp = 0; lp < 2; lp++) {
      float4 v = *reinterpret_cast<const float4*>(&gl[lp][i]);
      accG[lp] += v.x*w0 + v.y*w1 + v.z*w2 + v.w*w3;
    }
  }
  float gamv = gam[tid], betv = bet[tid], w2v = W2[tid], b2v = b2[0];
#pragma unroll
  for (int lp = 0; lp < 2; lp++) {
#pragma unroll
    for (int gg = 0; gg < 3; gg++) {
      float h = acc[lp][gg] + accG[lp];
      float s = blockSum192(h, red);
      float sq = blockSum192(h * h, red);
      float m = s * (1.0f / NDG);
      float var = sq * (1.0f / NDG) - m * m;
      float hn = fmaxf((h - m) * rsqrtf(var + 1e-5f) * gamv + betv, 0.0f);
      float dot = blockSum192(hn * w2v, red);
      float gate = 1.0f / (1.0f + expf(-(dot + b2v)));
      for (int d = tid; d < ND; d += NDG) {
        gatedA[(((size_t)b * NG + gg) * NL + l0 + lp) * ND + d] =
            __float2bfloat16(xr[lp][gg][d] * gate + gl[lp][d] * (1.0f - gate));
      }
    }
  }
}

// ---------------------------------------------------------------- conv as bf16 MFMA GEMM
#define BKC 64
__global__ __launch_bounds__(256) void k_conv_mfma(
    const __hip_bfloat16* __restrict__ Abuf,
    const __hip_bfloat16* __restrict__ Wt2,
    const float* __restrict__ cb,
    float* __restrict__ outp) {
  int bid = blockIdx.x;
  int ct = bid % 3; int rest = bid / 3;
  int rt = rest % 8; int bg = rest / 8;
  int b = bg / NG, gg = bg % NG;
  int l0 = rt * 128;
  int n0 = ct * 128;
  int tid = threadIdx.x;
  int lane = tid & 63, wid = tid >> 6;
  int wr = wid >> 1, wc = wid & 1;
  int r15 = lane & 15, kc = lane >> 4;

  __shared__ short As[128 * BKC];
  __shared__ short Bs[128 * BKC];

  f32x4 acc[4][4];
#pragma unroll
  for (int m = 0; m < 4; m++)
#pragma unroll
    for (int n = 0; n < 4; n++) acc[m][n] = (f32x4){0.f, 0.f, 0.f, 0.f};

  for (int kh = 0; kh < 3; kh++) {
    int gs = gg + kh - 1;
    if (gs < 0 || gs >= NG) continue;
    const __hip_bfloat16* Ag = Abuf + (((size_t)b * NG + gs) * NL + l0) * ND;
    const __hip_bfloat16* Bg = Wt2 + ((size_t)kh * 384 + n0) * 384;
    for (int k0 = 0; k0 < 384; k0 += BKC) {
      __syncthreads();
#pragma unroll
      for (int p = 0; p < 4; p++) {
        int idx = p * 256 + tid;
        int row = idx >> 3, c = idx & 7;
        int csrc = c ^ (row & 7);
        __builtin_amdgcn_global_load_lds(
            (const __attribute__((address_space(1))) void*)(Ag + (size_t)row * ND + k0 + csrc * 8),
            (__attribute__((address_space(3))) void*)(&As[idx * 8]), 16, 0, 0);
      }
#pragma unroll
      for (int p = 0; p < 4; p++) {
        int idx = p * 256 + tid;
        int row = idx >> 3, c = idx & 7;
        int csrc = c ^ (row & 7);
        __builtin_amdgcn_global_load_lds(
            (const __attribute__((address_space(1))) void*)(Bg + (size_t)row * 384 + k0 + csrc * 8),
            (__attribute__((address_space(3))) void*)(&Bs[idx * 8]), 16, 0, 0);
      }
      __syncthreads();
#pragma unroll
      for (int ks = 0; ks < 2; ks++) {
        short8n af[4], bfr[4];
        int cdata = ks * 4 + kc;
#pragma unroll
        for (int m = 0; m < 4; m++) {
          int row = wr * 64 + m * 16 + r15;
          af[m] = *reinterpret_cast<const short8n*>(&As[row * 64 + (cdata ^ (row & 7)) * 8]);
          int col = wc * 64 + m * 16 + r15;
          bfr[m] = *reinterpret_cast<const short8n*>(&Bs[col * 64 + (cdata ^ (col & 7)) * 8]);
        }
#pragma unroll
        for (int m = 0; m < 4; m++)
#pragma unroll
          for (int n = 0; n < 4; n++)
            acc[m][n] = __builtin_amdgcn_mfma_f32_16x16x32_bf16(af[m], bfr[n], acc[m][n], 0, 0, 0);
      }
    }
  }
  float cbv[4];
#pragma unroll
  for (int n = 0; n < 4; n++) cbv[n] = cb[n0 + wc * 64 + n * 16 + r15];
  size_t orow = (size_t)b * SEQR + 1 + (size_t)gg * NL + l0 + wr * 64;
#pragma unroll
  for (int m = 0; m < 4; m++) {
#pragma unroll
    for (int j = 0; j < 4; j++) {
      size_t grow = orow + m * 16 + kc * 4 + j;
#pragma unroll
      for (int n = 0; n < 4; n++) {
        outp[grow * ND + n0 + wc * 64 + n * 16 + r15] = acc[m][n][j] + cbv[n];
      }
    }
  }
}

// ---------------------------------------------------------------- FFT / IFFT
template <int INV>
__global__ __launch_bounds__(256) void k_fft_t(const float* __restrict__ twid,
                                               float* reb, float* imb) {
  int bid = blockIdx.x;
  int b = bid / 288; int r = bid % 288; int gg = r / 96; int d0 = (r % 96) * 4;
  int tid = threadIdx.x;
  __shared__ float sre[4][1028];
  __shared__ float sim[4][1028];
  size_t baseR = ((size_t)b * SEQR + 1 + (size_t)gg * NL) * ND + d0;
  size_t baseI = (((size_t)b * NG + gg) * NL) * ND + d0;
  for (int idx = tid; idx < 4096; idx += 256) {
    int dd = idx & 3; int l = idx >> 2;
    int rv = (int)(__brev((unsigned)l) >> 22);
    sre[dd][rv] = reb[baseR + (size_t)l * ND + dd];
    sim[dd][rv] = INV ? imb[baseI + (size_t)l * ND + dd] : 0.0f;
  }
  __syncthreads();
  for (int s = 0; s < 10; s++) {
    int m = 1 << s;
    for (int bt = tid; bt < 2048; bt += 256) {
      int line = bt >> 9; int j = bt & 511;
      int jj = j & (m - 1); int grp = j >> s;
      int p0 = (grp << (s + 1)) + jj; int p1 = p0 + m;
      int ti = jj << (9 - s);
      float twr = twid[2 * ti];
      float twi = twid[2 * ti + 1];
      if (INV) twi = -twi;
      float re1 = sre[line][p1], im1 = sim[line][p1];
      float tr = re1 * twr - im1 * twi;
      float tq = re1 * twi + im1 * twr;
      float re0 = sre[line][p0], im0 = sim[line][p0];
      sre[line][p1] = re0 - tr; sim[line][p1] = im0 - tq;
      sre[line][p0] = re0 + tr; sim[line][p0] = im0 + tq;
    }
    __syncthreads();
  }
  if (INV) {
    const float sc = 1.0f / 1024.0f;
    for (int idx = tid; idx < 4096; idx += 256) {
      int dd = idx & 3; int k = idx >> 2;
      reb[baseR + (size_t)k * ND + dd] = sre[dd][k] * sc;
    }
  } else {
    for (int idx = tid; idx < 4096; idx += 256) {
      int dd = idx & 3; int k = idx >> 2;
      reb[baseR + (size_t)k * ND + dd] = sre[dd][k];
      imb[baseI + (size_t)k * ND + dd] = sim[dd][k];
    }
  }
}

// ---------------------------------------------------------------- band MLP
__global__ __launch_bounds__(96) void k_bd(const float* __restrict__ outp,
    const float* __restrict__ W1, const float* __restrict__ b1,
    const float* __restrict__ gam, const float* __restrict__ bet,
    const float* __restrict__ W2, const float* __restrict__ b2,
    float* __restrict__ bwout) {
  int bid = blockIdx.x;
  int b = bid / NG, gg = bid % NG;
  int tid = threadIdx.x;
  __shared__ float xm[ND];
  __shared__ float hs[NH];
  __shared__ float o3[3];
  size_t dcrow = ((size_t)b * SEQR + 1 + (size_t)gg * NL) * ND;
  for (int i = tid; i < ND; i += NH) xm[i] = outp[dcrow + i] * (1.0f / NL);
  __syncthreads();
  float acc = b1[tid];
  for (int i = 0; i < ND; i++) acc += xm[i] * W1[i * NH + tid];
  hs[tid] = acc;
  __syncthreads();
  float s = 0, sq = 0;
  for (int i = 0; i < NH; i++) { float v = hs[i]; s += v; sq += v * v; }
  float m = s * (1.0f / NH), var = sq * (1.0f / NH) - m * m;
  float hn = fmaxf((acc - m) * rsqrtf(var + 1e-5f) * gam[tid] + bet[tid], 0.0f);
  __syncthreads();
  hs[tid] = hn;
  __syncthreads();
  if (tid < 3) {
    float o = b2[tid];
    for (int k = 0; k < NH; k++) o += hs[k] * W2[k * 3 + tid];
    o3[tid] = o;
  }
  __syncthreads();
  if (tid < 3) {
    float mx = fmaxf(o3[0], fmaxf(o3[1], o3[2]));
    float ssum = expf(o3[0] - mx) + expf(o3[1] - mx) + expf(o3[2] - mx);
    bwout[bid * 3 + tid] = expf(o3[tid] - mx) / ssum;
  }
}

// ---------------------------------------------------------------- mag/phase MLPs via MFMA + modulate
// block = 64 FFT rows of one (b,g); 256 thr = 4 waves x 16 rows.
#define AROW 64
#define APAD 392   // bf16 elems per LDS row (384 + 8): 2-way bank aliasing only
#define HPAD 104
__global__ __launch_bounds__(256) void k_att2(
    float* __restrict__ rebuf, float* __restrict__ imbuf,
    const __hip_bfloat16* __restrict__ W1A,   // [2][12][6][64][8]
    const __hip_bfloat16* __restrict__ W2A,   // [2][3][24][64][8]
    const float* __restrict__ mgb1, const float* __restrict__ mgg,
    const float* __restrict__ mgbe, const float* __restrict__ mgb2,
    const float* __restrict__ phb1, const float* __restrict__ phg,
    const float* __restrict__ phbe, const float* __restrict__ phb2,
    const float* __restrict__ bwp) {
  int bid = blockIdx.x;
  int bg = bid >> 4; int tile = bid & 15;
  int b = bg / NG, gg = bg % NG;
  int l0 = tile * AROW;
  int tid = threadIdx.x;
  int lane = tid & 63, wid = tid >> 6;
  int r15 = lane & 15, kc = lane >> 4;
  int wl0 = wid * 16;                 // wave's l-offset inside tile

  __shared__ short Am[AROW * APAD];
  __shared__ short Ap[AROW * APAD];
  __shared__ short ht0[AROW * HPAD];  // mag-branch hidden (post-LN-relu, bf16)
  __shared__ short ht1[AROW * HPAD];
  __shared__ float s_b1[2][NH], s_g[2][NH], s_be[2][NH];
  __shared__ float s_b2[2][ND];

  size_t rbase = ((size_t)b * SEQR + 1 + (size_t)gg * NL + l0) * ND;
  size_t ibase = (((size_t)b * NG + gg) * NL + l0) * ND;

  // ---- param staging
  if (tid < NH) {
    s_b1[0][tid] = mgb1[tid]; s_b1[1][tid] = phb1[tid];
    s_g[0][tid]  = mgg[tid];  s_g[1][tid]  = phg[tid];
    s_be[0][tid] = mgbe[tid]; s_be[1][tid] = phbe[tid];
  }
  for (int i = tid; i < ND; i += 256) { s_b2[0][i] = mgb2[i]; s_b2[1][i] = phb2[i]; }

  // ---- stage 1: re/im -> mag/phase bf16 in LDS
  for (int i = tid; i < AROW * 96; i += 256) {
    int l = i / 96, c = (i % 96) * 4;
    float4 re = *reinterpret_cast<const float4*>(&rebuf[rbase + (size_t)l * ND + c]);
    float4 im = *reinterpret_cast<const float4*>(&imbuf[ibase + (size_t)l * ND + c]);
    short4n mq, pq;
    mq.x = bfx(sqrtf(re.x * re.x + im.x * im.x));
    mq.y = bfx(sqrtf(re.y * re.y + im.y * im.y));
    mq.z = bfx(sqrtf(re.z * re.z + im.z * im.z));
    mq.w = bfx(sqrtf(re.w * re.w + im.w * im.w));
    pq.x = bfx(fast_atan2f(im.x, re.x));
    pq.y = bfx(fast_atan2f(im.y, re.y));
    pq.z = bfx(fast_atan2f(im.z, re.z));
    pq.w = bfx(fast_atan2f(im.w, re.w));
    *reinterpret_cast<short4n*>(&Am[l * APAD + c]) = mq;
    *reinterpret_cast<short4n*>(&Ap[l * APAD + c]) = pq;
  }
  __syncthreads();

  // ---- GEMM1 (both branches): h[96 x 16l] = W1^T x A^T, + bias, LN, relu -> ht
#pragma unroll
  for (int br = 0; br < 2; br++) {
    const short* Abuf = br ? Ap : Am;
    short* htb = br ? ht1 : ht0;
    const __hip_bfloat16* W1b = W1A + (size_t)br * 36864;
    f32x4 hacc[6];
#pragma unroll
    for (int f = 0; f < 6; f++) {
#pragma unroll
      for (int j = 0; j < 4; j++) hacc[f][j] = s_b1[br][f * 16 + kc * 4 + j];
    }
    for (int kk = 0; kk < 12; kk++) {
      short8n bx = *reinterpret_cast<const short8n*>(&Abuf[(wl0 + r15) * APAD + kk * 32 + kc * 8]);
#pragma unroll
      for (int f = 0; f < 6; f++) {
        short8n aw = *reinterpret_cast<const short8n*>(
            (const void*)(W1b + (((size_t)kk * 6 + f) * 64 + lane) * 8));
        hacc[f] = __builtin_amdgcn_mfma_f32_16x16x32_bf16(aw, bx, hacc[f], 0, 0, 0);
      }
    }
    // LN over hidden (96) for this lane's column l = wl0 + r15
    float s = 0.f, sq = 0.f;
#pragma unroll
    for (int f = 0; f < 6; f++)
#pragma unroll
      for (int j = 0; j < 4; j++) { float v = hacc[f][j]; s += v; sq += v * v; }
    s += __shfl_xor(s, 16, 64); s += __shfl_xor(s, 32, 64);
    sq += __shfl_xor(sq, 16, 64); sq += __shfl_xor(sq, 32, 64);
    float mean = s * (1.0f / NH);
    float var = sq * (1.0f / NH) - mean * mean;
    float rstd = rsqrtf(var + 1e-5f);
#pragma unroll
    for (int f = 0; f < 6; f++) {
      short4n hq;
#pragma unroll
      for (int j = 0; j < 4; j++) {
        int m = f * 16 + kc * 4 + j;
        float hn = fmaxf((hacc[f][j] - mean) * rstd * s_g[br][m] + s_be[br][m], 0.0f);
        ((short*)&hq)[j] = bfx(hn);
      }
      *reinterpret_cast<short4n*>(&htb[(wl0 + r15) * HPAD + f * 16 + kc * 4]) = hq;
    }
  }
  __syncthreads();

  // ---- GEMM2 (both branches) + fused modulation epilogue, 4 chunks of 96 d
  int lloc = wl0 + r15;               // row within tile
  int kbin = l0 + lloc;               // FFT bin index
  int fr = (kbin <= 512) ? kbin : (1024 - kbin);
  int bwb = (b * NG + gg) * 3;
  float wmv = (fr <= 128) ? bwp[bwb] : ((fr <= 256) ? bwp[bwb + 1] : bwp[bwb + 2]);

  short8n bhm[3], bhp[3];
#pragma unroll
  for (int kk = 0; kk < 3; kk++) {
    bhm[kk] = *reinterpret_cast<const short8n*>(&ht0[lloc * HPAD + kk * 32 + kc * 8]);
    bhp[kk] = *reinterpret_cast<const short8n*>(&ht1[lloc * HPAD + kk * 32 + kc * 8]);
  }

#pragma unroll
  for (int chunk = 0; chunk < 4; chunk++) {
    f32x4 aM[6], aP[6];
#pragma unroll
    for (int f = 0; f < 6; f++) {
      int dbase = (chunk * 6 + f) * 16 + kc * 4;
#pragma unroll
      for (int j = 0; j < 4; j++) {
        aM[f][j] = s_b2[0][dbase + j];
        aP[f][j] = s_b2[1][dbase + j];
      }
    }
#pragma unroll
    for (int kk = 0; kk < 3; kk++) {
#pragma unroll
      for (int f = 0; f < 6; f++) {
        int fg = chunk * 6 + f;
        short8n awm = *reinterpret_cast<const short8n*>(
            (const void*)(W2A + (((size_t)kk * 24 + fg) * 64 + lane) * 8));
        short8n awp = *reinterpret_cast<const short8n*>(
            (const void*)(W2A + 36864 + (((size_t)kk * 24 + fg) * 64 + lane) * 8));
        aM[f] = __builtin_amdgcn_mfma_f32_16x16x32_bf16(awm, bhm[kk], aM[f], 0, 0, 0);
        aP[f] = __builtin_amdgcn_mfma_f32_16x16x32_bf16(awp, bhp[kk], aP[f], 0, 0, 0);
      }
    }
    // epilogue: recompute fp32 mag/phase from untouched re/im, modulate, store
#pragma unroll
    for (int f = 0; f < 6; f++) {
      int d0 = (chunk * 6 + f) * 16 + kc * 4;
      size_t ra = rbase + (size_t)lloc * ND + d0;
      size_t ia = ibase + (size_t)lloc * ND + d0;
      float4 re = *reinterpret_cast<const float4*>(&rebuf[ra]);
      float4 im = *reinterpret_cast<const float4*>(&imbuf[ia]);
      float rr[4] = {re.x, re.y, re.z, re.w};
      float ii[4] = {im.x, im.y, im.z, im.w};
      float4 ro, io;
#pragma unroll
      for (int j = 0; j < 4; j++) {
        float mag = sqrtf(rr[j] * rr[j] + ii[j] * ii[j]);
        float ph = fast_atan2f(ii[j], rr[j]);
        float ma = fast_sigmoid(aM[f][j]);
        float pa = fast_tanh(aP[f][j]);
        float mago = mag * wmv * ma;
        float pho = ph * wmv + pa;
        float cs = __cosf(pho), sn = __sinf(pho);
        ((float*)&ro)[j] = mago * cs;
        ((float*)&io)[j] = mago * sn;
      }
      *reinterpret_cast<float4*>(&rebuf[ra]) = ro;
      *reinterpret_cast<float4*>(&imbuf[ia]) = io;
    }
  }
}

// ---------------------------------------------------------------- launch
extern "C" void kernel_launch(void* const* d_in, const int* in_sizes, int n_in,
                              void* d_out, int out_size, void* d_ws, size_t ws_size,
                              hipStream_t stream) {
  (void)in_sizes; (void)n_in; (void)out_size; (void)ws_size;
  const float* x     = (const float*)d_in[0];
  const float* mgW1  = (const float*)d_in[1];
  const float* mgb1  = (const float*)d_in[2];
  const float* mgg   = (const float*)d_in[3];
  const float* mgbe  = (const float*)d_in[4];
  const float* mgW2  = (const float*)d_in[5];
  const float* mgb2  = (const float*)d_in[6];
  const float* phW1  = (const float*)d_in[7];
  const float* phb1  = (const float*)d_in[8];
  const float* phg   = (const float*)d_in[9];
  const float* phbe  = (const float*)d_in[10];
  const float* phW2  = (const float*)d_in[11];
  const float* phb2  = (const float*)d_in[12];
  const float* bdW1  = (const float*)d_in[13];
  const float* bdb1  = (const float*)d_in[14];
  const float* bdg   = (const float*)d_in[15];
  const float* bdbe  = (const float*)d_in[16];
  const float* bdW2  = (const float*)d_in[17];
  const float* bdb2  = (const float*)d_in[18];
  const float* cgW1  = (const float*)d_in[19];
  const float* cgb1  = (const float*)d_in[20];
  const float* cgg   = (const float*)d_in[21];
  const float* cgbe  = (const float*)d_in[22];
  const float* cgW2  = (const float*)d_in[23];
  const float* cgb2  = (const float*)d_in[24];
  const float* convW = (const float*)d_in[25];
  const float* convB = (const float*)d_in[26];

  float* outp = (float*)d_out;
  float* wsf  = (float*)d_ws;
  // region0: gated activations (bf16) then FFT imag (fp32) — disjoint lifetimes
  float* bufA = wsf;
  __hip_bfloat16* gatedA = (__hip_bfloat16*)wsf;
  char* p = (char*)(wsf + (size_t)NB * NG * NL * ND);
  __hip_bfloat16* Wt2 = (__hip_bfloat16*)p;           p += (size_t)384 * 384 * 3 * 2;
  float* twid = (float*)p;                            p += 1024 * 4;
  float* bwp  = (float*)p;                            p += 512 * 4;   // 288 used, pad to 16B
  __hip_bfloat16* W1A = (__hip_bfloat16*)p;           p += (size_t)2 * 36864 * 2;
  __hip_bfloat16* W2A = (__hip_bfloat16*)p;           p += (size_t)2 * 36864 * 2;

  k_prep<<<dim3(2354), dim3(256), 0, stream>>>(convW, x, mgW1, phW1, mgW2, phW2,
                                               Wt2, twid, W1A, W2A, outp);
  k_gate<<<dim3(NB * 512), dim3(192), 0, stream>>>(x, cgW1, cgb1, cgg, cgbe, cgW2, cgb2, gatedA);
  k_conv_mfma<<<dim3(NB * NG * 8 * 3), dim3(256), 0, stream>>>(gatedA, Wt2, convB, outp);
  k_fft_t<0><<<dim3(NB * NG * 96), dim3(256), 0, stream>>>(twid, outp, bufA);
  k_bd<<<dim3(NB * NG), dim3(96), 0, stream>>>(outp, bdW1, bdb1, bdg, bdbe, bdW2, bdb2, bwp);
  k_att2<<<dim3(NB * NG * 16), dim3(256), 0, stream>>>(outp, bufA,
      W1A, W2A, mgb1, mgg, mgbe, mgb2, phb1, phg, phbe, phb2, bwp);
  k_fft_t<1><<<dim3(NB * NG * 96), dim3(256), 0, stream>>>(twid, outp, bufA);
}

// Round 4
// 1589.252 us; speedup vs baseline: 2.5288x; 1.3686x over previous
//
#include <hip/hip_runtime.h>
#include <hip/hip_bf16.h>
#include <math.h>

#define NB 32
#define NL 1024
#define NG 3
#define ND 384
#define NH 96
#define NDG 192
#define SEQR 3073   // 1 + G*L

typedef __attribute__((ext_vector_type(8))) short short8n;
typedef __attribute__((ext_vector_type(4))) short short4n;
typedef __attribute__((ext_vector_type(4))) float f32x4;

__device__ __forceinline__ short bfx(float f) {
  __hip_bfloat16 h = __float2bfloat16(f);
  return *reinterpret_cast<short*>(&h);
}
__device__ __forceinline__ float xbf(short s) {
  __hip_bfloat16 h = *reinterpret_cast<__hip_bfloat16*>(&s);
  return __bfloat162float(h);
}

// fast atan2, abs err <= ~1e-5 rad
__device__ __forceinline__ float fast_atan2f(float y, float x) {
  float ax = fabsf(x), ay = fabsf(y);
  float mx = fmaxf(ax, ay), mn = fminf(ax, ay);
  float r = (mx == 0.0f) ? 0.0f : __fdividef(mn, mx);
  float s = r * r;
  float p = fmaf(s, 0.0208351f, -0.0851330f);
  p = fmaf(s, p, 0.1801410f);
  p = fmaf(s, p, -0.3302995f);
  p = fmaf(s, p, 0.9998660f);
  p = r * p;
  float a = (ay > ax) ? (1.5707963267948966f - p) : p;
  a = (x < 0.0f) ? (3.14159265358979323846f - a) : a;
  return (y < 0.0f) ? -a : a;
}

__device__ __forceinline__ float fast_sigmoid(float x) {
  return __fdividef(1.0f, 1.0f + __expf(-x));
}
__device__ __forceinline__ float fast_tanh(float x) {
  return 1.0f - __fdividef(2.0f, 1.0f + __expf(2.0f * x));
}

// ---------------------------------------------------------------- prep
// Wt2[kh][o][i] bf16; twiddles; cls copy; W1A/W2A/W1G MFMA-frag-packed bf16
__global__ __launch_bounds__(256) void k_prep(const float* __restrict__ convW,
                                              const float* __restrict__ x,
                                              const float* __restrict__ mgW1s,
                                              const float* __restrict__ phW1s,
                                              const float* __restrict__ mgW2s,
                                              const float* __restrict__ phW2s,
                                              const float* __restrict__ cgW1s,
                                              __hip_bfloat16* __restrict__ Wt2,
                                              float* __restrict__ twid,
                                              __hip_bfloat16* __restrict__ W1Ao,
                                              __hip_bfloat16* __restrict__ W2Ao,
                                              __hip_bfloat16* __restrict__ W1Go,
                                              float* __restrict__ outp) {
  int id = blockIdx.x * 256 + threadIdx.x;
  if (id < 384 * 384 * 3) {
    int i = id % 384; int rest = id / 384; int o = rest % 384; int kh = rest / 384;
    Wt2[id] = __float2bfloat16(convW[(o * 384 + i) * 3 + kh]);
    return;
  }
  int id2 = id - 384 * 384 * 3;
  if (id2 < 512) {
    float ang = -6.283185307179586f * (float)id2 / 1024.0f;
    float s, c; sincosf(ang, &s, &c);
    twid[2 * id2] = c; twid[2 * id2 + 1] = s;
    return;
  }
  int id3 = id2 - 512;
  if (id3 < NB * ND) {
    int b = id3 / ND, d = id3 % ND;
    outp[(size_t)b * SEQR * ND + d] = x[(size_t)b * SEQR * ND + d];
    return;
  }
  int id4 = id3 - NB * ND;
  if (id4 < 2 * 36864) {   // W1A: [br][kk(12)][f(6)][lane(64)][8]
    int br = id4 / 36864, idx = id4 % 36864;
    int j = idx & 7, ln = (idx >> 3) & 63, rest = idx >> 9;
    int f = rest % 6, kk = rest / 6;
    int m = f * 16 + (ln & 15), k = kk * 32 + (ln >> 4) * 8 + j;
    const float* W = br ? phW1s : mgW1s;
    W1Ao[id4] = __float2bfloat16(W[k * NH + m]);
    return;
  }
  int id5 = id4 - 2 * 36864;
  if (id5 < 2 * 36864) {   // W2A: [br][kk(3)][f(24)][lane(64)][8]
    int br = id5 / 36864, idx = id5 % 36864;
    int j = idx & 7, ln = (idx >> 3) & 63, rest = idx >> 9;
    int f = rest % 24, kk = rest / 24;
    int d = f * 16 + (ln & 15), k = kk * 32 + (ln >> 4) * 8 + j;
    const float* W = br ? phW2s : mgW2s;
    W2Ao[id5] = __float2bfloat16(W[k * ND + d]);
    return;
  }
  int id6 = id5 - 2 * 36864;
  if (id6 < 147456) {      // W1G: [part(2)][kk(12)][f(12)][lane(64)][8]
    int j = id6 & 7, ln = (id6 >> 3) & 63, rest = id6 >> 9;
    int f = rest % 12, rest2 = rest / 12;
    int kk = rest2 % 12, part = rest2 / 12;
    int m = f * 16 + (ln & 15), k = part * 384 + kk * 32 + (ln >> 4) * 8 + j;
    W1Go[id6] = __float2bfloat16(cgW1s[k * NDG + m]);
  }
}

// ---------------------------------------------------------------- gate MLP via MFMA
// block = (b, 16 l); waves 0-2: xg.W1[0:384] for group g=wid; wave 3: glob.W1[384:768]
__global__ __launch_bounds__(256) void k_gate2(const float* __restrict__ x,
    const __hip_bfloat16* __restrict__ W1G,
    const float* __restrict__ b1, const float* __restrict__ gam,
    const float* __restrict__ bet, const float* __restrict__ W2,
    const float* __restrict__ b2p,
    __hip_bfloat16* __restrict__ gatedA) {
  int bid = blockIdx.x;
  int b = bid >> 6; int l0 = (bid & 63) * 16;
  int tid = threadIdx.x;
  int lane = tid & 63, wid = tid >> 6;
  int r15 = lane & 15, kc = lane >> 4;

  __shared__ short xs[3][16][392];
  __shared__ short gs[16][392];
  __shared__ float hG[16][196];
  __shared__ float s_b1[NDG], s_g[NDG], s_be[NDG], s_w2[NDG];
  __shared__ float sgate[3][16];

  if (tid < NDG) {
    s_b1[tid] = b1[tid]; s_g[tid] = gam[tid];
    s_be[tid] = bet[tid]; s_w2[tid] = W2[tid];
  }
  // stage: fp32 loads -> bf16 xs + fp32-mean glob -> bf16 gs
  for (int c = tid; c < 16 * 96; c += 256) {
    int l = c / 96, d4 = (c % 96) * 4;
    size_t base = ((size_t)b * SEQR + 1 + l0 + l) * ND + d4;
    float4 v0 = *reinterpret_cast<const float4*>(&x[base]);
    float4 v1 = *reinterpret_cast<const float4*>(&x[base + (size_t)NL * ND]);
    float4 v2 = *reinterpret_cast<const float4*>(&x[base + (size_t)2 * NL * ND]);
    short4n q0, q1, q2, qg;
    q0.x = bfx(v0.x); q0.y = bfx(v0.y); q0.z = bfx(v0.z); q0.w = bfx(v0.w);
    q1.x = bfx(v1.x); q1.y = bfx(v1.y); q1.z = bfx(v1.z); q1.w = bfx(v1.w);
    q2.x = bfx(v2.x); q2.y = bfx(v2.y); q2.z = bfx(v2.z); q2.w = bfx(v2.w);
    qg.x = bfx((v0.x + v1.x + v2.x) * (1.0f / 3.0f));
    qg.y = bfx((v0.y + v1.y + v2.y) * (1.0f / 3.0f));
    qg.z = bfx((v0.z + v1.z + v2.z) * (1.0f / 3.0f));
    qg.w = bfx((v0.w + v1.w + v2.w) * (1.0f / 3.0f));
    *reinterpret_cast<short4n*>(&xs[0][l][d4]) = q0;
    *reinterpret_cast<short4n*>(&xs[1][l][d4]) = q1;
    *reinterpret_cast<short4n*>(&xs[2][l][d4]) = q2;
    *reinterpret_cast<short4n*>(&gs[l][d4]) = qg;
  }
  __syncthreads();

  // GEMM: hidden[192] x 16 cols; col = lane&15 -> l
  const short* bsrc = (wid == 3) ? &gs[0][0] : &xs[wid][0][0];
  const __hip_bfloat16* W1b = W1G + (size_t)(wid == 3 ? 1 : 0) * 73728;
  f32x4 hacc[12];
#pragma unroll
  for (int f = 0; f < 12; f++)
#pragma unroll
    for (int j = 0; j < 4; j++)
      hacc[f][j] = (wid == 3) ? 0.0f : s_b1[f * 16 + kc * 4 + j];
  for (int kk = 0; kk < 12; kk++) {
    short8n bx = *reinterpret_cast<const short8n*>(&bsrc[r15 * 392 + kk * 32 + kc * 8]);
#pragma unroll
    for (int f = 0; f < 12; f++) {
      short8n aw = *reinterpret_cast<const short8n*>(
          (const void*)(W1b + (((size_t)kk * 12 + f) * 64 + lane) * 8));
      hacc[f] = __builtin_amdgcn_mfma_f32_16x16x32_bf16(aw, bx, hacc[f], 0, 0, 0);
    }
  }
  if (wid == 3) {
#pragma unroll
    for (int f = 0; f < 12; f++)
#pragma unroll
      for (int j = 0; j < 4; j++)
        hG[r15][f * 16 + kc * 4 + j] = hacc[f][j];
  }
  __syncthreads();
  if (wid < 3) {
    float s = 0.f, sq = 0.f;
#pragma unroll
    for (int f = 0; f < 12; f++)
#pragma unroll
      for (int j = 0; j < 4; j++) {
        float v = hacc[f][j] + hG[r15][f * 16 + kc * 4 + j];
        hacc[f][j] = v; s += v; sq += v * v;
      }
    s += __shfl_xor(s, 16, 64); s += __shfl_xor(s, 32, 64);
    sq += __shfl_xor(sq, 16, 64); sq += __shfl_xor(sq, 32, 64);
    float mean = s * (1.0f / NDG);
    float var = sq * (1.0f / NDG) - mean * mean;
    float rstd = rsqrtf(var + 1e-5f);
    float dot = 0.f;
#pragma unroll
    for (int f = 0; f < 12; f++)
#pragma unroll
      for (int j = 0; j < 4; j++) {
        int m = f * 16 + kc * 4 + j;
        float hn = fmaxf((hacc[f][j] - mean) * rstd * s_g[m] + s_be[m], 0.0f);
        dot += hn * s_w2[m];
      }
    dot += __shfl_xor(dot, 16, 64); dot += __shfl_xor(dot, 32, 64);
    float gate = fast_sigmoid(dot + b2p[0]);
    if (lane < 16) sgate[wid][r15] = gate;
  }
  __syncthreads();
  if (wid < 3) {
    size_t obase = (((size_t)b * NG + wid) * NL + l0) * ND;
    for (int c = lane; c < 16 * 96; c += 64) {
      int l = c / 96, d4 = (c % 96) * 4;
      float gt = sgate[wid][l];
      short4n qx = *reinterpret_cast<const short4n*>(&xs[wid][l][d4]);
      short4n qg = *reinterpret_cast<const short4n*>(&gs[l][d4]);
      short4n qo;
#pragma unroll
      for (int j = 0; j < 4; j++) {
        float xv = xbf(((short*)&qx)[j]);
        float gv = xbf(((short*)&qg)[j]);
        ((short*)&qo)[j] = bfx(xv * gt + gv * (1.0f - gt));
      }
      *reinterpret_cast<short4n*>(&((short*)gatedA)[obase + (size_t)l * ND + d4]) = qo;
    }
  }
}

// ---------------------------------------------------------------- conv as bf16 MFMA GEMM
#define BKC 64
__global__ __launch_bounds__(256) void k_conv_mfma(
    const __hip_bfloat16* __restrict__ Abuf,
    const __hip_bfloat16* __restrict__ Wt2,
    const float* __restrict__ cb,
    float* __restrict__ outp) {
  int bid = blockIdx.x;
  int ct = bid % 3; int rest = bid / 3;
  int rt = rest % 8; int bg = rest / 8;
  int b = bg / NG, gg = bg % NG;
  int l0 = rt * 128;
  int n0 = ct * 128;
  int tid = threadIdx.x;
  int lane = tid & 63, wid = tid >> 6;
  int wr = wid >> 1, wc = wid & 1;
  int r15 = lane & 15, kc = lane >> 4;

  __shared__ short As[128 * BKC];
  __shared__ short Bs[128 * BKC];

  f32x4 acc[4][4];
#pragma unroll
  for (int m = 0; m < 4; m++)
#pragma unroll
    for (int n = 0; n < 4; n++) acc[m][n] = (f32x4){0.f, 0.f, 0.f, 0.f};

  for (int kh = 0; kh < 3; kh++) {
    int gs = gg + kh - 1;
    if (gs < 0 || gs >= NG) continue;
    const __hip_bfloat16* Ag = Abuf + (((size_t)b * NG + gs) * NL + l0) * ND;
    const __hip_bfloat16* Bg = Wt2 + ((size_t)kh * 384 + n0) * 384;
    for (int k0 = 0; k0 < 384; k0 += BKC) {
      __syncthreads();
#pragma unroll
      for (int p = 0; p < 4; p++) {
        int idx = p * 256 + tid;
        int row = idx >> 3, c = idx & 7;
        int csrc = c ^ (row & 7);
        __builtin_amdgcn_global_load_lds(
            (const __attribute__((address_space(1))) void*)(Ag + (size_t)row * ND + k0 + csrc * 8),
            (__attribute__((address_space(3))) void*)(&As[idx * 8]), 16, 0, 0);
      }
#pragma unroll
      for (int p = 0; p < 4; p++) {
        int idx = p * 256 + tid;
        int row = idx >> 3, c = idx & 7;
        int csrc = c ^ (row & 7);
        __builtin_amdgcn_global_load_lds(
            (const __attribute__((address_space(1))) void*)(Bg + (size_t)row * 384 + k0 + csrc * 8),
            (__attribute__((address_space(3))) void*)(&Bs[idx * 8]), 16, 0, 0);
      }
      __syncthreads();
#pragma unroll
      for (int ks = 0; ks < 2; ks++) {
        short8n af[4], bfr[4];
        int cdata = ks * 4 + kc;
#pragma unroll
        for (int m = 0; m < 4; m++) {
          int row = wr * 64 + m * 16 + r15;
          af[m] = *reinterpret_cast<const short8n*>(&As[row * 64 + (cdata ^ (row & 7)) * 8]);
          int col = wc * 64 + m * 16 + r15;
          bfr[m] = *reinterpret_cast<const short8n*>(&Bs[col * 64 + (cdata ^ (col & 7)) * 8]);
        }
#pragma unroll
        for (int m = 0; m < 4; m++)
#pragma unroll
          for (int n = 0; n < 4; n++)
            acc[m][n] = __builtin_amdgcn_mfma_f32_16x16x32_bf16(af[m], bfr[n], acc[m][n], 0, 0, 0);
      }
    }
  }
  float cbv[4];
#pragma unroll
  for (int n = 0; n < 4; n++) cbv[n] = cb[n0 + wc * 64 + n * 16 + r15];
  size_t orow = (size_t)b * SEQR + 1 + (size_t)gg * NL + l0 + wr * 64;
#pragma unroll
  for (int m = 0; m < 4; m++) {
#pragma unroll
    for (int j = 0; j < 4; j++) {
      size_t grow = orow + m * 16 + kc * 4 + j;
#pragma unroll
      for (int n = 0; n < 4; n++) {
        outp[grow * ND + n0 + wc * 64 + n * 16 + r15] = acc[m][n][j] + cbv[n];
      }
    }
  }
}

// ---------------------------------------------------------------- FFT / IFFT
template <int INV>
__global__ __launch_bounds__(256) void k_fft_t(const float* __restrict__ twid,
                                               float* reb, float* imb) {
  int bid = blockIdx.x;
  int b = bid / 288; int r = bid % 288; int gg = r / 96; int d0 = (r % 96) * 4;
  int tid = threadIdx.x;
  __shared__ float sre[4][1028];
  __shared__ float sim[4][1028];
  size_t baseR = ((size_t)b * SEQR + 1 + (size_t)gg * NL) * ND + d0;
  size_t baseI = (((size_t)b * NG + gg) * NL) * ND + d0;
  for (int idx = tid; idx < 4096; idx += 256) {
    int dd = idx & 3; int l = idx >> 2;
    int rv = (int)(__brev((unsigned)l) >> 22);
    sre[dd][rv] = reb[baseR + (size_t)l * ND + dd];
    sim[dd][rv] = INV ? imb[baseI + (size_t)l * ND + dd] : 0.0f;
  }
  __syncthreads();
  for (int s = 0; s < 10; s++) {
    int m = 1 << s;
    for (int bt = tid; bt < 2048; bt += 256) {
      int line = bt >> 9; int j = bt & 511;
      int jj = j & (m - 1); int grp = j >> s;
      int p0 = (grp << (s + 1)) + jj; int p1 = p0 + m;
      int ti = jj << (9 - s);
      float twr = twid[2 * ti];
      float twi = twid[2 * ti + 1];
      if (INV) twi = -twi;
      float re1 = sre[line][p1], im1 = sim[line][p1];
      float tr = re1 * twr - im1 * twi;
      float tq = re1 * twi + im1 * twr;
      float re0 = sre[line][p0], im0 = sim[line][p0];
      sre[line][p1] = re0 - tr; sim[line][p1] = im0 - tq;
      sre[line][p0] = re0 + tr; sim[line][p0] = im0 + tq;
    }
    __syncthreads();
  }
  if (INV) {
    const float sc = 1.0f / 1024.0f;
    for (int idx = tid; idx < 4096; idx += 256) {
      int dd = idx & 3; int k = idx >> 2;
      reb[baseR + (size_t)k * ND + dd] = sre[dd][k] * sc;
    }
  } else {
    for (int idx = tid; idx < 4096; idx += 256) {
      int dd = idx & 3; int k = idx >> 2;
      reb[baseR + (size_t)k * ND + dd] = sre[dd][k];
      imb[baseI + (size_t)k * ND + dd] = sim[dd][k];
    }
  }
}

// ---------------------------------------------------------------- band MLP
__global__ __launch_bounds__(96) void k_bd(const float* __restrict__ outp,
    const float* __restrict__ W1, const float* __restrict__ b1,
    const float* __restrict__ gam, const float* __restrict__ bet,
    const float* __restrict__ W2, const float* __restrict__ b2,
    float* __restrict__ bwout) {
  int bid = blockIdx.x;
  int b = bid / NG, gg = bid % NG;
  int tid = threadIdx.x;
  __shared__ float xm[ND];
  __shared__ float hs[NH];
  __shared__ float o3[3];
  size_t dcrow = ((size_t)b * SEQR + 1 + (size_t)gg * NL) * ND;
  for (int i = tid; i < ND; i += NH) xm[i] = outp[dcrow + i] * (1.0f / NL);
  __syncthreads();
  float acc = b1[tid];
  for (int i = 0; i < ND; i++) acc += xm[i] * W1[i * NH + tid];
  hs[tid] = acc;
  __syncthreads();
  float s = 0, sq = 0;
  for (int i = 0; i < NH; i++) { float v = hs[i]; s += v; sq += v * v; }
  float m = s * (1.0f / NH), var = sq * (1.0f / NH) - m * m;
  float hn = fmaxf((acc - m) * rsqrtf(var + 1e-5f) * gam[tid] + bet[tid], 0.0f);
  __syncthreads();
  hs[tid] = hn;
  __syncthreads();
  if (tid < 3) {
    float o = b2[tid];
    for (int k = 0; k < NH; k++) o += hs[k] * W2[k * 3 + tid];
    o3[tid] = o;
  }
  __syncthreads();
  if (tid < 3) {
    float mx = fmaxf(o3[0], fmaxf(o3[1], o3[2]));
    float ssum = expf(o3[0] - mx) + expf(o3[1] - mx) + expf(o3[2] - mx);
    bwout[bid * 3 + tid] = expf(o3[tid] - mx) / ssum;
  }
}

// ---------------------------------------------------------------- mag/phase MLPs via MFMA + modulate
#define AROW 64
#define APAD 392
#define HPAD 104
__global__ __launch_bounds__(256) void k_att2(
    float* __restrict__ rebuf, float* __restrict__ imbuf,
    const __hip_bfloat16* __restrict__ W1A,   // [2][12][6][64][8]
    const __hip_bfloat16* __restrict__ W2A,   // [2][3][24][64][8]
    const float* __restrict__ mgb1, const float* __restrict__ mgg,
    const float* __restrict__ mgbe, const float* __restrict__ mgb2,
    const float* __restrict__ phb1, const float* __restrict__ phg,
    const float* __restrict__ phbe, const float* __restrict__ phb2,
    const float* __restrict__ bwp) {
  int bid = blockIdx.x;
  int bg = bid >> 4; int tile = bid & 15;
  int b = bg / NG, gg = bg % NG;
  int l0 = tile * AROW;
  int tid = threadIdx.x;
  int lane = tid & 63, wid = tid >> 6;
  int r15 = lane & 15, kc = lane >> 4;
  int wl0 = wid * 16;

  __shared__ short Am[AROW * APAD];
  __shared__ short Ap[AROW * APAD];
  __shared__ short ht0[AROW * HPAD];
  __shared__ short ht1[AROW * HPAD];
  __shared__ float s_b1[2][NH], s_g[2][NH], s_be[2][NH];
  __shared__ float s_b2[2][ND];

  size_t rbase = ((size_t)b * SEQR + 1 + (size_t)gg * NL + l0) * ND;
  size_t ibase = (((size_t)b * NG + gg) * NL + l0) * ND;

  if (tid < NH) {
    s_b1[0][tid] = mgb1[tid]; s_b1[1][tid] = phb1[tid];
    s_g[0][tid]  = mgg[tid];  s_g[1][tid]  = phg[tid];
    s_be[0][tid] = mgbe[tid]; s_be[1][tid] = phbe[tid];
  }
  for (int i = tid; i < ND; i += 256) { s_b2[0][i] = mgb2[i]; s_b2[1][i] = phb2[i]; }

  for (int i = tid; i < AROW * 96; i += 256) {
    int l = i / 96, c = (i % 96) * 4;
    float4 re = *reinterpret_cast<const float4*>(&rebuf[rbase + (size_t)l * ND + c]);
    float4 im = *reinterpret_cast<const float4*>(&imbuf[ibase + (size_t)l * ND + c]);
    short4n mq, pq;
    mq.x = bfx(sqrtf(re.x * re.x + im.x * im.x));
    mq.y = bfx(sqrtf(re.y * re.y + im.y * im.y));
    mq.z = bfx(sqrtf(re.z * re.z + im.z * im.z));
    mq.w = bfx(sqrtf(re.w * re.w + im.w * im.w));
    pq.x = bfx(fast_atan2f(im.x, re.x));
    pq.y = bfx(fast_atan2f(im.y, re.y));
    pq.z = bfx(fast_atan2f(im.z, re.z));
    pq.w = bfx(fast_atan2f(im.w, re.w));
    *reinterpret_cast<short4n*>(&Am[l * APAD + c]) = mq;
    *reinterpret_cast<short4n*>(&Ap[l * APAD + c]) = pq;
  }
  __syncthreads();

#pragma unroll
  for (int br = 0; br < 2; br++) {
    const short* Abuf = br ? Ap : Am;
    short* htb = br ? ht1 : ht0;
    const __hip_bfloat16* W1b = W1A + (size_t)br * 36864;
    f32x4 hacc[6];
#pragma unroll
    for (int f = 0; f < 6; f++) {
#pragma unroll
      for (int j = 0; j < 4; j++) hacc[f][j] = s_b1[br][f * 16 + kc * 4 + j];
    }
    for (int kk = 0; kk < 12; kk++) {
      short8n bx = *reinterpret_cast<const short8n*>(&Abuf[(wl0 + r15) * APAD + kk * 32 + kc * 8]);
#pragma unroll
      for (int f = 0; f < 6; f++) {
        short8n aw = *reinterpret_cast<const short8n*>(
            (const void*)(W1b + (((size_t)kk * 6 + f) * 64 + lane) * 8));
        hacc[f] = __builtin_amdgcn_mfma_f32_16x16x32_bf16(aw, bx, hacc[f], 0, 0, 0);
      }
    }
    float s = 0.f, sq = 0.f;
#pragma unroll
    for (int f = 0; f < 6; f++)
#pragma unroll
      for (int j = 0; j < 4; j++) { float v = hacc[f][j]; s += v; sq += v * v; }
    s += __shfl_xor(s, 16, 64); s += __shfl_xor(s, 32, 64);
    sq += __shfl_xor(sq, 16, 64); sq += __shfl_xor(sq, 32, 64);
    float mean = s * (1.0f / NH);
    float var = sq * (1.0f / NH) - mean * mean;
    float rstd = rsqrtf(var + 1e-5f);
#pragma unroll
    for (int f = 0; f < 6; f++) {
      short4n hq;
#pragma unroll
      for (int j = 0; j < 4; j++) {
        int m = f * 16 + kc * 4 + j;
        float hn = fmaxf((hacc[f][j] - mean) * rstd * s_g[br][m] + s_be[br][m], 0.0f);
        ((short*)&hq)[j] = bfx(hn);
      }
      *reinterpret_cast<short4n*>(&htb[(wl0 + r15) * HPAD + f * 16 + kc * 4]) = hq;
    }
  }
  __syncthreads();

  int lloc = wl0 + r15;
  int kbin = l0 + lloc;
  int fr = (kbin <= 512) ? kbin : (1024 - kbin);
  int bwb = (b * NG + gg) * 3;
  float wmv = (fr <= 128) ? bwp[bwb] : ((fr <= 256) ? bwp[bwb + 1] : bwp[bwb + 2]);

  short8n bhm[3], bhp[3];
#pragma unroll
  for (int kk = 0; kk < 3; kk++) {
    bhm[kk] = *reinterpret_cast<const short8n*>(&ht0[lloc * HPAD + kk * 32 + kc * 8]);
    bhp[kk] = *reinterpret_cast<const short8n*>(&ht1[lloc * HPAD + kk * 32 + kc * 8]);
  }

#pragma unroll
  for (int chunk = 0; chunk < 4; chunk++) {
    f32x4 aM[6], aP[6];
#pragma unroll
    for (int f = 0; f < 6; f++) {
      int dbase = (chunk * 6 + f) * 16 + kc * 4;
#pragma unroll
      for (int j = 0; j < 4; j++) {
        aM[f][j] = s_b2[0][dbase + j];
        aP[f][j] = s_b2[1][dbase + j];
      }
    }
#pragma unroll
    for (int kk = 0; kk < 3; kk++) {
#pragma unroll
      for (int f = 0; f < 6; f++) {
        int fg = chunk * 6 + f;
        short8n awm = *reinterpret_cast<const short8n*>(
            (const void*)(W2A + (((size_t)kk * 24 + fg) * 64 + lane) * 8));
        short8n awp = *reinterpret_cast<const short8n*>(
            (const void*)(W2A + 36864 + (((size_t)kk * 24 + fg) * 64 + lane) * 8));
        aM[f] = __builtin_amdgcn_mfma_f32_16x16x32_bf16(awm, bhm[kk], aM[f], 0, 0, 0);
        aP[f] = __builtin_amdgcn_mfma_f32_16x16x32_bf16(awp, bhp[kk], aP[f], 0, 0, 0);
      }
    }
#pragma unroll
    for (int f = 0; f < 6; f++) {
      int d0 = (chunk * 6 + f) * 16 + kc * 4;
      size_t ra = rbase + (size_t)lloc * ND + d0;
      size_t ia = ibase + (size_t)lloc * ND + d0;
      float4 re = *reinterpret_cast<const float4*>(&rebuf[ra]);
      float4 im = *reinterpret_cast<const float4*>(&imbuf[ia]);
      float rr[4] = {re.x, re.y, re.z, re.w};
      float ii[4] = {im.x, im.y, im.z, im.w};
      float4 ro, io;
#pragma unroll
      for (int j = 0; j < 4; j++) {
        float mag = sqrtf(rr[j] * rr[j] + ii[j] * ii[j]);
        float ph = fast_atan2f(ii[j], rr[j]);
        float ma = fast_sigmoid(aM[f][j]);
        float pa = fast_tanh(aP[f][j]);
        float mago = mag * wmv * ma;
        float pho = ph * wmv + pa;
        float cs = __cosf(pho), sn = __sinf(pho);
        ((float*)&ro)[j] = mago * cs;
        ((float*)&io)[j] = mago * sn;
      }
      *reinterpret_cast<float4*>(&rebuf[ra]) = ro;
      *reinterpret_cast<float4*>(&imbuf[ia]) = io;
    }
  }
}

// ---------------------------------------------------------------- launch
extern "C" void kernel_launch(void* const* d_in, const int* in_sizes, int n_in,
                              void* d_out, int out_size, void* d_ws, size_t ws_size,
                              hipStream_t stream) {
  (void)in_sizes; (void)n_in; (void)out_size; (void)ws_size;
  const float* x     = (const float*)d_in[0];
  const float* mgW1  = (const float*)d_in[1];
  const float* mgb1  = (const float*)d_in[2];
  const float* mgg   = (const float*)d_in[3];
  const float* mgbe  = (const float*)d_in[4];
  const float* mgW2  = (const float*)d_in[5];
  const float* mgb2  = (const float*)d_in[6];
  const float* phW1  = (const float*)d_in[7];
  const float* phb1  = (const float*)d_in[8];
  const float* phg   = (const float*)d_in[9];
  const float* phbe  = (const float*)d_in[10];
  const float* phW2  = (const float*)d_in[11];
  const float* phb2  = (const float*)d_in[12];
  const float* bdW1  = (const float*)d_in[13];
  const float* bdb1  = (const float*)d_in[14];
  const float* bdg   = (const float*)d_in[15];
  const float* bdbe  = (const float*)d_in[16];
  const float* bdW2  = (const float*)d_in[17];
  const float* bdb2  = (const float*)d_in[18];
  const float* cgW1  = (const float*)d_in[19];
  const float* cgb1  = (const float*)d_in[20];
  const float* cgg   = (const float*)d_in[21];
  const float* cgbe  = (const float*)d_in[22];
  const float* cgW2  = (const float*)d_in[23];
  const float* cgb2  = (const float*)d_in[24];
  const float* convW = (const float*)d_in[25];
  const float* convB = (const float*)d_in[26];

  float* outp = (float*)d_out;
  float* wsf  = (float*)d_ws;
  float* bufA = wsf;
  __hip_bfloat16* gatedA = (__hip_bfloat16*)wsf;
  char* p = (char*)(wsf + (size_t)NB * NG * NL * ND);
  __hip_bfloat16* Wt2 = (__hip_bfloat16*)p;           p += (size_t)384 * 384 * 3 * 2;
  float* twid = (float*)p;                            p += 1024 * 4;
  float* bwp  = (float*)p;                            p += 512 * 4;
  __hip_bfloat16* W1A = (__hip_bfloat16*)p;           p += (size_t)2 * 36864 * 2;
  __hip_bfloat16* W2A = (__hip_bfloat16*)p;           p += (size_t)2 * 36864 * 2;
  __hip_bfloat16* W1G = (__hip_bfloat16*)p;           p += (size_t)147456 * 2;

  k_prep<<<dim3(2930), dim3(256), 0, stream>>>(convW, x, mgW1, phW1, mgW2, phW2, cgW1,
                                               Wt2, twid, W1A, W2A, W1G, outp);
  k_gate2<<<dim3(NB * 64), dim3(256), 0, stream>>>(x, W1G, cgb1, cgg, cgbe, cgW2, cgb2, gatedA);
  k_conv_mfma<<<dim3(NB * NG * 8 * 3), dim3(256), 0, stream>>>(gatedA, Wt2, convB, outp);
  k_fft_t<0><<<dim3(NB * NG * 96), dim3(256), 0, stream>>>(twid, outp, bufA);
  k_bd<<<dim3(NB * NG), dim3(96), 0, stream>>>(outp, bdW1, bdb1, bdg, bdbe, bdW2, bdb2, bwp);
  k_att2<<<dim3(NB * NG * 16), dim3(256), 0, stream>>>(outp, bufA,
      W1A, W2A, mgb1, mgg, mgbe, mgb2, phb1, phg, phbe, phb2, bwp);
  k_fft_t<1><<<dim3(NB * NG * 96), dim3(256), 0, stream>>>(twid, outp, bufA);
}

// Round 5
// 1140.561 us; speedup vs baseline: 3.5237x; 1.3934x over previous
//
#include <hip/hip_runtime.h>
#include <hip/hip_bf16.h>
#include <hip/hip_fp16.h>
#include <math.h>

#define NB 32
#define NL 1024
#define NG 3
#define ND 384
#define NH 96
#define NDG 192
#define SEQR 3073   // 1 + G*L

typedef __attribute__((ext_vector_type(8))) short short8n;
typedef __attribute__((ext_vector_type(4))) short short4n;
typedef __attribute__((ext_vector_type(4))) float f32x4;

__device__ __forceinline__ short bfx(float f) {
  __hip_bfloat16 h = __float2bfloat16(f);
  return *reinterpret_cast<short*>(&h);
}
__device__ __forceinline__ float xbf(short s) {
  __hip_bfloat16 h = *reinterpret_cast<__hip_bfloat16*>(&s);
  return __bfloat162float(h);
}
__device__ __forceinline__ short hfx(float f) {
  __half h = __float2half(f);
  return *reinterpret_cast<short*>(&h);
}
__device__ __forceinline__ float xhf(short s) {
  __half h = *reinterpret_cast<__half*>(&s);
  return __half2float(h);
}

// fast atan2, abs err <= ~1e-5 rad
__device__ __forceinline__ float fast_atan2f(float y, float x) {
  float ax = fabsf(x), ay = fabsf(y);
  float mx = fmaxf(ax, ay), mn = fminf(ax, ay);
  float r = (mx == 0.0f) ? 0.0f : __fdividef(mn, mx);
  float s = r * r;
  float p = fmaf(s, 0.0208351f, -0.0851330f);
  p = fmaf(s, p, 0.1801410f);
  p = fmaf(s, p, -0.3302995f);
  p = fmaf(s, p, 0.9998660f);
  p = r * p;
  float a = (ay > ax) ? (1.5707963267948966f - p) : p;
  a = (x < 0.0f) ? (3.14159265358979323846f - a) : a;
  return (y < 0.0f) ? -a : a;
}

__device__ __forceinline__ float fast_sigmoid(float x) {
  return __fdividef(1.0f, 1.0f + __expf(-x));
}
__device__ __forceinline__ float fast_tanh(float x) {
  return 1.0f - __fdividef(2.0f, 1.0f + __expf(2.0f * x));
}

// ---------------------------------------------------------------- prep
__global__ __launch_bounds__(256) void k_prep(const float* __restrict__ convW,
                                              const float* __restrict__ x,
                                              const float* __restrict__ mgW1s,
                                              const float* __restrict__ phW1s,
                                              const float* __restrict__ mgW2s,
                                              const float* __restrict__ phW2s,
                                              const float* __restrict__ cgW1s,
                                              __hip_bfloat16* __restrict__ Wt2,
                                              float* __restrict__ twid,
                                              __hip_bfloat16* __restrict__ W1Ao,
                                              __hip_bfloat16* __restrict__ W2Ao,
                                              __hip_bfloat16* __restrict__ W1Go,
                                              float* __restrict__ outp) {
  int id = blockIdx.x * 256 + threadIdx.x;
  if (id < 384 * 384 * 3) {
    int i = id % 384; int rest = id / 384; int o = rest % 384; int kh = rest / 384;
    Wt2[id] = __float2bfloat16(convW[(o * 384 + i) * 3 + kh]);
    return;
  }
  int id2 = id - 384 * 384 * 3;
  if (id2 < 512) {
    float ang = -6.283185307179586f * (float)id2 / 1024.0f;
    float s, c; sincosf(ang, &s, &c);
    twid[2 * id2] = c; twid[2 * id2 + 1] = s;
    return;
  }
  int id3 = id2 - 512;
  if (id3 < NB * ND) {
    int b = id3 / ND, d = id3 % ND;
    outp[(size_t)b * SEQR * ND + d] = x[(size_t)b * SEQR * ND + d];
    return;
  }
  int id4 = id3 - NB * ND;
  if (id4 < 2 * 36864) {   // W1A: [br][kk(12)][f(6)][lane(64)][8]
    int br = id4 / 36864, idx = id4 % 36864;
    int j = idx & 7, ln = (idx >> 3) & 63, rest = idx >> 9;
    int f = rest % 6, kk = rest / 6;
    int m = f * 16 + (ln & 15), k = kk * 32 + (ln >> 4) * 8 + j;
    const float* W = br ? phW1s : mgW1s;
    W1Ao[id4] = __float2bfloat16(W[k * NH + m]);
    return;
  }
  int id5 = id4 - 2 * 36864;
  if (id5 < 2 * 36864) {   // W2A: [br][kk(3)][f(24)][lane(64)][8]
    int br = id5 / 36864, idx = id5 % 36864;
    int j = idx & 7, ln = (idx >> 3) & 63, rest = idx >> 9;
    int f = rest % 24, kk = rest / 24;
    int d = f * 16 + (ln & 15), k = kk * 32 + (ln >> 4) * 8 + j;
    const float* W = br ? phW2s : mgW2s;
    W2Ao[id5] = __float2bfloat16(W[k * ND + d]);
    return;
  }
  int id6 = id5 - 2 * 36864;
  if (id6 < 147456) {      // W1G: [part(2)][kk(12)][f(12)][lane(64)][8]
    int j = id6 & 7, ln = (id6 >> 3) & 63, rest = id6 >> 9;
    int f = rest % 12, rest2 = rest / 12;
    int kk = rest2 % 12, part = rest2 / 12;
    int m = f * 16 + (ln & 15), k = part * 384 + kk * 32 + (ln >> 4) * 8 + j;
    W1Go[id6] = __float2bfloat16(cgW1s[k * NDG + m]);
  }
}

// ---------------------------------------------------------------- gate MLP via MFMA
__global__ __launch_bounds__(256) void k_gate2(const float* __restrict__ x,
    const __hip_bfloat16* __restrict__ W1G,
    const float* __restrict__ b1, const float* __restrict__ gam,
    const float* __restrict__ bet, const float* __restrict__ W2,
    const float* __restrict__ b2p,
    __hip_bfloat16* __restrict__ gatedA) {
  int bid = blockIdx.x;
  int b = bid >> 6; int l0 = (bid & 63) * 16;
  int tid = threadIdx.x;
  int lane = tid & 63, wid = tid >> 6;
  int r15 = lane & 15, kc = lane >> 4;

  __shared__ short xs[3][16][392];
  __shared__ short gs[16][392];
  __shared__ float hG[16][196];
  __shared__ float s_b1[NDG], s_g[NDG], s_be[NDG], s_w2[NDG];
  __shared__ float sgate[3][16];

  if (tid < NDG) {
    s_b1[tid] = b1[tid]; s_g[tid] = gam[tid];
    s_be[tid] = bet[tid]; s_w2[tid] = W2[tid];
  }
  for (int c = tid; c < 16 * 96; c += 256) {
    int l = c / 96, d4 = (c % 96) * 4;
    size_t base = ((size_t)b * SEQR + 1 + l0 + l) * ND + d4;
    float4 v0 = *reinterpret_cast<const float4*>(&x[base]);
    float4 v1 = *reinterpret_cast<const float4*>(&x[base + (size_t)NL * ND]);
    float4 v2 = *reinterpret_cast<const float4*>(&x[base + (size_t)2 * NL * ND]);
    short4n q0, q1, q2, qg;
    q0.x = bfx(v0.x); q0.y = bfx(v0.y); q0.z = bfx(v0.z); q0.w = bfx(v0.w);
    q1.x = bfx(v1.x); q1.y = bfx(v1.y); q1.z = bfx(v1.z); q1.w = bfx(v1.w);
    q2.x = bfx(v2.x); q2.y = bfx(v2.y); q2.z = bfx(v2.z); q2.w = bfx(v2.w);
    qg.x = bfx((v0.x + v1.x + v2.x) * (1.0f / 3.0f));
    qg.y = bfx((v0.y + v1.y + v2.y) * (1.0f / 3.0f));
    qg.z = bfx((v0.z + v1.z + v2.z) * (1.0f / 3.0f));
    qg.w = bfx((v0.w + v1.w + v2.w) * (1.0f / 3.0f));
    *reinterpret_cast<short4n*>(&xs[0][l][d4]) = q0;
    *reinterpret_cast<short4n*>(&xs[1][l][d4]) = q1;
    *reinterpret_cast<short4n*>(&xs[2][l][d4]) = q2;
    *reinterpret_cast<short4n*>(&gs[l][d4]) = qg;
  }
  __syncthreads();

  const short* bsrc = (wid == 3) ? &gs[0][0] : &xs[wid][0][0];
  const __hip_bfloat16* W1b = W1G + (size_t)(wid == 3 ? 1 : 0) * 73728;
  f32x4 hacc[12];
#pragma unroll
  for (int f = 0; f < 12; f++)
#pragma unroll
    for (int j = 0; j < 4; j++)
      hacc[f][j] = (wid == 3) ? 0.0f : s_b1[f * 16 + kc * 4 + j];
  for (int kk = 0; kk < 12; kk++) {
    short8n bx = *reinterpret_cast<const short8n*>(&bsrc[r15 * 392 + kk * 32 + kc * 8]);
#pragma unroll
    for (int f = 0; f < 12; f++) {
      short8n aw = *reinterpret_cast<const short8n*>(
          (const void*)(W1b + (((size_t)kk * 12 + f) * 64 + lane) * 8));
      hacc[f] = __builtin_amdgcn_mfma_f32_16x16x32_bf16(aw, bx, hacc[f], 0, 0, 0);
    }
  }
  if (wid == 3) {
#pragma unroll
    for (int f = 0; f < 12; f++)
#pragma unroll
      for (int j = 0; j < 4; j++)
        hG[r15][f * 16 + kc * 4 + j] = hacc[f][j];
  }
  __syncthreads();
  if (wid < 3) {
    float s = 0.f, sq = 0.f;
#pragma unroll
    for (int f = 0; f < 12; f++)
#pragma unroll
      for (int j = 0; j < 4; j++) {
        float v = hacc[f][j] + hG[r15][f * 16 + kc * 4 + j];
        hacc[f][j] = v; s += v; sq += v * v;
      }
    s += __shfl_xor(s, 16, 64); s += __shfl_xor(s, 32, 64);
    sq += __shfl_xor(sq, 16, 64); sq += __shfl_xor(sq, 32, 64);
    float mean = s * (1.0f / NDG);
    float var = sq * (1.0f / NDG) - mean * mean;
    float rstd = rsqrtf(var + 1e-5f);
    float dot = 0.f;
#pragma unroll
    for (int f = 0; f < 12; f++)
#pragma unroll
      for (int j = 0; j < 4; j++) {
        int m = f * 16 + kc * 4 + j;
        float hn = fmaxf((hacc[f][j] - mean) * rstd * s_g[m] + s_be[m], 0.0f);
        dot += hn * s_w2[m];
      }
    dot += __shfl_xor(dot, 16, 64); dot += __shfl_xor(dot, 32, 64);
    float gate = fast_sigmoid(dot + b2p[0]);
    if (lane < 16) sgate[wid][r15] = gate;
  }
  __syncthreads();
  if (wid < 3) {
    size_t obase = (((size_t)b * NG + wid) * NL + l0) * ND;
    for (int c = lane; c < 16 * 96; c += 64) {
      int l = c / 96, d4 = (c % 96) * 4;
      float gt = sgate[wid][l];
      short4n qx = *reinterpret_cast<const short4n*>(&xs[wid][l][d4]);
      short4n qg = *reinterpret_cast<const short4n*>(&gs[l][d4]);
      short4n qo;
#pragma unroll
      for (int j = 0; j < 4; j++) {
        float xv = xbf(((short*)&qx)[j]);
        float gv = xbf(((short*)&qg)[j]);
        ((short*)&qo)[j] = bfx(xv * gt + gv * (1.0f - gt));
      }
      *reinterpret_cast<short4n*>(&((short*)gatedA)[obase + (size_t)l * ND + d4]) = qo;
    }
  }
}

// ---------------------------------------------------------------- conv as bf16 MFMA GEMM
// output written TRANSPOSED: reT[b][(g*384+d)][l] at base outp + (b*SEQR+1)*ND
#define BKC 64
__global__ __launch_bounds__(256) void k_conv_mfma(
    const __hip_bfloat16* __restrict__ Abuf,
    const __hip_bfloat16* __restrict__ Wt2,
    const float* __restrict__ cb,
    float* __restrict__ outp) {
  int bid = blockIdx.x;
  int ct = bid % 3; int rest = bid / 3;
  int rt = rest % 8; int bg = rest / 8;
  int b = bg / NG, gg = bg % NG;
  int l0 = rt * 128;
  int n0 = ct * 128;
  int tid = threadIdx.x;
  int lane = tid & 63, wid = tid >> 6;
  int wr = wid >> 1, wc = wid & 1;
  int r15 = lane & 15, kc = lane >> 4;

  __shared__ short As[128 * BKC];
  __shared__ short Bs[128 * BKC];

  f32x4 acc[4][4];
#pragma unroll
  for (int m = 0; m < 4; m++)
#pragma unroll
    for (int n = 0; n < 4; n++) acc[m][n] = (f32x4){0.f, 0.f, 0.f, 0.f};

  for (int kh = 0; kh < 3; kh++) {
    int gs = gg + kh - 1;
    if (gs < 0 || gs >= NG) continue;
    const __hip_bfloat16* Ag = Abuf + (((size_t)b * NG + gs) * NL + l0) * ND;
    const __hip_bfloat16* Bg = Wt2 + ((size_t)kh * 384 + n0) * 384;
    for (int k0 = 0; k0 < 384; k0 += BKC) {
      __syncthreads();
#pragma unroll
      for (int p = 0; p < 4; p++) {
        int idx = p * 256 + tid;
        int row = idx >> 3, c = idx & 7;
        int csrc = c ^ (row & 7);
        __builtin_amdgcn_global_load_lds(
            (const __attribute__((address_space(1))) void*)(Ag + (size_t)row * ND + k0 + csrc * 8),
            (__attribute__((address_space(3))) void*)(&As[idx * 8]), 16, 0, 0);
      }
#pragma unroll
      for (int p = 0; p < 4; p++) {
        int idx = p * 256 + tid;
        int row = idx >> 3, c = idx & 7;
        int csrc = c ^ (row & 7);
        __builtin_amdgcn_global_load_lds(
            (const __attribute__((address_space(1))) void*)(Bg + (size_t)row * 384 + k0 + csrc * 8),
            (__attribute__((address_space(3))) void*)(&Bs[idx * 8]), 16, 0, 0);
      }
      __syncthreads();
#pragma unroll
      for (int ks = 0; ks < 2; ks++) {
        short8n af[4], bfr[4];
        int cdata = ks * 4 + kc;
#pragma unroll
        for (int m = 0; m < 4; m++) {
          int row = wr * 64 + m * 16 + r15;
          af[m] = *reinterpret_cast<const short8n*>(&As[row * 64 + (cdata ^ (row & 7)) * 8]);
          int col = wc * 64 + m * 16 + r15;
          bfr[m] = *reinterpret_cast<const short8n*>(&Bs[col * 64 + (cdata ^ (col & 7)) * 8]);
        }
#pragma unroll
        for (int m = 0; m < 4; m++)
#pragma unroll
          for (int n = 0; n < 4; n++)
            acc[m][n] = __builtin_amdgcn_mfma_f32_16x16x32_bf16(af[m], bfr[n], acc[m][n], 0, 0, 0);
      }
    }
  }
  // transposed epilogue: lane holds 4 consecutive l for fixed d -> float4 along l
  float cbv[4];
#pragma unroll
  for (int n = 0; n < 4; n++) cbv[n] = cb[n0 + wc * 64 + n * 16 + r15];
  size_t tbase = (size_t)(b * SEQR + 1) * ND;
#pragma unroll
  for (int n = 0; n < 4; n++) {
    int drow = gg * ND + n0 + wc * 64 + n * 16 + r15;
#pragma unroll
    for (int m = 0; m < 4; m++) {
      int lcol = l0 + wr * 64 + m * 16 + kc * 4;
      float4 v = {acc[m][n][0] + cbv[n], acc[m][n][1] + cbv[n],
                  acc[m][n][2] + cbv[n], acc[m][n][3] + cbv[n]};
      *reinterpret_cast<float4*>(&outp[tbase + (size_t)drow * NL + lcol]) = v;
    }
  }
}

// ---------------------------------------------------------------- FFT fwd: DIF, natural-in, bitrev-out
// re in/out: outp rows [d][l]; im out: imT rows. Fully coalesced global I/O.
__global__ __launch_bounds__(256) void k_fft_fwd(const float* __restrict__ twid,
                                                 float* __restrict__ outp,
                                                 float* __restrict__ imT) {
  int bid = blockIdx.x;
  int b = bid / 288;                 // 288 = 1152 rows / 4 per block
  int rloc = (bid % 288) * 4;
  size_t rbase = (size_t)(b * SEQR + 1) * ND + (size_t)rloc * NL;
  size_t ibase = ((size_t)b * NG * ND + rloc) * NL;
  int tid = threadIdx.x;
  __shared__ float sre[4][1024];
  __shared__ float sim[4][1024];
  for (int idx = tid; idx < 4096; idx += 256) {
    int line = idx >> 10, pos = idx & 1023;
    sre[line][pos] = outp[rbase + (size_t)line * NL + pos];
    sim[line][pos] = 0.0f;
  }
  __syncthreads();
  for (int s = 9; s >= 0; s--) {
    int m = 1 << s;
    for (int bt = tid; bt < 2048; bt += 256) {
      int line = bt >> 9, j = bt & 511;
      int jj = j & (m - 1), grp = j >> s;
      int p0 = (grp << (s + 1)) + jj, p1 = p0 + m;
      int ti = jj << (9 - s);
      float twr = twid[2 * ti], twi = twid[2 * ti + 1];
      float ar = sre[line][p0], ai = sim[line][p0];
      float br_ = sre[line][p1], bi = sim[line][p1];
      float dr = ar - br_, di = ai - bi;
      sre[line][p0] = ar + br_; sim[line][p0] = ai + bi;
      sre[line][p1] = dr * twr - di * twi;
      sim[line][p1] = dr * twi + di * twr;
    }
    __syncthreads();
  }
  for (int idx = tid; idx < 4096; idx += 256) {
    int line = idx >> 10, pos = idx & 1023;
    outp[rbase + (size_t)line * NL + pos] = sre[line][pos];
    imT[ibase + (size_t)line * NL + pos] = sim[line][pos];
  }
}

// ---------------------------------------------------------------- FFT inv: DIT, bitrev-in, natural-out
// reads outp(re)+imT(im) rows; writes real/1024 in-place into imT rows [d][l]
__global__ __launch_bounds__(256) void k_fft_inv(const float* __restrict__ twid,
                                                 const float* __restrict__ outp,
                                                 float* __restrict__ imT) {
  int bid = blockIdx.x;
  int b = bid / 288;
  int rloc = (bid % 288) * 4;
  size_t rbase = (size_t)(b * SEQR + 1) * ND + (size_t)rloc * NL;
  size_t ibase = ((size_t)b * NG * ND + rloc) * NL;
  int tid = threadIdx.x;
  __shared__ float sre[4][1024];
  __shared__ float sim[4][1024];
  for (int idx = tid; idx < 4096; idx += 256) {
    int line = idx >> 10, pos = idx & 1023;
    sre[line][pos] = outp[rbase + (size_t)line * NL + pos];
    sim[line][pos] = imT[ibase + (size_t)line * NL + pos];
  }
  __syncthreads();
  for (int s = 0; s < 10; s++) {
    int m = 1 << s;
    for (int bt = tid; bt < 2048; bt += 256) {
      int line = bt >> 9, j = bt & 511;
      int jj = j & (m - 1), grp = j >> s;
      int p0 = (grp << (s + 1)) + jj, p1 = p0 + m;
      int ti = jj << (9 - s);
      float twr = twid[2 * ti];
      float twi = -twid[2 * ti + 1];      // conj for inverse
      float re1 = sre[line][p1], im1 = sim[line][p1];
      float tr = re1 * twr - im1 * twi;
      float tq = re1 * twi + im1 * twr;
      float re0 = sre[line][p0], im0 = sim[line][p0];
      sre[line][p1] = re0 - tr; sim[line][p1] = im0 - tq;
      sre[line][p0] = re0 + tr; sim[line][p0] = im0 + tq;
    }
    __syncthreads();
  }
  const float sc = 1.0f / 1024.0f;
  for (int idx = tid; idx < 4096; idx += 256) {
    int line = idx >> 10, pos = idx & 1023;
    imT[ibase + (size_t)line * NL + pos] = sre[line][pos] * sc;
  }
}

// ---------------------------------------------------------------- final transpose [d][l] -> [l][d]
__global__ __launch_bounds__(256) void k_tr(const float* __restrict__ src,
                                            float* __restrict__ dst) {
  int bid = blockIdx.x;
  int dt = bid % 6; int r1 = bid / 6;
  int lt = r1 % 16; int r2 = r1 / 16;
  int gg = r2 % NG; int b = r2 / NG;
  int tid = threadIdx.x;
  __shared__ float T[64][67];
  size_t sbase = ((size_t)b * NG * ND + gg * ND + dt * 64) * NL + lt * 64;
  for (int c = tid; c < 64 * 16; c += 256) {
    int r = c >> 4, cc = c & 15;
    float4 v = *reinterpret_cast<const float4*>(&src[sbase + (size_t)r * NL + cc * 4]);
    T[r][cc * 4 + 0] = v.x; T[r][cc * 4 + 1] = v.y;
    T[r][cc * 4 + 2] = v.z; T[r][cc * 4 + 3] = v.w;
  }
  __syncthreads();
  size_t dbase = ((size_t)b * SEQR + 1 + (size_t)gg * NL + lt * 64) * ND + dt * 64;
  for (int c = tid; c < 64 * 16; c += 256) {
    int r = c >> 4, cc = c & 15;
    float4 v = {T[cc * 4 + 0][r], T[cc * 4 + 1][r], T[cc * 4 + 2][r], T[cc * 4 + 3][r]};
    *reinterpret_cast<float4*>(&dst[dbase + (size_t)r * ND + cc * 4]) = v;
  }
}

// ---------------------------------------------------------------- band MLP (reads DC = storage pos 0)
__global__ __launch_bounds__(96) void k_bd(const float* __restrict__ outp,
    const float* __restrict__ W1, const float* __restrict__ b1,
    const float* __restrict__ gam, const float* __restrict__ bet,
    const float* __restrict__ W2, const float* __restrict__ b2,
    float* __restrict__ bwout) {
  int bid = blockIdx.x;
  int b = bid / NG, gg = bid % NG;
  int tid = threadIdx.x;
  __shared__ float xm[ND];
  __shared__ float hs[NH];
  __shared__ float o3[3];
  size_t dcbase = (size_t)(b * SEQR + 1) * ND + (size_t)(gg * ND) * NL;
  for (int i = tid; i < ND; i += NH) xm[i] = outp[dcbase + (size_t)i * NL] * (1.0f / NL);
  __syncthreads();
  float acc = b1[tid];
  for (int i = 0; i < ND; i++) acc += xm[i] * W1[i * NH + tid];
  hs[tid] = acc;
  __syncthreads();
  float s = 0, sq = 0;
  for (int i = 0; i < NH; i++) { float v = hs[i]; s += v; sq += v * v; }
  float m = s * (1.0f / NH), var = sq * (1.0f / NH) - m * m;
  float hn = fmaxf((acc - m) * rsqrtf(var + 1e-5f) * gam[tid] + bet[tid], 0.0f);
  __syncthreads();
  hs[tid] = hn;
  __syncthreads();
  if (tid < 3) {
    float o = b2[tid];
    for (int k = 0; k < NH; k++) o += hs[k] * W2[k * 3 + tid];
    o3[tid] = o;
  }
  __syncthreads();
  if (tid < 3) {
    float mx = fmaxf(o3[0], fmaxf(o3[1], o3[2]));
    float ssum = expf(o3[0] - mx) + expf(o3[1] - mx) + expf(o3[2] - mx);
    bwout[bid * 3 + tid] = expf(o3[tid] - mx) / ssum;
  }
}

// ---------------------------------------------------------------- mag/phase MLPs via MFMA + modulate
// freq data in [d][l]-bitrev layout. Tile = 64 storage positions x 384 d.
#define AROW 64
#define APAD 392
#define HPAD 104
__global__ __launch_bounds__(256) void k_att2(
    float* __restrict__ reT, float* __restrict__ imT,
    const __hip_bfloat16* __restrict__ W1A,
    const __hip_bfloat16* __restrict__ W2A,
    const float* __restrict__ mgb1, const float* __restrict__ mgg,
    const float* __restrict__ mgbe, const float* __restrict__ mgb2,
    const float* __restrict__ phb1, const float* __restrict__ phg,
    const float* __restrict__ phbe, const float* __restrict__ phb2,
    const float* __restrict__ bwp) {
  int bid = blockIdx.x;
  int bg = bid >> 4; int tile = bid & 15;
  int b = bg / NG, gg = bg % NG;
  int l0 = tile * AROW;                // storage-position base
  int tid = threadIdx.x;
  int lane = tid & 63, wid = tid >> 6;
  int r15 = lane & 15, kc = lane >> 4;
  int wl0 = wid * 16;

  __shared__ short Am[AROW * APAD];    // stage1: bf16 mag; stage3: fp16 ma
  __shared__ short Ap[AROW * APAD];    // stage1: bf16 phase; stage3: fp16 pa
  __shared__ short ht0[AROW * HPAD];
  __shared__ short ht1[AROW * HPAD];
  __shared__ float s_b1[2][NH], s_g[2][NH], s_be[2][NH];
  __shared__ float s_b2[2][ND];
  __shared__ float s_wm[AROW];

  size_t rb = (size_t)(b * SEQR + 1) * ND + (size_t)(gg * ND) * NL;  // batch/g base in reT
  size_t ib = ((size_t)b * NG * ND + gg * ND) * NL;

  if (tid < NH) {
    s_b1[0][tid] = mgb1[tid]; s_b1[1][tid] = phb1[tid];
    s_g[0][tid]  = mgg[tid];  s_g[1][tid]  = phg[tid];
    s_be[0][tid] = mgbe[tid]; s_be[1][tid] = phbe[tid];
  }
  for (int i = tid; i < ND; i += 256) { s_b2[0][i] = mgb2[i]; s_b2[1][i] = phb2[i]; }
  if (tid < AROW) {   // band weight per storage position (true bin = brev10(pos))
    int k = (int)(__brev((unsigned)(l0 + tid)) >> 22);
    int fr = (k <= 512) ? k : (1024 - k);
    int bwb = (b * NG + gg) * 3;
    s_wm[tid] = (fr <= 128) ? bwp[bwb] : ((fr <= 256) ? bwp[bwb + 1] : bwp[bwb + 2]);
  }

  // stage 1: coalesced [d][l] reads, scatter bf16 mag/phase into Am/Ap[pos][d]
  for (int i = tid; i < ND * 16; i += 256) {
    int d = i >> 4, lc = i & 15;
    size_t off = (size_t)d * NL + l0 + lc * 4;
    float4 re = *reinterpret_cast<const float4*>(&reT[rb + off]);
    float4 im = *reinterpret_cast<const float4*>(&imT[ib + off]);
    float rr[4] = {re.x, re.y, re.z, re.w};
    float ii[4] = {im.x, im.y, im.z, im.w};
#pragma unroll
    for (int j = 0; j < 4; j++) {
      int row = lc * 4 + j;
      Am[row * APAD + d] = bfx(sqrtf(rr[j] * rr[j] + ii[j] * ii[j]));
      Ap[row * APAD + d] = bfx(fast_atan2f(ii[j], rr[j]));
    }
  }
  __syncthreads();

  // GEMM1 both branches -> LN -> relu -> ht (bf16)
#pragma unroll
  for (int br = 0; br < 2; br++) {
    const short* Abuf = br ? Ap : Am;
    short* htb = br ? ht1 : ht0;
    const __hip_bfloat16* W1b = W1A + (size_t)br * 36864;
    f32x4 hacc[6];
#pragma unroll
    for (int f = 0; f < 6; f++) {
#pragma unroll
      for (int j = 0; j < 4; j++) hacc[f][j] = s_b1[br][f * 16 + kc * 4 + j];
    }
    for (int kk = 0; kk < 12; kk++) {
      short8n bx = *reinterpret_cast<const short8n*>(&Abuf[(wl0 + r15) * APAD + kk * 32 + kc * 8]);
#pragma unroll
      for (int f = 0; f < 6; f++) {
        short8n aw = *reinterpret_cast<const short8n*>(
            (const void*)(W1b + (((size_t)kk * 6 + f) * 64 + lane) * 8));
        hacc[f] = __builtin_amdgcn_mfma_f32_16x16x32_bf16(aw, bx, hacc[f], 0, 0, 0);
      }
    }
    float s = 0.f, sq = 0.f;
#pragma unroll
    for (int f = 0; f < 6; f++)
#pragma unroll
      for (int j = 0; j < 4; j++) { float v = hacc[f][j]; s += v; sq += v * v; }
    s += __shfl_xor(s, 16, 64); s += __shfl_xor(s, 32, 64);
    sq += __shfl_xor(sq, 16, 64); sq += __shfl_xor(sq, 32, 64);
    float mean = s * (1.0f / NH);
    float var = sq * (1.0f / NH) - mean * mean;
    float rstd = rsqrtf(var + 1e-5f);
#pragma unroll
    for (int f = 0; f < 6; f++) {
      short4n hq;
#pragma unroll
      for (int j = 0; j < 4; j++) {
        int m = f * 16 + kc * 4 + j;
        float hn = fmaxf((hacc[f][j] - mean) * rstd * s_g[br][m] + s_be[br][m], 0.0f);
        ((short*)&hq)[j] = bfx(hn);
      }
      *reinterpret_cast<short4n*>(&htb[(wl0 + r15) * HPAD + f * 16 + kc * 4]) = hq;
    }
  }
  __syncthreads();

  int lloc = wl0 + r15;
  short8n bhm[3], bhp[3];
#pragma unroll
  for (int kk = 0; kk < 3; kk++) {
    bhm[kk] = *reinterpret_cast<const short8n*>(&ht0[lloc * HPAD + kk * 32 + kc * 8]);
    bhp[kk] = *reinterpret_cast<const short8n*>(&ht1[lloc * HPAD + kk * 32 + kc * 8]);
  }

  // GEMM2: stash sigmoid/tanh as fp16 into Am/Ap (mag/phase no longer needed)
#pragma unroll
  for (int chunk = 0; chunk < 4; chunk++) {
    f32x4 aM[6], aP[6];
#pragma unroll
    for (int f = 0; f < 6; f++) {
      int dbase = (chunk * 6 + f) * 16 + kc * 4;
#pragma unroll
      for (int j = 0; j < 4; j++) {
        aM[f][j] = s_b2[0][dbase + j];
        aP[f][j] = s_b2[1][dbase + j];
      }
    }
#pragma unroll
    for (int kk = 0; kk < 3; kk++) {
#pragma unroll
      for (int f = 0; f < 6; f++) {
        int fg = chunk * 6 + f;
        short8n awm = *reinterpret_cast<const short8n*>(
            (const void*)(W2A + (((size_t)kk * 24 + fg) * 64 + lane) * 8));
        short8n awp = *reinterpret_cast<const short8n*>(
            (const void*)(W2A + 36864 + (((size_t)kk * 24 + fg) * 64 + lane) * 8));
        aM[f] = __builtin_amdgcn_mfma_f32_16x16x32_bf16(awm, bhm[kk], aM[f], 0, 0, 0);
        aP[f] = __builtin_amdgcn_mfma_f32_16x16x32_bf16(awp, bhp[kk], aP[f], 0, 0, 0);
      }
    }
#pragma unroll
    for (int f = 0; f < 6; f++) {
      int dbase = (chunk * 6 + f) * 16 + kc * 4;
      short4n qm, qp;
#pragma unroll
      for (int j = 0; j < 4; j++) {
        ((short*)&qm)[j] = hfx(fast_sigmoid(aM[f][j]));
        ((short*)&qp)[j] = hfx(fast_tanh(aP[f][j]));
      }
      *reinterpret_cast<short4n*>(&Am[lloc * APAD + dbase]) = qm;
      *reinterpret_cast<short4n*>(&Ap[lloc * APAD + dbase]) = qp;
    }
  }
  __syncthreads();

  // final pass: coalesced modulate of reT/imT in place
  for (int i = tid; i < ND * 16; i += 256) {
    int d = i >> 4, lc = i & 15;
    size_t off = (size_t)d * NL + l0 + lc * 4;
    float4 re = *reinterpret_cast<const float4*>(&reT[rb + off]);
    float4 im = *reinterpret_cast<const float4*>(&imT[ib + off]);
    float rr[4] = {re.x, re.y, re.z, re.w};
    float ii[4] = {im.x, im.y, im.z, im.w};
    float4 ro, io;
#pragma unroll
    for (int j = 0; j < 4; j++) {
      int row = lc * 4 + j;
      float ma = xhf(Am[row * APAD + d]);
      float pa = xhf(Ap[row * APAD + d]);
      float wm = s_wm[row];
      float mag = sqrtf(rr[j] * rr[j] + ii[j] * ii[j]);
      float ph = fast_atan2f(ii[j], rr[j]);
      float mago = mag * wm * ma;
      float pho = ph * wm + pa;
      float cs = __cosf(pho), sn = __sinf(pho);
      ((float*)&ro)[j] = mago * cs;
      ((float*)&io)[j] = mago * sn;
    }
    *reinterpret_cast<float4*>(&reT[rb + off]) = ro;
    *reinterpret_cast<float4*>(&imT[ib + off]) = io;
  }
}

// ---------------------------------------------------------------- launch
extern "C" void kernel_launch(void* const* d_in, const int* in_sizes, int n_in,
                              void* d_out, int out_size, void* d_ws, size_t ws_size,
                              hipStream_t stream) {
  (void)in_sizes; (void)n_in; (void)out_size; (void)ws_size;
  const float* x     = (const float*)d_in[0];
  const float* mgW1  = (const float*)d_in[1];
  const float* mgb1  = (const float*)d_in[2];
  const float* mgg   = (const float*)d_in[3];
  const float* mgbe  = (const float*)d_in[4];
  const float* mgW2  = (const float*)d_in[5];
  const float* mgb2  = (const float*)d_in[6];
  const float* phW1  = (const float*)d_in[7];
  const float* phb1  = (const float*)d_in[8];
  const float* phg   = (const float*)d_in[9];
  const float* phbe  = (const float*)d_in[10];
  const float* phW2  = (const float*)d_in[11];
  const float* phb2  = (const float*)d_in[12];
  const float* bdW1  = (const float*)d_in[13];
  const float* bdb1  = (const float*)d_in[14];
  const float* bdg   = (const float*)d_in[15];
  const float* bdbe  = (const float*)d_in[16];
  const float* bdW2  = (const float*)d_in[17];
  const float* bdb2  = (const float*)d_in[18];
  const float* cgW1  = (const float*)d_in[19];
  const float* cgb1  = (const float*)d_in[20];
  const float* cgg   = (const float*)d_in[21];
  const float* cgbe  = (const float*)d_in[22];
  const float* cgW2  = (const float*)d_in[23];
  const float* cgb2  = (const float*)d_in[24];
  const float* convW = (const float*)d_in[25];
  const float* convB = (const float*)d_in[26];

  float* outp = (float*)d_out;
  float* wsf  = (float*)d_ws;
  // ws region0 (151MB): gatedA (bf16) during gate->conv, then imT (fp32) for FFT onward
  float* imT = wsf;
  __hip_bfloat16* gatedA = (__hip_bfloat16*)wsf;
  char* p = (char*)(wsf + (size_t)NB * NG * NL * ND);
  __hip_bfloat16* Wt2 = (__hip_bfloat16*)p;           p += (size_t)384 * 384 * 3 * 2;
  float* twid = (float*)p;                            p += 1024 * 4;
  float* bwp  = (float*)p;                            p += 512 * 4;
  __hip_bfloat16* W1A = (__hip_bfloat16*)p;           p += (size_t)2 * 36864 * 2;
  __hip_bfloat16* W2A = (__hip_bfloat16*)p;           p += (size_t)2 * 36864 * 2;
  __hip_bfloat16* W1G = (__hip_bfloat16*)p;           p += (size_t)147456 * 2;

  k_prep<<<dim3(2930), dim3(256), 0, stream>>>(convW, x, mgW1, phW1, mgW2, phW2, cgW1,
                                               Wt2, twid, W1A, W2A, W1G, outp);
  k_gate2<<<dim3(NB * 64), dim3(256), 0, stream>>>(x, W1G, cgb1, cgg, cgbe, cgW2, cgb2, gatedA);
  k_conv_mfma<<<dim3(NB * NG * 8 * 3), dim3(256), 0, stream>>>(gatedA, Wt2, convB, outp);
  k_fft_fwd<<<dim3(NB * 288), dim3(256), 0, stream>>>(twid, outp, imT);
  k_bd<<<dim3(NB * NG), dim3(96), 0, stream>>>(outp, bdW1, bdb1, bdg, bdbe, bdW2, bdb2, bwp);
  k_att2<<<dim3(NB * NG * 16), dim3(256), 0, stream>>>(outp, imT,
      W1A, W2A, mgb1, mgg, mgbe, mgb2, phb1, phg, phbe, phb2, bwp);
  k_fft_inv<<<dim3(NB * 288), dim3(256), 0, stream>>>(twid, outp, imT);
  k_tr<<<dim3(NB * NG * 16 * 6), dim3(256), 0, stream>>>(imT, outp);
}

// Round 6
// 1110.220 us; speedup vs baseline: 3.6200x; 1.0273x over previous
//
#include <hip/hip_runtime.h>
#include <hip/hip_bf16.h>
#include <hip/hip_fp16.h>
#include <math.h>

#define NB 32
#define NL 1024
#define NG 3
#define ND 384
#define NH 96
#define NDG 192
#define SEQR 3073   // 1 + G*L

typedef __attribute__((ext_vector_type(8))) short short8n;
typedef __attribute__((ext_vector_type(4))) short short4n;
typedef __attribute__((ext_vector_type(4))) float f32x4;

__device__ __forceinline__ short bfx(float f) {
  __hip_bfloat16 h = __float2bfloat16(f);
  return *reinterpret_cast<short*>(&h);
}
__device__ __forceinline__ float xbf(short s) {
  __hip_bfloat16 h = *reinterpret_cast<__hip_bfloat16*>(&s);
  return __bfloat162float(h);
}
__device__ __forceinline__ short hfx(float f) {
  __half h = __float2half(f);
  return *reinterpret_cast<short*>(&h);
}
__device__ __forceinline__ float xhf(short s) {
  __half h = *reinterpret_cast<__half*>(&s);
  return __half2float(h);
}

// fast atan2, abs err <= ~1e-5 rad
__device__ __forceinline__ float fast_atan2f(float y, float x) {
  float ax = fabsf(x), ay = fabsf(y);
  float mx = fmaxf(ax, ay), mn = fminf(ax, ay);
  float r = (mx == 0.0f) ? 0.0f : __fdividef(mn, mx);
  float s = r * r;
  float p = fmaf(s, 0.0208351f, -0.0851330f);
  p = fmaf(s, p, 0.1801410f);
  p = fmaf(s, p, -0.3302995f);
  p = fmaf(s, p, 0.9998660f);
  p = r * p;
  float a = (ay > ax) ? (1.5707963267948966f - p) : p;
  a = (x < 0.0f) ? (3.14159265358979323846f - a) : a;
  return (y < 0.0f) ? -a : a;
}

__device__ __forceinline__ float fast_sigmoid(float x) {
  return __fdividef(1.0f, 1.0f + __expf(-x));
}
__device__ __forceinline__ float fast_tanh(float x) {
  return 1.0f - __fdividef(2.0f, 1.0f + __expf(2.0f * x));
}

// ---------------------------------------------------------------- prep
__global__ __launch_bounds__(256) void k_prep(const float* __restrict__ convW,
                                              const float* __restrict__ x,
                                              const float* __restrict__ mgW1s,
                                              const float* __restrict__ phW1s,
                                              const float* __restrict__ mgW2s,
                                              const float* __restrict__ phW2s,
                                              const float* __restrict__ cgW1s,
                                              __hip_bfloat16* __restrict__ Wt2,
                                              float* __restrict__ twid,
                                              __hip_bfloat16* __restrict__ W1Ao,
                                              __hip_bfloat16* __restrict__ W2Ao,
                                              __hip_bfloat16* __restrict__ W1Go,
                                              float* __restrict__ outp) {
  int id = blockIdx.x * 256 + threadIdx.x;
  if (id < 384 * 384 * 3) {
    int i = id % 384; int rest = id / 384; int o = rest % 384; int kh = rest / 384;
    Wt2[id] = __float2bfloat16(convW[(o * 384 + i) * 3 + kh]);
    return;
  }
  int id2 = id - 384 * 384 * 3;
  if (id2 < 512) {
    float ang = -6.283185307179586f * (float)id2 / 1024.0f;
    float s, c; sincosf(ang, &s, &c);
    twid[2 * id2] = c; twid[2 * id2 + 1] = s;
    return;
  }
  int id3 = id2 - 512;
  if (id3 < NB * ND) {
    int b = id3 / ND, d = id3 % ND;
    outp[(size_t)b * SEQR * ND + d] = x[(size_t)b * SEQR * ND + d];
    return;
  }
  int id4 = id3 - NB * ND;
  if (id4 < 2 * 36864) {   // W1A: [br][kk(12)][f(6)][lane(64)][8]
    int br = id4 / 36864, idx = id4 % 36864;
    int j = idx & 7, ln = (idx >> 3) & 63, rest = idx >> 9;
    int f = rest % 6, kk = rest / 6;
    int m = f * 16 + (ln & 15), k = kk * 32 + (ln >> 4) * 8 + j;
    const float* W = br ? phW1s : mgW1s;
    W1Ao[id4] = __float2bfloat16(W[k * NH + m]);
    return;
  }
  int id5 = id4 - 2 * 36864;
  if (id5 < 2 * 36864) {   // W2A: [br][kk(3)][f(24)][lane(64)][8]
    int br = id5 / 36864, idx = id5 % 36864;
    int j = idx & 7, ln = (idx >> 3) & 63, rest = idx >> 9;
    int f = rest % 24, kk = rest / 24;
    int d = f * 16 + (ln & 15), k = kk * 32 + (ln >> 4) * 8 + j;
    const float* W = br ? phW2s : mgW2s;
    W2Ao[id5] = __float2bfloat16(W[k * ND + d]);
    return;
  }
  int id6 = id5 - 2 * 36864;
  if (id6 < 147456) {      // W1G: [part(2)][kk(12)][f(12)][lane(64)][8]
    int j = id6 & 7, ln = (id6 >> 3) & 63, rest = id6 >> 9;
    int f = rest % 12, rest2 = rest / 12;
    int kk = rest2 % 12, part = rest2 / 12;
    int m = f * 16 + (ln & 15), k = part * 384 + kk * 32 + (ln >> 4) * 8 + j;
    W1Go[id6] = __float2bfloat16(cgW1s[k * NDG + m]);
  }
}

// ---------------------------------------------------------------- gate MLP via MFMA
__global__ __launch_bounds__(256) void k_gate2(const float* __restrict__ x,
    const __hip_bfloat16* __restrict__ W1G,
    const float* __restrict__ b1, const float* __restrict__ gam,
    const float* __restrict__ bet, const float* __restrict__ W2,
    const float* __restrict__ b2p,
    __hip_bfloat16* __restrict__ gatedA) {
  int bid = blockIdx.x;
  int b = bid >> 6; int l0 = (bid & 63) * 16;
  int tid = threadIdx.x;
  int lane = tid & 63, wid = tid >> 6;
  int r15 = lane & 15, kc = lane >> 4;

  __shared__ short xs[3][16][392];
  __shared__ short gs[16][392];
  __shared__ float hG[16][196];
  __shared__ float s_b1[NDG], s_g[NDG], s_be[NDG], s_w2[NDG];
  __shared__ float sgate[3][16];

  if (tid < NDG) {
    s_b1[tid] = b1[tid]; s_g[tid] = gam[tid];
    s_be[tid] = bet[tid]; s_w2[tid] = W2[tid];
  }
  for (int c = tid; c < 16 * 96; c += 256) {
    int l = c / 96, d4 = (c % 96) * 4;
    size_t base = ((size_t)b * SEQR + 1 + l0 + l) * ND + d4;
    float4 v0 = *reinterpret_cast<const float4*>(&x[base]);
    float4 v1 = *reinterpret_cast<const float4*>(&x[base + (size_t)NL * ND]);
    float4 v2 = *reinterpret_cast<const float4*>(&x[base + (size_t)2 * NL * ND]);
    short4n q0, q1, q2, qg;
    q0.x = bfx(v0.x); q0.y = bfx(v0.y); q0.z = bfx(v0.z); q0.w = bfx(v0.w);
    q1.x = bfx(v1.x); q1.y = bfx(v1.y); q1.z = bfx(v1.z); q1.w = bfx(v1.w);
    q2.x = bfx(v2.x); q2.y = bfx(v2.y); q2.z = bfx(v2.z); q2.w = bfx(v2.w);
    qg.x = bfx((v0.x + v1.x + v2.x) * (1.0f / 3.0f));
    qg.y = bfx((v0.y + v1.y + v2.y) * (1.0f / 3.0f));
    qg.z = bfx((v0.z + v1.z + v2.z) * (1.0f / 3.0f));
    qg.w = bfx((v0.w + v1.w + v2.w) * (1.0f / 3.0f));
    *reinterpret_cast<short4n*>(&xs[0][l][d4]) = q0;
    *reinterpret_cast<short4n*>(&xs[1][l][d4]) = q1;
    *reinterpret_cast<short4n*>(&xs[2][l][d4]) = q2;
    *reinterpret_cast<short4n*>(&gs[l][d4]) = qg;
  }
  __syncthreads();

  const short* bsrc = (wid == 3) ? &gs[0][0] : &xs[wid][0][0];
  const __hip_bfloat16* W1b = W1G + (size_t)(wid == 3 ? 1 : 0) * 73728;
  f32x4 hacc[12];
#pragma unroll
  for (int f = 0; f < 12; f++)
#pragma unroll
    for (int j = 0; j < 4; j++)
      hacc[f][j] = (wid == 3) ? 0.0f : s_b1[f * 16 + kc * 4 + j];
  for (int kk = 0; kk < 12; kk++) {
    short8n bx = *reinterpret_cast<const short8n*>(&bsrc[r15 * 392 + kk * 32 + kc * 8]);
#pragma unroll
    for (int f = 0; f < 12; f++) {
      short8n aw = *reinterpret_cast<const short8n*>(
          (const void*)(W1b + (((size_t)kk * 12 + f) * 64 + lane) * 8));
      hacc[f] = __builtin_amdgcn_mfma_f32_16x16x32_bf16(aw, bx, hacc[f], 0, 0, 0);
    }
  }
  if (wid == 3) {
#pragma unroll
    for (int f = 0; f < 12; f++)
#pragma unroll
      for (int j = 0; j < 4; j++)
        hG[r15][f * 16 + kc * 4 + j] = hacc[f][j];
  }
  __syncthreads();
  if (wid < 3) {
    float s = 0.f, sq = 0.f;
#pragma unroll
    for (int f = 0; f < 12; f++)
#pragma unroll
      for (int j = 0; j < 4; j++) {
        float v = hacc[f][j] + hG[r15][f * 16 + kc * 4 + j];
        hacc[f][j] = v; s += v; sq += v * v;
      }
    s += __shfl_xor(s, 16, 64); s += __shfl_xor(s, 32, 64);
    sq += __shfl_xor(sq, 16, 64); sq += __shfl_xor(sq, 32, 64);
    float mean = s * (1.0f / NDG);
    float var = sq * (1.0f / NDG) - mean * mean;
    float rstd = rsqrtf(var + 1e-5f);
    float dot = 0.f;
#pragma unroll
    for (int f = 0; f < 12; f++)
#pragma unroll
      for (int j = 0; j < 4; j++) {
        int m = f * 16 + kc * 4 + j;
        float hn = fmaxf((hacc[f][j] - mean) * rstd * s_g[m] + s_be[m], 0.0f);
        dot += hn * s_w2[m];
      }
    dot += __shfl_xor(dot, 16, 64); dot += __shfl_xor(dot, 32, 64);
    float gate = fast_sigmoid(dot + b2p[0]);
    if (lane < 16) sgate[wid][r15] = gate;
  }
  __syncthreads();
  if (wid < 3) {
    size_t obase = (((size_t)b * NG + wid) * NL + l0) * ND;
    for (int c = lane; c < 16 * 96; c += 64) {
      int l = c / 96, d4 = (c % 96) * 4;
      float gt = sgate[wid][l];
      short4n qx = *reinterpret_cast<const short4n*>(&xs[wid][l][d4]);
      short4n qg = *reinterpret_cast<const short4n*>(&gs[l][d4]);
      short4n qo;
#pragma unroll
      for (int j = 0; j < 4; j++) {
        float xv = xbf(((short*)&qx)[j]);
        float gv = xbf(((short*)&qg)[j]);
        ((short*)&qo)[j] = bfx(xv * gt + gv * (1.0f - gt));
      }
      *reinterpret_cast<short4n*>(&((short*)gatedA)[obase + (size_t)l * ND + d4]) = qo;
    }
  }
}

// ---------------------------------------------------------------- conv as bf16 MFMA GEMM
// output written TRANSPOSED: reT[b][(g*384+d)][l] at base outp + (b*SEQR+1)*ND
#define BKC 64
__global__ __launch_bounds__(256) void k_conv_mfma(
    const __hip_bfloat16* __restrict__ Abuf,
    const __hip_bfloat16* __restrict__ Wt2,
    const float* __restrict__ cb,
    float* __restrict__ outp) {
  int bid = blockIdx.x;
  int ct = bid % 3; int rest = bid / 3;
  int rt = rest % 8; int bg = rest / 8;
  int b = bg / NG, gg = bg % NG;
  int l0 = rt * 128;
  int n0 = ct * 128;
  int tid = threadIdx.x;
  int lane = tid & 63, wid = tid >> 6;
  int wr = wid >> 1, wc = wid & 1;
  int r15 = lane & 15, kc = lane >> 4;

  __shared__ short As[128 * BKC];
  __shared__ short Bs[128 * BKC];

  f32x4 acc[4][4];
#pragma unroll
  for (int m = 0; m < 4; m++)
#pragma unroll
    for (int n = 0; n < 4; n++) acc[m][n] = (f32x4){0.f, 0.f, 0.f, 0.f};

  for (int kh = 0; kh < 3; kh++) {
    int gs = gg + kh - 1;
    if (gs < 0 || gs >= NG) continue;
    const __hip_bfloat16* Ag = Abuf + (((size_t)b * NG + gs) * NL + l0) * ND;
    const __hip_bfloat16* Bg = Wt2 + ((size_t)kh * 384 + n0) * 384;
    for (int k0 = 0; k0 < 384; k0 += BKC) {
      __syncthreads();
#pragma unroll
      for (int p = 0; p < 4; p++) {
        int idx = p * 256 + tid;
        int row = idx >> 3, c = idx & 7;
        int csrc = c ^ (row & 7);
        __builtin_amdgcn_global_load_lds(
            (const __attribute__((address_space(1))) void*)(Ag + (size_t)row * ND + k0 + csrc * 8),
            (__attribute__((address_space(3))) void*)(&As[idx * 8]), 16, 0, 0);
      }
#pragma unroll
      for (int p = 0; p < 4; p++) {
        int idx = p * 256 + tid;
        int row = idx >> 3, c = idx & 7;
        int csrc = c ^ (row & 7);
        __builtin_amdgcn_global_load_lds(
            (const __attribute__((address_space(1))) void*)(Bg + (size_t)row * 384 + k0 + csrc * 8),
            (__attribute__((address_space(3))) void*)(&Bs[idx * 8]), 16, 0, 0);
      }
      __syncthreads();
#pragma unroll
      for (int ks = 0; ks < 2; ks++) {
        short8n af[4], bfr[4];
        int cdata = ks * 4 + kc;
#pragma unroll
        for (int m = 0; m < 4; m++) {
          int row = wr * 64 + m * 16 + r15;
          af[m] = *reinterpret_cast<const short8n*>(&As[row * 64 + (cdata ^ (row & 7)) * 8]);
          int col = wc * 64 + m * 16 + r15;
          bfr[m] = *reinterpret_cast<const short8n*>(&Bs[col * 64 + (cdata ^ (col & 7)) * 8]);
        }
#pragma unroll
        for (int m = 0; m < 4; m++)
#pragma unroll
          for (int n = 0; n < 4; n++)
            acc[m][n] = __builtin_amdgcn_mfma_f32_16x16x32_bf16(af[m], bfr[n], acc[m][n], 0, 0, 0);
      }
    }
  }
  // transposed epilogue: lane holds 4 consecutive l for fixed d -> float4 along l
  float cbv[4];
#pragma unroll
  for (int n = 0; n < 4; n++) cbv[n] = cb[n0 + wc * 64 + n * 16 + r15];
  size_t tbase = (size_t)(b * SEQR + 1) * ND;
#pragma unroll
  for (int n = 0; n < 4; n++) {
    int drow = gg * ND + n0 + wc * 64 + n * 16 + r15;
#pragma unroll
    for (int m = 0; m < 4; m++) {
      int lcol = l0 + wr * 64 + m * 16 + kc * 4;
      float4 v = {acc[m][n][0] + cbv[n], acc[m][n][1] + cbv[n],
                  acc[m][n][2] + cbv[n], acc[m][n][3] + cbv[n]};
      *reinterpret_cast<float4*>(&outp[tbase + (size_t)drow * NL + lcol]) = v;
    }
  }
}

// ---------------------------------------------------------------- FFT fwd: DIF, natural-in, bitrev-out
__global__ __launch_bounds__(256) void k_fft_fwd(const float* __restrict__ twid,
                                                 float* __restrict__ outp,
                                                 float* __restrict__ imT) {
  int bid = blockIdx.x;
  int b = bid / 288;
  int rloc = (bid % 288) * 4;
  size_t rbase = (size_t)(b * SEQR + 1) * ND + (size_t)rloc * NL;
  size_t ibase = ((size_t)b * NG * ND + rloc) * NL;
  int tid = threadIdx.x;
  __shared__ float sre[4][1024];
  __shared__ float sim[4][1024];
  for (int idx = tid; idx < 4096; idx += 256) {
    int line = idx >> 10, pos = idx & 1023;
    sre[line][pos] = outp[rbase + (size_t)line * NL + pos];
    sim[line][pos] = 0.0f;
  }
  __syncthreads();
  for (int s = 9; s >= 0; s--) {
    int m = 1 << s;
    for (int bt = tid; bt < 2048; bt += 256) {
      int line = bt >> 9, j = bt & 511;
      int jj = j & (m - 1), grp = j >> s;
      int p0 = (grp << (s + 1)) + jj, p1 = p0 + m;
      int ti = jj << (9 - s);
      float twr = twid[2 * ti], twi = twid[2 * ti + 1];
      float ar = sre[line][p0], ai = sim[line][p0];
      float br_ = sre[line][p1], bi = sim[line][p1];
      float dr = ar - br_, di = ai - bi;
      sre[line][p0] = ar + br_; sim[line][p0] = ai + bi;
      sre[line][p1] = dr * twr - di * twi;
      sim[line][p1] = dr * twi + di * twr;
    }
    __syncthreads();
  }
  for (int idx = tid; idx < 4096; idx += 256) {
    int line = idx >> 10, pos = idx & 1023;
    outp[rbase + (size_t)line * NL + pos] = sre[line][pos];
    imT[ibase + (size_t)line * NL + pos] = sim[line][pos];
  }
}

// ---------------------------------------------------------------- FFT inv: DIT, bitrev-in, natural-out
__global__ __launch_bounds__(256) void k_fft_inv(const float* __restrict__ twid,
                                                 const float* __restrict__ outp,
                                                 float* __restrict__ imT) {
  int bid = blockIdx.x;
  int b = bid / 288;
  int rloc = (bid % 288) * 4;
  size_t rbase = (size_t)(b * SEQR + 1) * ND + (size_t)rloc * NL;
  size_t ibase = ((size_t)b * NG * ND + rloc) * NL;
  int tid = threadIdx.x;
  __shared__ float sre[4][1024];
  __shared__ float sim[4][1024];
  for (int idx = tid; idx < 4096; idx += 256) {
    int line = idx >> 10, pos = idx & 1023;
    sre[line][pos] = outp[rbase + (size_t)line * NL + pos];
    sim[line][pos] = imT[ibase + (size_t)line * NL + pos];
  }
  __syncthreads();
  for (int s = 0; s < 10; s++) {
    int m = 1 << s;
    for (int bt = tid; bt < 2048; bt += 256) {
      int line = bt >> 9, j = bt & 511;
      int jj = j & (m - 1), grp = j >> s;
      int p0 = (grp << (s + 1)) + jj, p1 = p0 + m;
      int ti = jj << (9 - s);
      float twr = twid[2 * ti];
      float twi = -twid[2 * ti + 1];      // conj for inverse
      float re1 = sre[line][p1], im1 = sim[line][p1];
      float tr = re1 * twr - im1 * twi;
      float tq = re1 * twi + im1 * twr;
      float re0 = sre[line][p0], im0 = sim[line][p0];
      sre[line][p1] = re0 - tr; sim[line][p1] = im0 - tq;
      sre[line][p0] = re0 + tr; sim[line][p0] = im0 + tq;
    }
    __syncthreads();
  }
  const float sc = 1.0f / 1024.0f;
  for (int idx = tid; idx < 4096; idx += 256) {
    int line = idx >> 10, pos = idx & 1023;
    imT[ibase + (size_t)line * NL + pos] = sre[line][pos] * sc;
  }
}

// ---------------------------------------------------------------- final transpose [d][l] -> [l][d]
__global__ __launch_bounds__(256) void k_tr(const float* __restrict__ src,
                                            float* __restrict__ dst) {
  int bid = blockIdx.x;
  int dt = bid % 6; int r1 = bid / 6;
  int lt = r1 % 16; int r2 = r1 / 16;
  int gg = r2 % NG; int b = r2 / NG;
  int tid = threadIdx.x;
  __shared__ float T[64][67];
  size_t sbase = ((size_t)b * NG * ND + gg * ND + dt * 64) * NL + lt * 64;
  for (int c = tid; c < 64 * 16; c += 256) {
    int r = c >> 4, cc = c & 15;
    float4 v = *reinterpret_cast<const float4*>(&src[sbase + (size_t)r * NL + cc * 4]);
    T[r][cc * 4 + 0] = v.x; T[r][cc * 4 + 1] = v.y;
    T[r][cc * 4 + 2] = v.z; T[r][cc * 4 + 3] = v.w;
  }
  __syncthreads();
  size_t dbase = ((size_t)b * SEQR + 1 + (size_t)gg * NL + lt * 64) * ND + dt * 64;
  for (int c = tid; c < 64 * 16; c += 256) {
    int r = c >> 4, cc = c & 15;
    float4 v = {T[cc * 4 + 0][r], T[cc * 4 + 1][r], T[cc * 4 + 2][r], T[cc * 4 + 3][r]};
    *reinterpret_cast<float4*>(&dst[dbase + (size_t)r * ND + cc * 4]) = v;
  }
}

// ---------------------------------------------------------------- band MLP (reads DC = storage pos 0)
__global__ __launch_bounds__(96) void k_bd(const float* __restrict__ outp,
    const float* __restrict__ W1, const float* __restrict__ b1,
    const float* __restrict__ gam, const float* __restrict__ bet,
    const float* __restrict__ W2, const float* __restrict__ b2,
    float* __restrict__ bwout) {
  int bid = blockIdx.x;
  int b = bid / NG, gg = bid % NG;
  int tid = threadIdx.x;
  __shared__ float xm[ND];
  __shared__ float hs[NH];
  __shared__ float o3[3];
  size_t dcbase = (size_t)(b * SEQR + 1) * ND + (size_t)(gg * ND) * NL;
  for (int i = tid; i < ND; i += NH) xm[i] = outp[dcbase + (size_t)i * NL] * (1.0f / NL);
  __syncthreads();
  float acc = b1[tid];
  for (int i = 0; i < ND; i++) acc += xm[i] * W1[i * NH + tid];
  hs[tid] = acc;
  __syncthreads();
  float s = 0, sq = 0;
  for (int i = 0; i < NH; i++) { float v = hs[i]; s += v; sq += v * v; }
  float m = s * (1.0f / NH), var = sq * (1.0f / NH) - m * m;
  float hn = fmaxf((acc - m) * rsqrtf(var + 1e-5f) * gam[tid] + bet[tid], 0.0f);
  __syncthreads();
  hs[tid] = hn;
  __syncthreads();
  if (tid < 3) {
    float o = b2[tid];
    for (int k = 0; k < NH; k++) o += hs[k] * W2[k * 3 + tid];
    o3[tid] = o;
  }
  __syncthreads();
  if (tid < 3) {
    float mx = fmaxf(o3[0], fmaxf(o3[1], o3[2]));
    float ssum = expf(o3[0] - mx) + expf(o3[1] - mx) + expf(o3[2] - mx);
    bwout[bid * 3 + tid] = expf(o3[tid] - mx) / ssum;
  }
}

// ---------------------------------------------------------------- mag/phase MLPs via MFMA + modulate
// AROW=32 tile; waves 0-1 = mag branch, waves 2-3 = phase branch.
// APAD=390: scatter lane-stride 780 dwords = 12 mod 32 -> 2 lanes/bank (free).
#define AROW 32
#define APAD 390
#define HPAD 104
__global__ __launch_bounds__(256) void k_att3(
    float* __restrict__ reT, float* __restrict__ imT,
    const __hip_bfloat16* __restrict__ W1A,
    const __hip_bfloat16* __restrict__ W2A,
    const float* __restrict__ mgb1, const float* __restrict__ mgg,
    const float* __restrict__ mgbe, const float* __restrict__ mgb2,
    const float* __restrict__ phb1, const float* __restrict__ phg,
    const float* __restrict__ phbe, const float* __restrict__ phb2,
    const float* __restrict__ bwp) {
  int bid = blockIdx.x;
  int bg = bid >> 5; int tile = bid & 31;
  int b = bg / NG, gg = bg % NG;
  int l0 = tile * AROW;                // storage-position base
  int tid = threadIdx.x;
  int lane = tid & 63, wid = tid >> 6;
  int r15 = lane & 15, kc = lane >> 4;
  int br = wid >> 1;                   // branch: 0=mag, 1=phase
  int wl = (wid & 1) * 16 + r15;       // this lane's column (pos in tile)

  __shared__ short Am[AROW * APAD];    // stage1: bf16 mag; stage3: fp16 ma
  __shared__ short Ap[AROW * APAD];    // stage1: bf16 phase; stage3: fp16 pa
  __shared__ short ht0[AROW * HPAD];
  __shared__ short ht1[AROW * HPAD];
  __shared__ float s_b1[2][NH], s_g[2][NH], s_be[2][NH];
  __shared__ float s_b2[2][ND];
  __shared__ float s_wm[AROW];

  size_t rb = (size_t)(b * SEQR + 1) * ND + (size_t)(gg * ND) * NL;
  size_t ib = ((size_t)b * NG * ND + gg * ND) * NL;

  if (tid < NH) {
    s_b1[0][tid] = mgb1[tid]; s_b1[1][tid] = phb1[tid];
    s_g[0][tid]  = mgg[tid];  s_g[1][tid]  = phg[tid];
    s_be[0][tid] = mgbe[tid]; s_be[1][tid] = phbe[tid];
  }
  for (int i = tid; i < ND; i += 256) { s_b2[0][i] = mgb2[i]; s_b2[1][i] = phb2[i]; }
  if (tid < AROW) {   // band weight per storage position (true bin = brev10(pos))
    int k = (int)(__brev((unsigned)(l0 + tid)) >> 22);
    int fr = (k <= 512) ? k : (1024 - k);
    int bwb = (b * NG + gg) * 3;
    s_wm[tid] = (fr <= 128) ? bwp[bwb] : ((fr <= 256) ? bwp[bwb + 1] : bwp[bwb + 2]);
  }

  // stage 1: coalesced [d][l] reads, scatter bf16 mag/phase into Am/Ap[pos][d]
  for (int i = tid; i < ND * 8; i += 256) {
    int d = i >> 3, lc = i & 7;
    size_t off = (size_t)d * NL + l0 + lc * 4;
    float4 re = *reinterpret_cast<const float4*>(&reT[rb + off]);
    float4 im = *reinterpret_cast<const float4*>(&imT[ib + off]);
    float rr[4] = {re.x, re.y, re.z, re.w};
    float ii[4] = {im.x, im.y, im.z, im.w};
#pragma unroll
    for (int j = 0; j < 4; j++) {
      int row = lc * 4 + j;
      Am[row * APAD + d] = bfx(sqrtf(rr[j] * rr[j] + ii[j] * ii[j]));
      Ap[row * APAD + d] = bfx(fast_atan2f(ii[j], rr[j]));
    }
  }
  __syncthreads();

  // GEMM1 (this wave's branch only) -> LN -> relu -> ht (bf16)
  {
    const short* Abuf = br ? Ap : Am;
    short* htb = br ? ht1 : ht0;
    const __hip_bfloat16* W1b = W1A + (size_t)br * 36864;
    f32x4 hacc[6];
#pragma unroll
    for (int f = 0; f < 6; f++) {
#pragma unroll
      for (int j = 0; j < 4; j++) hacc[f][j] = s_b1[br][f * 16 + kc * 4 + j];
    }
    for (int kk = 0; kk < 12; kk++) {
      short8n bx = *reinterpret_cast<const short8n*>(&Abuf[wl * APAD + kk * 32 + kc * 8]);
#pragma unroll
      for (int f = 0; f < 6; f++) {
        short8n aw = *reinterpret_cast<const short8n*>(
            (const void*)(W1b + (((size_t)kk * 6 + f) * 64 + lane) * 8));
        hacc[f] = __builtin_amdgcn_mfma_f32_16x16x32_bf16(aw, bx, hacc[f], 0, 0, 0);
      }
    }
    float s = 0.f, sq = 0.f;
#pragma unroll
    for (int f = 0; f < 6; f++)
#pragma unroll
      for (int j = 0; j < 4; j++) { float v = hacc[f][j]; s += v; sq += v * v; }
    s += __shfl_xor(s, 16, 64); s += __shfl_xor(s, 32, 64);
    sq += __shfl_xor(sq, 16, 64); sq += __shfl_xor(sq, 32, 64);
    float mean = s * (1.0f / NH);
    float var = sq * (1.0f / NH) - mean * mean;
    float rstd = rsqrtf(var + 1e-5f);
#pragma unroll
    for (int f = 0; f < 6; f++) {
      short4n hq;
#pragma unroll
      for (int j = 0; j < 4; j++) {
        int m = f * 16 + kc * 4 + j;
        float hn = fmaxf((hacc[f][j] - mean) * rstd * s_g[br][m] + s_be[br][m], 0.0f);
        ((short*)&hq)[j] = bfx(hn);
      }
      *reinterpret_cast<short4n*>(&htb[wl * HPAD + f * 16 + kc * 4]) = hq;
    }
  }
  __syncthreads();

  // GEMM2 (this wave's branch): 24 fg chunks over 384 d; stash fp16 act into Am/Ap
  {
    const short* htb = br ? ht1 : ht0;
    const __hip_bfloat16* W2b = W2A + (size_t)br * 36864;
    short* stash = br ? Ap : Am;
    short8n bh[3];
#pragma unroll
    for (int kk = 0; kk < 3; kk++)
      bh[kk] = *reinterpret_cast<const short8n*>(&htb[wl * HPAD + kk * 32 + kc * 8]);
#pragma unroll
    for (int chunk = 0; chunk < 4; chunk++) {
      f32x4 aX[6];
#pragma unroll
      for (int f = 0; f < 6; f++) {
        int dbase = (chunk * 6 + f) * 16 + kc * 4;
#pragma unroll
        for (int j = 0; j < 4; j++) aX[f][j] = s_b2[br][dbase + j];
      }
#pragma unroll
      for (int kk = 0; kk < 3; kk++) {
#pragma unroll
        for (int f = 0; f < 6; f++) {
          int fg = chunk * 6 + f;
          short8n aw = *reinterpret_cast<const short8n*>(
              (const void*)(W2b + (((size_t)kk * 24 + fg) * 64 + lane) * 8));
          aX[f] = __builtin_amdgcn_mfma_f32_16x16x32_bf16(aw, bh[kk], aX[f], 0, 0, 0);
        }
      }
#pragma unroll
      for (int f = 0; f < 6; f++) {
        int dbase = (chunk * 6 + f) * 16 + kc * 4;
        short4n q;
#pragma unroll
        for (int j = 0; j < 4; j++) {
          float v = br ? fast_tanh(aX[f][j]) : fast_sigmoid(aX[f][j]);
          ((short*)&q)[j] = hfx(v);
        }
        *reinterpret_cast<short4n*>(&stash[wl * APAD + dbase]) = q;
      }
    }
  }
  __syncthreads();

  // final pass: coalesced modulate of reT/imT in place
  for (int i = tid; i < ND * 8; i += 256) {
    int d = i >> 3, lc = i & 7;
    size_t off = (size_t)d * NL + l0 + lc * 4;
    float4 re = *reinterpret_cast<const float4*>(&reT[rb + off]);
    float4 im = *reinterpret_cast<const float4*>(&imT[ib + off]);
    float rr[4] = {re.x, re.y, re.z, re.w};
    float ii[4] = {im.x, im.y, im.z, im.w};
    float4 ro, io;
#pragma unroll
    for (int j = 0; j < 4; j++) {
      int row = lc * 4 + j;
      float ma = xhf(Am[row * APAD + d]);
      float pa = xhf(Ap[row * APAD + d]);
      float wm = s_wm[row];
      float mag = sqrtf(rr[j] * rr[j] + ii[j] * ii[j]);
      float ph = fast_atan2f(ii[j], rr[j]);
      float mago = mag * wm * ma;
      float pho = ph * wm + pa;
      float cs = __cosf(pho), sn = __sinf(pho);
      ((float*)&ro)[j] = mago * cs;
      ((float*)&io)[j] = mago * sn;
    }
    *reinterpret_cast<float4*>(&reT[rb + off]) = ro;
    *reinterpret_cast<float4*>(&imT[ib + off]) = io;
  }
}

// ---------------------------------------------------------------- launch
extern "C" void kernel_launch(void* const* d_in, const int* in_sizes, int n_in,
                              void* d_out, int out_size, void* d_ws, size_t ws_size,
                              hipStream_t stream) {
  (void)in_sizes; (void)n_in; (void)out_size; (void)ws_size;
  const float* x     = (const float*)d_in[0];
  const float* mgW1  = (const float*)d_in[1];
  const float* mgb1  = (const float*)d_in[2];
  const float* mgg   = (const float*)d_in[3];
  const float* mgbe  = (const float*)d_in[4];
  const float* mgW2  = (const float*)d_in[5];
  const float* mgb2  = (const float*)d_in[6];
  const float* phW1  = (const float*)d_in[7];
  const float* phb1  = (const float*)d_in[8];
  const float* phg   = (const float*)d_in[9];
  const float* phbe  = (const float*)d_in[10];
  const float* phW2  = (const float*)d_in[11];
  const float* phb2  = (const float*)d_in[12];
  const float* bdW1  = (const float*)d_in[13];
  const float* bdb1  = (const float*)d_in[14];
  const float* bdg   = (const float*)d_in[15];
  const float* bdbe  = (const float*)d_in[16];
  const float* bdW2  = (const float*)d_in[17];
  const float* bdb2  = (const float*)d_in[18];
  const float* cgW1  = (const float*)d_in[19];
  const float* cgb1  = (const float*)d_in[20];
  const float* cgg   = (const float*)d_in[21];
  const float* cgbe  = (const float*)d_in[22];
  const float* cgW2  = (const float*)d_in[23];
  const float* cgb2  = (const float*)d_in[24];
  const float* convW = (const float*)d_in[25];
  const float* convB = (const float*)d_in[26];

  float* outp = (float*)d_out;
  float* wsf  = (float*)d_ws;
  // ws region0 (151MB): gatedA (bf16) during gate->conv, then imT (fp32) for FFT onward
  float* imT = wsf;
  __hip_bfloat16* gatedA = (__hip_bfloat16*)wsf;
  char* p = (char*)(wsf + (size_t)NB * NG * NL * ND);
  __hip_bfloat16* Wt2 = (__hip_bfloat16*)p;           p += (size_t)384 * 384 * 3 * 2;
  float* twid = (float*)p;                            p += 1024 * 4;
  float* bwp  = (float*)p;                            p += 512 * 4;
  __hip_bfloat16* W1A = (__hip_bfloat16*)p;           p += (size_t)2 * 36864 * 2;
  __hip_bfloat16* W2A = (__hip_bfloat16*)p;           p += (size_t)2 * 36864 * 2;
  __hip_bfloat16* W1G = (__hip_bfloat16*)p;           p += (size_t)147456 * 2;

  k_prep<<<dim3(2930), dim3(256), 0, stream>>>(convW, x, mgW1, phW1, mgW2, phW2, cgW1,
                                               Wt2, twid, W1A, W2A, W1G, outp);
  k_gate2<<<dim3(NB * 64), dim3(256), 0, stream>>>(x, W1G, cgb1, cgg, cgbe, cgW2, cgb2, gatedA);
  k_conv_mfma<<<dim3(NB * NG * 8 * 3), dim3(256), 0, stream>>>(gatedA, Wt2, convB, outp);
  k_fft_fwd<<<dim3(NB * 288), dim3(256), 0, stream>>>(twid, outp, imT);
  k_bd<<<dim3(NB * NG), dim3(96), 0, stream>>>(outp, bdW1, bdb1, bdg, bdbe, bdW2, bdb2, bwp);
  k_att3<<<dim3(NB * NG * 32), dim3(256), 0, stream>>>(outp, imT,
      W1A, W2A, mgb1, mgg, mgbe, mgb2, phb1, phg, phbe, phb2, bwp);
  k_fft_inv<<<dim3(NB * 288), dim3(256), 0, stream>>>(twid, outp, imT);
  k_tr<<<dim3(NB * NG * 16 * 6), dim3(256), 0, stream>>>(imT, outp);
}

// Round 7
// 1033.837 us; speedup vs baseline: 3.8874x; 1.0739x over previous
//
#include <hip/hip_runtime.h>
#include <hip/hip_bf16.h>
#include <hip/hip_fp16.h>
#include <math.h>

#define NB 32
#define NL 1024
#define NG 3
#define ND 384
#define NH 96
#define NDG 192
#define SEQR 3073   // 1 + G*L

typedef __attribute__((ext_vector_type(8))) short short8n;
typedef __attribute__((ext_vector_type(4))) short short4n;
typedef __attribute__((ext_vector_type(4))) float f32x4;

__device__ __forceinline__ short bfx(float f) {
  __hip_bfloat16 h = __float2bfloat16(f);
  return *reinterpret_cast<short*>(&h);
}
__device__ __forceinline__ float xbf(short s) {
  __hip_bfloat16 h = *reinterpret_cast<__hip_bfloat16*>(&s);
  return __bfloat162float(h);
}
__device__ __forceinline__ short hfx(float f) {
  __half h = __float2half(f);
  return *reinterpret_cast<short*>(&h);
}
__device__ __forceinline__ float xhf(short s) {
  __half h = *reinterpret_cast<__half*>(&s);
  return __half2float(h);
}

// fast atan2, abs err <= ~1e-5 rad
__device__ __forceinline__ float fast_atan2f(float y, float x) {
  float ax = fabsf(x), ay = fabsf(y);
  float mx = fmaxf(ax, ay), mn = fminf(ax, ay);
  float r = (mx == 0.0f) ? 0.0f : __fdividef(mn, mx);
  float s = r * r;
  float p = fmaf(s, 0.0208351f, -0.0851330f);
  p = fmaf(s, p, 0.1801410f);
  p = fmaf(s, p, -0.3302995f);
  p = fmaf(s, p, 0.9998660f);
  p = r * p;
  float a = (ay > ax) ? (1.5707963267948966f - p) : p;
  a = (x < 0.0f) ? (3.14159265358979323846f - a) : a;
  return (y < 0.0f) ? -a : a;
}

__device__ __forceinline__ float fast_sigmoid(float x) {
  return __fdividef(1.0f, 1.0f + __expf(-x));
}
__device__ __forceinline__ float fast_tanh(float x) {
  return 1.0f - __fdividef(2.0f, 1.0f + __expf(2.0f * x));
}

// ---------------------------------------------------------------- prep
__global__ __launch_bounds__(256) void k_prep(const float* __restrict__ convW,
                                              const float* __restrict__ x,
                                              const float* __restrict__ mgW1s,
                                              const float* __restrict__ phW1s,
                                              const float* __restrict__ mgW2s,
                                              const float* __restrict__ phW2s,
                                              const float* __restrict__ cgW1s,
                                              __hip_bfloat16* __restrict__ Wt2,
                                              float* __restrict__ twid,
                                              __hip_bfloat16* __restrict__ W1Ao,
                                              __hip_bfloat16* __restrict__ W2Ao,
                                              __hip_bfloat16* __restrict__ W1Go,
                                              float* __restrict__ outp) {
  int id = blockIdx.x * 256 + threadIdx.x;
  if (id < 384 * 384 * 3) {
    int i = id % 384; int rest = id / 384; int o = rest % 384; int kh = rest / 384;
    Wt2[id] = __float2bfloat16(convW[(o * 384 + i) * 3 + kh]);
    return;
  }
  int id2 = id - 384 * 384 * 3;
  if (id2 < 512) {
    float ang = -6.283185307179586f * (float)id2 / 1024.0f;
    float s, c; sincosf(ang, &s, &c);
    twid[2 * id2] = c; twid[2 * id2 + 1] = s;
    return;
  }
  int id3 = id2 - 512;
  if (id3 < NB * ND) {
    int b = id3 / ND, d = id3 % ND;
    outp[(size_t)b * SEQR * ND + d] = x[(size_t)b * SEQR * ND + d];
    return;
  }
  int id4 = id3 - NB * ND;
  if (id4 < 2 * 36864) {   // W1A: [br][kk(12)][f(6)][lane(64)][8]
    int br = id4 / 36864, idx = id4 % 36864;
    int j = idx & 7, ln = (idx >> 3) & 63, rest = idx >> 9;
    int f = rest % 6, kk = rest / 6;
    int m = f * 16 + (ln & 15), k = kk * 32 + (ln >> 4) * 8 + j;
    const float* W = br ? phW1s : mgW1s;
    W1Ao[id4] = __float2bfloat16(W[k * NH + m]);
    return;
  }
  int id5 = id4 - 2 * 36864;
  if (id5 < 2 * 36864) {   // W2A: [br][kk(3)][f(24)][lane(64)][8]
    int br = id5 / 36864, idx = id5 % 36864;
    int j = idx & 7, ln = (idx >> 3) & 63, rest = idx >> 9;
    int f = rest % 24, kk = rest / 24;
    int d = f * 16 + (ln & 15), k = kk * 32 + (ln >> 4) * 8 + j;
    const float* W = br ? phW2s : mgW2s;
    W2Ao[id5] = __float2bfloat16(W[k * ND + d]);
    return;
  }
  int id6 = id5 - 2 * 36864;
  if (id6 < 147456) {      // W1G: [part(2)][kk(12)][f(12)][lane(64)][8]
    int j = id6 & 7, ln = (id6 >> 3) & 63, rest = id6 >> 9;
    int f = rest % 12, rest2 = rest / 12;
    int kk = rest2 % 12, part = rest2 / 12;
    int m = f * 16 + (ln & 15), k = part * 384 + kk * 32 + (ln >> 4) * 8 + j;
    W1Go[id6] = __float2bfloat16(cgW1s[k * NDG + m]);
  }
}

// ---------------------------------------------------------------- gate MLP via MFMA
__global__ __launch_bounds__(256) void k_gate2(const float* __restrict__ x,
    const __hip_bfloat16* __restrict__ W1G,
    const float* __restrict__ b1, const float* __restrict__ gam,
    const float* __restrict__ bet, const float* __restrict__ W2,
    const float* __restrict__ b2p,
    __hip_bfloat16* __restrict__ gatedA) {
  int bid = blockIdx.x;
  int b = bid >> 6; int l0 = (bid & 63) * 16;
  int tid = threadIdx.x;
  int lane = tid & 63, wid = tid >> 6;
  int r15 = lane & 15, kc = lane >> 4;

  __shared__ short xs[3][16][392];
  __shared__ short gs[16][392];
  __shared__ float hG[16][196];
  __shared__ float s_b1[NDG], s_g[NDG], s_be[NDG], s_w2[NDG];
  __shared__ float sgate[3][16];

  if (tid < NDG) {
    s_b1[tid] = b1[tid]; s_g[tid] = gam[tid];
    s_be[tid] = bet[tid]; s_w2[tid] = W2[tid];
  }
  for (int c = tid; c < 16 * 96; c += 256) {
    int l = c / 96, d4 = (c % 96) * 4;
    size_t base = ((size_t)b * SEQR + 1 + l0 + l) * ND + d4;
    float4 v0 = *reinterpret_cast<const float4*>(&x[base]);
    float4 v1 = *reinterpret_cast<const float4*>(&x[base + (size_t)NL * ND]);
    float4 v2 = *reinterpret_cast<const float4*>(&x[base + (size_t)2 * NL * ND]);
    short4n q0, q1, q2, qg;
    q0.x = bfx(v0.x); q0.y = bfx(v0.y); q0.z = bfx(v0.z); q0.w = bfx(v0.w);
    q1.x = bfx(v1.x); q1.y = bfx(v1.y); q1.z = bfx(v1.z); q1.w = bfx(v1.w);
    q2.x = bfx(v2.x); q2.y = bfx(v2.y); q2.z = bfx(v2.z); q2.w = bfx(v2.w);
    qg.x = bfx((v0.x + v1.x + v2.x) * (1.0f / 3.0f));
    qg.y = bfx((v0.y + v1.y + v2.y) * (1.0f / 3.0f));
    qg.z = bfx((v0.z + v1.z + v2.z) * (1.0f / 3.0f));
    qg.w = bfx((v0.w + v1.w + v2.w) * (1.0f / 3.0f));
    *reinterpret_cast<short4n*>(&xs[0][l][d4]) = q0;
    *reinterpret_cast<short4n*>(&xs[1][l][d4]) = q1;
    *reinterpret_cast<short4n*>(&xs[2][l][d4]) = q2;
    *reinterpret_cast<short4n*>(&gs[l][d4]) = qg;
  }
  __syncthreads();

  const short* bsrc = (wid == 3) ? &gs[0][0] : &xs[wid][0][0];
  const __hip_bfloat16* W1b = W1G + (size_t)(wid == 3 ? 1 : 0) * 73728;
  f32x4 hacc[12];
#pragma unroll
  for (int f = 0; f < 12; f++)
#pragma unroll
    for (int j = 0; j < 4; j++)
      hacc[f][j] = (wid == 3) ? 0.0f : s_b1[f * 16 + kc * 4 + j];
  for (int kk = 0; kk < 12; kk++) {
    short8n bx = *reinterpret_cast<const short8n*>(&bsrc[r15 * 392 + kk * 32 + kc * 8]);
#pragma unroll
    for (int f = 0; f < 12; f++) {
      short8n aw = *reinterpret_cast<const short8n*>(
          (const void*)(W1b + (((size_t)kk * 12 + f) * 64 + lane) * 8));
      hacc[f] = __builtin_amdgcn_mfma_f32_16x16x32_bf16(aw, bx, hacc[f], 0, 0, 0);
    }
  }
  if (wid == 3) {
#pragma unroll
    for (int f = 0; f < 12; f++)
#pragma unroll
      for (int j = 0; j < 4; j++)
        hG[r15][f * 16 + kc * 4 + j] = hacc[f][j];
  }
  __syncthreads();
  if (wid < 3) {
    float s = 0.f, sq = 0.f;
#pragma unroll
    for (int f = 0; f < 12; f++)
#pragma unroll
      for (int j = 0; j < 4; j++) {
        float v = hacc[f][j] + hG[r15][f * 16 + kc * 4 + j];
        hacc[f][j] = v; s += v; sq += v * v;
      }
    s += __shfl_xor(s, 16, 64); s += __shfl_xor(s, 32, 64);
    sq += __shfl_xor(sq, 16, 64); sq += __shfl_xor(sq, 32, 64);
    float mean = s * (1.0f / NDG);
    float var = sq * (1.0f / NDG) - mean * mean;
    float rstd = rsqrtf(var + 1e-5f);
    float dot = 0.f;
#pragma unroll
    for (int f = 0; f < 12; f++)
#pragma unroll
      for (int j = 0; j < 4; j++) {
        int m = f * 16 + kc * 4 + j;
        float hn = fmaxf((hacc[f][j] - mean) * rstd * s_g[m] + s_be[m], 0.0f);
        dot += hn * s_w2[m];
      }
    dot += __shfl_xor(dot, 16, 64); dot += __shfl_xor(dot, 32, 64);
    float gate = fast_sigmoid(dot + b2p[0]);
    if (lane < 16) sgate[wid][r15] = gate;
  }
  __syncthreads();
  if (wid < 3) {
    size_t obase = (((size_t)b * NG + wid) * NL + l0) * ND;
    for (int c = lane; c < 16 * 96; c += 64) {
      int l = c / 96, d4 = (c % 96) * 4;
      float gt = sgate[wid][l];
      short4n qx = *reinterpret_cast<const short4n*>(&xs[wid][l][d4]);
      short4n qg = *reinterpret_cast<const short4n*>(&gs[l][d4]);
      short4n qo;
#pragma unroll
      for (int j = 0; j < 4; j++) {
        float xv = xbf(((short*)&qx)[j]);
        float gv = xbf(((short*)&qg)[j]);
        ((short*)&qo)[j] = bfx(xv * gt + gv * (1.0f - gt));
      }
      *reinterpret_cast<short4n*>(&((short*)gatedA)[obase + (size_t)l * ND + d4]) = qo;
    }
  }
}

// ---------------------------------------------------------------- conv as bf16 MFMA GEMM
// output written TRANSPOSED: reT[b][(g*384+d)][l] at base outp + (b*SEQR+1)*ND
#define BKC 64
__global__ __launch_bounds__(256) void k_conv_mfma(
    const __hip_bfloat16* __restrict__ Abuf,
    const __hip_bfloat16* __restrict__ Wt2,
    const float* __restrict__ cb,
    float* __restrict__ outp) {
  int bid = blockIdx.x;
  int ct = bid % 3; int rest = bid / 3;
  int rt = rest % 8; int bg = rest / 8;
  int b = bg / NG, gg = bg % NG;
  int l0 = rt * 128;
  int n0 = ct * 128;
  int tid = threadIdx.x;
  int lane = tid & 63, wid = tid >> 6;
  int wr = wid >> 1, wc = wid & 1;
  int r15 = lane & 15, kc = lane >> 4;

  __shared__ short As[128 * BKC];
  __shared__ short Bs[128 * BKC];

  f32x4 acc[4][4];
#pragma unroll
  for (int m = 0; m < 4; m++)
#pragma unroll
    for (int n = 0; n < 4; n++) acc[m][n] = (f32x4){0.f, 0.f, 0.f, 0.f};

  for (int kh = 0; kh < 3; kh++) {
    int gs = gg + kh - 1;
    if (gs < 0 || gs >= NG) continue;
    const __hip_bfloat16* Ag = Abuf + (((size_t)b * NG + gs) * NL + l0) * ND;
    const __hip_bfloat16* Bg = Wt2 + ((size_t)kh * 384 + n0) * 384;
    for (int k0 = 0; k0 < 384; k0 += BKC) {
      __syncthreads();
#pragma unroll
      for (int p = 0; p < 4; p++) {
        int idx = p * 256 + tid;
        int row = idx >> 3, c = idx & 7;
        int csrc = c ^ (row & 7);
        __builtin_amdgcn_global_load_lds(
            (const __attribute__((address_space(1))) void*)(Ag + (size_t)row * ND + k0 + csrc * 8),
            (__attribute__((address_space(3))) void*)(&As[idx * 8]), 16, 0, 0);
      }
#pragma unroll
      for (int p = 0; p < 4; p++) {
        int idx = p * 256 + tid;
        int row = idx >> 3, c = idx & 7;
        int csrc = c ^ (row & 7);
        __builtin_amdgcn_global_load_lds(
            (const __attribute__((address_space(1))) void*)(Bg + (size_t)row * 384 + k0 + csrc * 8),
            (__attribute__((address_space(3))) void*)(&Bs[idx * 8]), 16, 0, 0);
      }
      __syncthreads();
#pragma unroll
      for (int ks = 0; ks < 2; ks++) {
        short8n af[4], bfr[4];
        int cdata = ks * 4 + kc;
#pragma unroll
        for (int m = 0; m < 4; m++) {
          int row = wr * 64 + m * 16 + r15;
          af[m] = *reinterpret_cast<const short8n*>(&As[row * 64 + (cdata ^ (row & 7)) * 8]);
          int col = wc * 64 + m * 16 + r15;
          bfr[m] = *reinterpret_cast<const short8n*>(&Bs[col * 64 + (cdata ^ (col & 7)) * 8]);
        }
#pragma unroll
        for (int m = 0; m < 4; m++)
#pragma unroll
          for (int n = 0; n < 4; n++)
            acc[m][n] = __builtin_amdgcn_mfma_f32_16x16x32_bf16(af[m], bfr[n], acc[m][n], 0, 0, 0);
      }
    }
  }
  // transposed epilogue: lane holds 4 consecutive l for fixed d -> float4 along l
  float cbv[4];
#pragma unroll
  for (int n = 0; n < 4; n++) cbv[n] = cb[n0 + wc * 64 + n * 16 + r15];
  size_t tbase = (size_t)(b * SEQR + 1) * ND;
#pragma unroll
  for (int n = 0; n < 4; n++) {
    int drow = gg * ND + n0 + wc * 64 + n * 16 + r15;
#pragma unroll
    for (int m = 0; m < 4; m++) {
      int lcol = l0 + wr * 64 + m * 16 + kc * 4;
      float4 v = {acc[m][n][0] + cbv[n], acc[m][n][1] + cbv[n],
                  acc[m][n][2] + cbv[n], acc[m][n][3] + cbv[n]};
      *reinterpret_cast<float4*>(&outp[tbase + (size_t)drow * NL + lcol]) = v;
    }
  }
}

// ---------------------------------------------------------------- FFT fwd: DIF, natural-in, bitrev-out
__global__ __launch_bounds__(256) void k_fft_fwd(const float* __restrict__ twid,
                                                 float* __restrict__ outp,
                                                 float* __restrict__ imT) {
  int bid = blockIdx.x;
  int b = bid / 288;
  int rloc = (bid % 288) * 4;
  size_t rbase = (size_t)(b * SEQR + 1) * ND + (size_t)rloc * NL;
  size_t ibase = ((size_t)b * NG * ND + rloc) * NL;
  int tid = threadIdx.x;
  __shared__ float sre[4][1024];
  __shared__ float sim[4][1024];
  for (int idx = tid; idx < 4096; idx += 256) {
    int line = idx >> 10, pos = idx & 1023;
    sre[line][pos] = outp[rbase + (size_t)line * NL + pos];
    sim[line][pos] = 0.0f;
  }
  __syncthreads();
  for (int s = 9; s >= 0; s--) {
    int m = 1 << s;
    for (int bt = tid; bt < 2048; bt += 256) {
      int line = bt >> 9, j = bt & 511;
      int jj = j & (m - 1), grp = j >> s;
      int p0 = (grp << (s + 1)) + jj, p1 = p0 + m;
      int ti = jj << (9 - s);
      float twr = twid[2 * ti], twi = twid[2 * ti + 1];
      float ar = sre[line][p0], ai = sim[line][p0];
      float br_ = sre[line][p1], bi = sim[line][p1];
      float dr = ar - br_, di = ai - bi;
      sre[line][p0] = ar + br_; sim[line][p0] = ai + bi;
      sre[line][p1] = dr * twr - di * twi;
      sim[line][p1] = dr * twi + di * twr;
    }
    __syncthreads();
  }
  for (int idx = tid; idx < 4096; idx += 256) {
    int line = idx >> 10, pos = idx & 1023;
    outp[rbase + (size_t)line * NL + pos] = sre[line][pos];
    imT[ibase + (size_t)line * NL + pos] = sim[line][pos];
  }
}

// ---------------------------------------------------------------- FFT inv: DIT, bitrev-in, natural-out
__global__ __launch_bounds__(256) void k_fft_inv(const float* __restrict__ twid,
                                                 const float* __restrict__ outp,
                                                 float* __restrict__ imT) {
  int bid = blockIdx.x;
  int b = bid / 288;
  int rloc = (bid % 288) * 4;
  size_t rbase = (size_t)(b * SEQR + 1) * ND + (size_t)rloc * NL;
  size_t ibase = ((size_t)b * NG * ND + rloc) * NL;
  int tid = threadIdx.x;
  __shared__ float sre[4][1024];
  __shared__ float sim[4][1024];
  for (int idx = tid; idx < 4096; idx += 256) {
    int line = idx >> 10, pos = idx & 1023;
    sre[line][pos] = outp[rbase + (size_t)line * NL + pos];
    sim[line][pos] = imT[ibase + (size_t)line * NL + pos];
  }
  __syncthreads();
  for (int s = 0; s < 10; s++) {
    int m = 1 << s;
    for (int bt = tid; bt < 2048; bt += 256) {
      int line = bt >> 9, j = bt & 511;
      int jj = j & (m - 1), grp = j >> s;
      int p0 = (grp << (s + 1)) + jj, p1 = p0 + m;
      int ti = jj << (9 - s);
      float twr = twid[2 * ti];
      float twi = -twid[2 * ti + 1];      // conj for inverse
      float re1 = sre[line][p1], im1 = sim[line][p1];
      float tr = re1 * twr - im1 * twi;
      float tq = re1 * twi + im1 * twr;
      float re0 = sre[line][p0], im0 = sim[line][p0];
      sre[line][p1] = re0 - tr; sim[line][p1] = im0 - tq;
      sre[line][p0] = re0 + tr; sim[line][p0] = im0 + tq;
    }
    __syncthreads();
  }
  const float sc = 1.0f / 1024.0f;
  for (int idx = tid; idx < 4096; idx += 256) {
    int line = idx >> 10, pos = idx & 1023;
    imT[ibase + (size_t)line * NL + pos] = sre[line][pos] * sc;
  }
}

// ---------------------------------------------------------------- final transpose [d][l] -> [l][d]
__global__ __launch_bounds__(256) void k_tr(const float* __restrict__ src,
                                            float* __restrict__ dst) {
  int bid = blockIdx.x;
  int dt = bid % 6; int r1 = bid / 6;
  int lt = r1 % 16; int r2 = r1 / 16;
  int gg = r2 % NG; int b = r2 / NG;
  int tid = threadIdx.x;
  __shared__ float T[64][67];
  size_t sbase = ((size_t)b * NG * ND + gg * ND + dt * 64) * NL + lt * 64;
  for (int c = tid; c < 64 * 16; c += 256) {
    int r = c >> 4, cc = c & 15;
    float4 v = *reinterpret_cast<const float4*>(&src[sbase + (size_t)r * NL + cc * 4]);
    T[r][cc * 4 + 0] = v.x; T[r][cc * 4 + 1] = v.y;
    T[r][cc * 4 + 2] = v.z; T[r][cc * 4 + 3] = v.w;
  }
  __syncthreads();
  size_t dbase = ((size_t)b * SEQR + 1 + (size_t)gg * NL + lt * 64) * ND + dt * 64;
  for (int c = tid; c < 64 * 16; c += 256) {
    int r = c >> 4, cc = c & 15;
    float4 v = {T[cc * 4 + 0][r], T[cc * 4 + 1][r], T[cc * 4 + 2][r], T[cc * 4 + 3][r]};
    *reinterpret_cast<float4*>(&dst[dbase + (size_t)r * ND + cc * 4]) = v;
  }
}

// ---------------------------------------------------------------- band MLP (reads DC = storage pos 0)
__global__ __launch_bounds__(96) void k_bd(const float* __restrict__ outp,
    const float* __restrict__ W1, const float* __restrict__ b1,
    const float* __restrict__ gam, const float* __restrict__ bet,
    const float* __restrict__ W2, const float* __restrict__ b2,
    float* __restrict__ bwout) {
  int bid = blockIdx.x;
  int b = bid / NG, gg = bid % NG;
  int tid = threadIdx.x;
  __shared__ float xm[ND];
  __shared__ float hs[NH];
  __shared__ float o3[3];
  size_t dcbase = (size_t)(b * SEQR + 1) * ND + (size_t)(gg * ND) * NL;
  for (int i = tid; i < ND; i += NH) xm[i] = outp[dcbase + (size_t)i * NL] * (1.0f / NL);
  __syncthreads();
  float acc = b1[tid];
  for (int i = 0; i < ND; i++) acc += xm[i] * W1[i * NH + tid];
  hs[tid] = acc;
  __syncthreads();
  float s = 0, sq = 0;
  for (int i = 0; i < NH; i++) { float v = hs[i]; s += v; sq += v * v; }
  float m = s * (1.0f / NH), var = sq * (1.0f / NH) - m * m;
  float hn = fmaxf((acc - m) * rsqrtf(var + 1e-5f) * gam[tid] + bet[tid], 0.0f);
  __syncthreads();
  hs[tid] = hn;
  __syncthreads();
  if (tid < 3) {
    float o = b2[tid];
    for (int k = 0; k < NH; k++) o += hs[k] * W2[k * 3 + tid];
    o3[tid] = o;
  }
  __syncthreads();
  if (tid < 3) {
    float mx = fmaxf(o3[0], fmaxf(o3[1], o3[2]));
    float ssum = expf(o3[0] - mx) + expf(o3[1] - mx) + expf(o3[2] - mx);
    bwout[bid * 3 + tid] = expf(o3[tid] - mx) / ssum;
  }
}

// ---------------------------------------------------------------- mag/phase MLPs via MFMA + modulate
// AROW=32; waves 0-1 = mag, 2-3 = phase. LDS ~52.7KB -> 3 blocks/CU.
// GEMM1->GEMM2 hidden handoff is in-register via 4-lane-group shuffles (no ht LDS).
#define AROW 32
#define APAD 390
__global__ __launch_bounds__(256, 3) void k_att4(
    float* __restrict__ reT, float* __restrict__ imT,
    const __hip_bfloat16* __restrict__ W1A,
    const __hip_bfloat16* __restrict__ W2A,
    const float* __restrict__ mgb1, const float* __restrict__ mgg,
    const float* __restrict__ mgbe, const float* __restrict__ mgb2,
    const float* __restrict__ phb1, const float* __restrict__ phg,
    const float* __restrict__ phbe, const float* __restrict__ phb2,
    const float* __restrict__ bwp) {
  int bid = blockIdx.x;
  int bg = bid >> 5; int tile = bid & 31;
  int b = bg / NG, gg = bg % NG;
  int l0 = tile * AROW;                // storage-position base
  int tid = threadIdx.x;
  int lane = tid & 63, wid = tid >> 6;
  int r15 = lane & 15, kc = lane >> 4;
  int br = wid >> 1;                   // branch: 0=mag, 1=phase
  int wl = (wid & 1) * 16 + r15;       // this lane's column (pos in tile)

  __shared__ short Am[AROW * APAD];    // stage1: bf16 mag; stage3: fp16 ma
  __shared__ short Ap[AROW * APAD];    // stage1: bf16 phase; stage3: fp16 pa
  __shared__ short s_b1h[2][NH], s_gh[2][NH], s_beh[2][NH];
  __shared__ short s_b2h[2][ND];
  __shared__ float s_wm[AROW];

  size_t rb = (size_t)(b * SEQR + 1) * ND + (size_t)(gg * ND) * NL;
  size_t ib = ((size_t)b * NG * ND + gg * ND) * NL;

  if (tid < NH) {
    s_b1h[0][tid] = bfx(mgb1[tid]); s_b1h[1][tid] = bfx(phb1[tid]);
    s_gh[0][tid]  = bfx(mgg[tid]);  s_gh[1][tid]  = bfx(phg[tid]);
    s_beh[0][tid] = bfx(mgbe[tid]); s_beh[1][tid] = bfx(phbe[tid]);
  }
  for (int i = tid; i < ND; i += 256) { s_b2h[0][i] = bfx(mgb2[i]); s_b2h[1][i] = bfx(phb2[i]); }
  if (tid < AROW) {   // band weight per storage position (true bin = brev10(pos))
    int k = (int)(__brev((unsigned)(l0 + tid)) >> 22);
    int fr = (k <= 512) ? k : (1024 - k);
    int bwb = (b * NG + gg) * 3;
    s_wm[tid] = (fr <= 128) ? bwp[bwb] : ((fr <= 256) ? bwp[bwb + 1] : bwp[bwb + 2]);
  }

  // stage 1: coalesced [d][l] reads (4x unroll-and-jam), scatter bf16 into Am/Ap[pos][d]
  for (int u0 = 0; u0 < 12; u0 += 4) {
    float4 rv[4], iv[4];
#pragma unroll
    for (int u = 0; u < 4; u++) {
      int i = tid + (u0 + u) * 256;
      int d = i >> 3, lc = i & 7;
      size_t off = (size_t)d * NL + l0 + lc * 4;
      rv[u] = *reinterpret_cast<const float4*>(&reT[rb + off]);
      iv[u] = *reinterpret_cast<const float4*>(&imT[ib + off]);
    }
#pragma unroll
    for (int u = 0; u < 4; u++) {
      int i = tid + (u0 + u) * 256;
      int d = i >> 3, lc = i & 7;
      float rr[4] = {rv[u].x, rv[u].y, rv[u].z, rv[u].w};
      float ii[4] = {iv[u].x, iv[u].y, iv[u].z, iv[u].w};
#pragma unroll
      for (int j = 0; j < 4; j++) {
        int row = lc * 4 + j;
        Am[row * APAD + d] = bfx(sqrtf(rr[j] * rr[j] + ii[j] * ii[j]));
        Ap[row * APAD + d] = bfx(fast_atan2f(ii[j], rr[j]));
      }
    }
  }
  __syncthreads();

  // GEMM1 (this wave's branch) -> LN -> relu -> bf16 packs in registers
  unsigned pk[6][2];    // pk[f][p] = packed bf16 (h[f][2p], h[f][2p+1])
  {
    const short* Abuf = br ? Ap : Am;
    const __hip_bfloat16* W1b = W1A + (size_t)br * 36864;
    f32x4 hacc[6];
#pragma unroll
    for (int f = 0; f < 6; f++) {
#pragma unroll
      for (int j = 0; j < 4; j++) hacc[f][j] = xbf(s_b1h[br][f * 16 + kc * 4 + j]);
    }
    for (int kk = 0; kk < 12; kk++) {
      short8n bx = *reinterpret_cast<const short8n*>(&Abuf[wl * APAD + kk * 32 + kc * 8]);
#pragma unroll
      for (int f = 0; f < 6; f++) {
        short8n aw = *reinterpret_cast<const short8n*>(
            (const void*)(W1b + (((size_t)kk * 6 + f) * 64 + lane) * 8));
        hacc[f] = __builtin_amdgcn_mfma_f32_16x16x32_bf16(aw, bx, hacc[f], 0, 0, 0);
      }
    }
    float s = 0.f, sq = 0.f;
#pragma unroll
    for (int f = 0; f < 6; f++)
#pragma unroll
      for (int j = 0; j < 4; j++) { float v = hacc[f][j]; s += v; sq += v * v; }
    s += __shfl_xor(s, 16, 64); s += __shfl_xor(s, 32, 64);
    sq += __shfl_xor(sq, 16, 64); sq += __shfl_xor(sq, 32, 64);
    float mean = s * (1.0f / NH);
    float var = sq * (1.0f / NH) - mean * mean;
    float rstd = rsqrtf(var + 1e-5f);
#pragma unroll
    for (int f = 0; f < 6; f++) {
      float hn[4];
#pragma unroll
      for (int j = 0; j < 4; j++) {
        int m = f * 16 + kc * 4 + j;
        hn[j] = fmaxf((hacc[f][j] - mean) * rstd * xbf(s_gh[br][m]) + xbf(s_beh[br][m]), 0.0f);
      }
#pragma unroll
      for (int p = 0; p < 2; p++) {
        unsigned lo = (unsigned)(unsigned short)bfx(hn[2 * p]);
        unsigned hi = (unsigned)(unsigned short)bfx(hn[2 * p + 1]);
        pk[f][p] = lo | (hi << 16);
      }
    }
  }
  __syncthreads();   // all waves done reading Am/Ap before stash overwrites

  // in-register handoff: build GEMM2 B-frags bh[kk] via 4-lane-group shuffles.
  // element k=kk*32+kc*8+jj lives in lane kc_src=(2kc+(jj>=4))&3, f=2kk+(kc>>1), j=jj&3
  short8n bh[3];
  {
    int srcA = r15 + ((( 2 * kc )     & 3) << 4);
    int srcB = r15 + (((2 * kc + 1) & 3) << 4);
    int hiF = kc >> 1;
#pragma unroll
    for (int kk = 0; kk < 3; kk++) {
      int a0l = __shfl((int)pk[kk * 2][0], srcA, 64);
      int a0h = __shfl((int)pk[kk * 2 + 1][0], srcA, 64);
      int a1l = __shfl((int)pk[kk * 2][1], srcA, 64);
      int a1h = __shfl((int)pk[kk * 2 + 1][1], srcA, 64);
      int b0l = __shfl((int)pk[kk * 2][0], srcB, 64);
      int b0h = __shfl((int)pk[kk * 2 + 1][0], srcB, 64);
      int b1l = __shfl((int)pk[kk * 2][1], srcB, 64);
      int b1h = __shfl((int)pk[kk * 2 + 1][1], srcB, 64);
      int4 tv;
      tv.x = hiF ? a0h : a0l;
      tv.y = hiF ? a1h : a1l;
      tv.z = hiF ? b0h : b0l;
      tv.w = hiF ? b1h : b1l;
      bh[kk] = *reinterpret_cast<short8n*>(&tv);
    }
  }

  // GEMM2 (this wave's branch): 4 chunks over 384 d; stash fp16 act into Am/Ap
  {
    const __hip_bfloat16* W2b = W2A + (size_t)br * 36864;
    short* stash = br ? Ap : Am;
#pragma unroll
    for (int chunk = 0; chunk < 4; chunk++) {
      f32x4 aX[6];
#pragma unroll
      for (int f = 0; f < 6; f++) {
        int dbase = (chunk * 6 + f) * 16 + kc * 4;
#pragma unroll
        for (int j = 0; j < 4; j++) aX[f][j] = xbf(s_b2h[br][dbase + j]);
      }
#pragma unroll
      for (int kk = 0; kk < 3; kk++) {
#pragma unroll
        for (int f = 0; f < 6; f++) {
          int fg = chunk * 6 + f;
          short8n aw = *reinterpret_cast<const short8n*>(
              (const void*)(W2b + (((size_t)kk * 24 + fg) * 64 + lane) * 8));
          aX[f] = __builtin_amdgcn_mfma_f32_16x16x32_bf16(aw, bh[kk], aX[f], 0, 0, 0);
        }
      }
#pragma unroll
      for (int f = 0; f < 6; f++) {
        int dbase = (chunk * 6 + f) * 16 + kc * 4;
        short4n q;
#pragma unroll
        for (int j = 0; j < 4; j++) {
          float v = br ? fast_tanh(aX[f][j]) : fast_sigmoid(aX[f][j]);
          ((short*)&q)[j] = hfx(v);
        }
        *reinterpret_cast<short4n*>(&stash[wl * APAD + dbase]) = q;
      }
    }
  }
  __syncthreads();

  // final pass: coalesced modulate of reT/imT in place (4x unroll-and-jam)
  for (int u0 = 0; u0 < 12; u0 += 4) {
    float4 rv[4], iv[4];
#pragma unroll
    for (int u = 0; u < 4; u++) {
      int i = tid + (u0 + u) * 256;
      int d = i >> 3, lc = i & 7;
      size_t off = (size_t)d * NL + l0 + lc * 4;
      rv[u] = *reinterpret_cast<const float4*>(&reT[rb + off]);
      iv[u] = *reinterpret_cast<const float4*>(&imT[ib + off]);
    }
#pragma unroll
    for (int u = 0; u < 4; u++) {
      int i = tid + (u0 + u) * 256;
      int d = i >> 3, lc = i & 7;
      size_t off = (size_t)d * NL + l0 + lc * 4;
      float rr[4] = {rv[u].x, rv[u].y, rv[u].z, rv[u].w};
      float ii[4] = {iv[u].x, iv[u].y, iv[u].z, iv[u].w};
      float4 ro, io;
#pragma unroll
      for (int j = 0; j < 4; j++) {
        int row = lc * 4 + j;
        float ma = xhf(Am[row * APAD + d]);
        float pa = xhf(Ap[row * APAD + d]);
        float wm = s_wm[row];
        float mag = sqrtf(rr[j] * rr[j] + ii[j] * ii[j]);
        float ph = fast_atan2f(ii[j], rr[j]);
        float mago = mag * wm * ma;
        float pho = ph * wm + pa;
        float cs = __cosf(pho), sn = __sinf(pho);
        ((float*)&ro)[j] = mago * cs;
        ((float*)&io)[j] = mago * sn;
      }
      *reinterpret_cast<float4*>(&reT[rb + off]) = ro;
      *reinterpret_cast<float4*>(&imT[ib + off]) = io;
    }
  }
}

// ---------------------------------------------------------------- launch
extern "C" void kernel_launch(void* const* d_in, const int* in_sizes, int n_in,
                              void* d_out, int out_size, void* d_ws, size_t ws_size,
                              hipStream_t stream) {
  (void)in_sizes; (void)n_in; (void)out_size; (void)ws_size;
  const float* x     = (const float*)d_in[0];
  const float* mgW1  = (const float*)d_in[1];
  const float* mgb1  = (const float*)d_in[2];
  const float* mgg   = (const float*)d_in[3];
  const float* mgbe  = (const float*)d_in[4];
  const float* mgW2  = (const float*)d_in[5];
  const float* mgb2  = (const float*)d_in[6];
  const float* phW1  = (const float*)d_in[7];
  const float* phb1  = (const float*)d_in[8];
  const float* phg   = (const float*)d_in[9];
  const float* phbe  = (const float*)d_in[10];
  const float* phW2  = (const float*)d_in[11];
  const float* phb2  = (const float*)d_in[12];
  const float* bdW1  = (const float*)d_in[13];
  const float* bdb1  = (const float*)d_in[14];
  const float* bdg   = (const float*)d_in[15];
  const float* bdbe  = (const float*)d_in[16];
  const float* bdW2  = (const float*)d_in[17];
  const float* bdb2  = (const float*)d_in[18];
  const float* cgW1  = (const float*)d_in[19];
  const float* cgb1  = (const float*)d_in[20];
  const float* cgg   = (const float*)d_in[21];
  const float* cgbe  = (const float*)d_in[22];
  const float* cgW2  = (const float*)d_in[23];
  const float* cgb2  = (const float*)d_in[24];
  const float* convW = (const float*)d_in[25];
  const float* convB = (const float*)d_in[26];

  float* outp = (float*)d_out;
  float* wsf  = (float*)d_ws;
  // ws region0 (151MB): gatedA (bf16) during gate->conv, then imT (fp32) for FFT onward
  float* imT = wsf;
  __hip_bfloat16* gatedA = (__hip_bfloat16*)wsf;
  char* p = (char*)(wsf + (size_t)NB * NG * NL * ND);
  __hip_bfloat16* Wt2 = (__hip_bfloat16*)p;           p += (size_t)384 * 384 * 3 * 2;
  float* twid = (float*)p;                            p += 1024 * 4;
  float* bwp  = (float*)p;                            p += 512 * 4;
  __hip_bfloat16* W1A = (__hip_bfloat16*)p;           p += (size_t)2 * 36864 * 2;
  __hip_bfloat16* W2A = (__hip_bfloat16*)p;           p += (size_t)2 * 36864 * 2;
  __hip_bfloat16* W1G = (__hip_bfloat16*)p;           p += (size_t)147456 * 2;

  k_prep<<<dim3(2930), dim3(256), 0, stream>>>(convW, x, mgW1, phW1, mgW2, phW2, cgW1,
                                               Wt2, twid, W1A, W2A, W1G, outp);
  k_gate2<<<dim3(NB * 64), dim3(256), 0, stream>>>(x, W1G, cgb1, cgg, cgbe, cgW2, cgb2, gatedA);
  k_conv_mfma<<<dim3(NB * NG * 8 * 3), dim3(256), 0, stream>>>(gatedA, Wt2, convB, outp);
  k_fft_fwd<<<dim3(NB * 288), dim3(256), 0, stream>>>(twid, outp, imT);
  k_bd<<<dim3(NB * NG), dim3(96), 0, stream>>>(outp, bdW1, bdb1, bdg, bdbe, bdW2, bdb2, bwp);
  k_att4<<<dim3(NB * NG * 32), dim3(256), 0, stream>>>(outp, imT,
      W1A, W2A, mgb1, mgg, mgbe, mgb2, phb1, phg, phbe, phb2, bwp);
  k_fft_inv<<<dim3(NB * 288), dim3(256), 0, stream>>>(twid, outp, imT);
  k_tr<<<dim3(NB * NG * 16 * 6), dim3(256), 0, stream>>>(imT, outp);
}

// Round 8
// 929.137 us; speedup vs baseline: 4.3255x; 1.1127x over previous
//
#include <hip/hip_runtime.h>
#include <hip/hip_bf16.h>
#include <hip/hip_fp16.h>
#include <math.h>

#define NB 32
#define NL 1024
#define NG 3
#define ND 384
#define NH 96
#define NDG 192
#define SEQR 3073   // 1 + G*L

typedef __attribute__((ext_vector_type(8))) short short8n;
typedef __attribute__((ext_vector_type(4))) short short4n;
typedef __attribute__((ext_vector_type(4))) float f32x4;

__device__ __forceinline__ short bfx(float f) {
  __hip_bfloat16 h = __float2bfloat16(f);
  return *reinterpret_cast<short*>(&h);
}
__device__ __forceinline__ float xbf(short s) {
  __hip_bfloat16 h = *reinterpret_cast<__hip_bfloat16*>(&s);
  return __bfloat162float(h);
}
__device__ __forceinline__ short hfx(float f) {
  __half h = __float2half(f);
  return *reinterpret_cast<short*>(&h);
}
__device__ __forceinline__ float xhf(short s) {
  __half h = *reinterpret_cast<__half*>(&s);
  return __half2float(h);
}

// fast atan2, abs err <= ~1e-5 rad
__device__ __forceinline__ float fast_atan2f(float y, float x) {
  float ax = fabsf(x), ay = fabsf(y);
  float mx = fmaxf(ax, ay), mn = fminf(ax, ay);
  float r = (mx == 0.0f) ? 0.0f : __fdividef(mn, mx);
  float s = r * r;
  float p = fmaf(s, 0.0208351f, -0.0851330f);
  p = fmaf(s, p, 0.1801410f);
  p = fmaf(s, p, -0.3302995f);
  p = fmaf(s, p, 0.9998660f);
  p = r * p;
  float a = (ay > ax) ? (1.5707963267948966f - p) : p;
  a = (x < 0.0f) ? (3.14159265358979323846f - a) : a;
  return (y < 0.0f) ? -a : a;
}

__device__ __forceinline__ float fast_sigmoid(float x) {
  return __fdividef(1.0f, 1.0f + __expf(-x));
}
__device__ __forceinline__ float fast_tanh(float x) {
  return 1.0f - __fdividef(2.0f, 1.0f + __expf(2.0f * x));
}

// FFT LDS swizzles: break power-of-2 stride bank patterns
__device__ __forceinline__ int swzd(int p) { return p + (p >> 5); }  // data (max 1054)
__device__ __forceinline__ int swzt(int t) { return t + (t >> 4); }  // twiddle (max 542)

// ---------------------------------------------------------------- prep
__global__ __launch_bounds__(256) void k_prep(const float* __restrict__ convW,
                                              const float* __restrict__ x,
                                              const float* __restrict__ mgW1s,
                                              const float* __restrict__ phW1s,
                                              const float* __restrict__ mgW2s,
                                              const float* __restrict__ phW2s,
                                              const float* __restrict__ cgW1s,
                                              __hip_bfloat16* __restrict__ Wt2,
                                              float* __restrict__ twid,
                                              __hip_bfloat16* __restrict__ W1Ao,
                                              __hip_bfloat16* __restrict__ W2Ao,
                                              __hip_bfloat16* __restrict__ W1Go,
                                              float* __restrict__ outp) {
  int id = blockIdx.x * 256 + threadIdx.x;
  if (id < 384 * 384 * 3) {
    int i = id % 384; int rest = id / 384; int o = rest % 384; int kh = rest / 384;
    Wt2[id] = __float2bfloat16(convW[(o * 384 + i) * 3 + kh]);
    return;
  }
  int id2 = id - 384 * 384 * 3;
  if (id2 < 512) {
    float ang = -6.283185307179586f * (float)id2 / 1024.0f;
    float s, c; sincosf(ang, &s, &c);
    twid[2 * id2] = c; twid[2 * id2 + 1] = s;
    return;
  }
  int id3 = id2 - 512;
  if (id3 < NB * ND) {
    int b = id3 / ND, d = id3 % ND;
    outp[(size_t)b * SEQR * ND + d] = x[(size_t)b * SEQR * ND + d];
    return;
  }
  int id4 = id3 - NB * ND;
  if (id4 < 2 * 36864) {   // W1A: [br][kk(12)][f(6)][lane(64)][8]
    int br = id4 / 36864, idx = id4 % 36864;
    int j = idx & 7, ln = (idx >> 3) & 63, rest = idx >> 9;
    int f = rest % 6, kk = rest / 6;
    int m = f * 16 + (ln & 15), k = kk * 32 + (ln >> 4) * 8 + j;
    const float* W = br ? phW1s : mgW1s;
    W1Ao[id4] = __float2bfloat16(W[k * NH + m]);
    return;
  }
  int id5 = id4 - 2 * 36864;
  if (id5 < 2 * 36864) {   // W2A: [br][kk(3)][f(24)][lane(64)][8]
    int br = id5 / 36864, idx = id5 % 36864;
    int j = idx & 7, ln = (idx >> 3) & 63, rest = idx >> 9;
    int f = rest % 24, kk = rest / 24;
    int d = f * 16 + (ln & 15), k = kk * 32 + (ln >> 4) * 8 + j;
    const float* W = br ? phW2s : mgW2s;
    W2Ao[id5] = __float2bfloat16(W[k * ND + d]);
    return;
  }
  int id6 = id5 - 2 * 36864;
  if (id6 < 147456) {      // W1G: [part(2)][kk(12)][f(12)][lane(64)][8]
    int j = id6 & 7, ln = (id6 >> 3) & 63, rest = id6 >> 9;
    int f = rest % 12, rest2 = rest / 12;
    int kk = rest2 % 12, part = rest2 / 12;
    int m = f * 16 + (ln & 15), k = part * 384 + kk * 32 + (ln >> 4) * 8 + j;
    W1Go[id6] = __float2bfloat16(cgW1s[k * NDG + m]);
  }
}

// ---------------------------------------------------------------- gate MLP via MFMA
__global__ __launch_bounds__(256) void k_gate2(const float* __restrict__ x,
    const __hip_bfloat16* __restrict__ W1G,
    const float* __restrict__ b1, const float* __restrict__ gam,
    const float* __restrict__ bet, const float* __restrict__ W2,
    const float* __restrict__ b2p,
    __hip_bfloat16* __restrict__ gatedA) {
  int bid = blockIdx.x;
  int b = bid >> 6; int l0 = (bid & 63) * 16;
  int tid = threadIdx.x;
  int lane = tid & 63, wid = tid >> 6;
  int r15 = lane & 15, kc = lane >> 4;

  __shared__ short xs[3][16][392];
  __shared__ short gs[16][392];
  __shared__ float hG[16][196];
  __shared__ float s_b1[NDG], s_g[NDG], s_be[NDG], s_w2[NDG];
  __shared__ float sgate[3][16];

  if (tid < NDG) {
    s_b1[tid] = b1[tid]; s_g[tid] = gam[tid];
    s_be[tid] = bet[tid]; s_w2[tid] = W2[tid];
  }
  for (int c = tid; c < 16 * 96; c += 256) {
    int l = c / 96, d4 = (c % 96) * 4;
    size_t base = ((size_t)b * SEQR + 1 + l0 + l) * ND + d4;
    float4 v0 = *reinterpret_cast<const float4*>(&x[base]);
    float4 v1 = *reinterpret_cast<const float4*>(&x[base + (size_t)NL * ND]);
    float4 v2 = *reinterpret_cast<const float4*>(&x[base + (size_t)2 * NL * ND]);
    short4n q0, q1, q2, qg;
    q0.x = bfx(v0.x); q0.y = bfx(v0.y); q0.z = bfx(v0.z); q0.w = bfx(v0.w);
    q1.x = bfx(v1.x); q1.y = bfx(v1.y); q1.z = bfx(v1.z); q1.w = bfx(v1.w);
    q2.x = bfx(v2.x); q2.y = bfx(v2.y); q2.z = bfx(v2.z); q2.w = bfx(v2.w);
    qg.x = bfx((v0.x + v1.x + v2.x) * (1.0f / 3.0f));
    qg.y = bfx((v0.y + v1.y + v2.y) * (1.0f / 3.0f));
    qg.z = bfx((v0.z + v1.z + v2.z) * (1.0f / 3.0f));
    qg.w = bfx((v0.w + v1.w + v2.w) * (1.0f / 3.0f));
    *reinterpret_cast<short4n*>(&xs[0][l][d4]) = q0;
    *reinterpret_cast<short4n*>(&xs[1][l][d4]) = q1;
    *reinterpret_cast<short4n*>(&xs[2][l][d4]) = q2;
    *reinterpret_cast<short4n*>(&gs[l][d4]) = qg;
  }
  __syncthreads();

  const short* bsrc = (wid == 3) ? &gs[0][0] : &xs[wid][0][0];
  const __hip_bfloat16* W1b = W1G + (size_t)(wid == 3 ? 1 : 0) * 73728;
  f32x4 hacc[12];
#pragma unroll
  for (int f = 0; f < 12; f++)
#pragma unroll
    for (int j = 0; j < 4; j++)
      hacc[f][j] = (wid == 3) ? 0.0f : s_b1[f * 16 + kc * 4 + j];
  for (int kk = 0; kk < 12; kk++) {
    short8n bx = *reinterpret_cast<const short8n*>(&bsrc[r15 * 392 + kk * 32 + kc * 8]);
#pragma unroll
    for (int f = 0; f < 12; f++) {
      short8n aw = *reinterpret_cast<const short8n*>(
          (const void*)(W1b + (((size_t)kk * 12 + f) * 64 + lane) * 8));
      hacc[f] = __builtin_amdgcn_mfma_f32_16x16x32_bf16(aw, bx, hacc[f], 0, 0, 0);
    }
  }
  if (wid == 3) {
#pragma unroll
    for (int f = 0; f < 12; f++)
#pragma unroll
      for (int j = 0; j < 4; j++)
        hG[r15][f * 16 + kc * 4 + j] = hacc[f][j];
  }
  __syncthreads();
  if (wid < 3) {
    float s = 0.f, sq = 0.f;
#pragma unroll
    for (int f = 0; f < 12; f++)
#pragma unroll
      for (int j = 0; j < 4; j++) {
        float v = hacc[f][j] + hG[r15][f * 16 + kc * 4 + j];
        hacc[f][j] = v; s += v; sq += v * v;
      }
    s += __shfl_xor(s, 16, 64); s += __shfl_xor(s, 32, 64);
    sq += __shfl_xor(sq, 16, 64); sq += __shfl_xor(sq, 32, 64);
    float mean = s * (1.0f / NDG);
    float var = sq * (1.0f / NDG) - mean * mean;
    float rstd = rsqrtf(var + 1e-5f);
    float dot = 0.f;
#pragma unroll
    for (int f = 0; f < 12; f++)
#pragma unroll
      for (int j = 0; j < 4; j++) {
        int m = f * 16 + kc * 4 + j;
        float hn = fmaxf((hacc[f][j] - mean) * rstd * s_g[m] + s_be[m], 0.0f);
        dot += hn * s_w2[m];
      }
    dot += __shfl_xor(dot, 16, 64); dot += __shfl_xor(dot, 32, 64);
    float gate = fast_sigmoid(dot + b2p[0]);
    if (lane < 16) sgate[wid][r15] = gate;
  }
  __syncthreads();
  if (wid < 3) {
    size_t obase = (((size_t)b * NG + wid) * NL + l0) * ND;
    for (int c = lane; c < 16 * 96; c += 64) {
      int l = c / 96, d4 = (c % 96) * 4;
      float gt = sgate[wid][l];
      short4n qx = *reinterpret_cast<const short4n*>(&xs[wid][l][d4]);
      short4n qg = *reinterpret_cast<const short4n*>(&gs[l][d4]);
      short4n qo;
#pragma unroll
      for (int j = 0; j < 4; j++) {
        float xv = xbf(((short*)&qx)[j]);
        float gv = xbf(((short*)&qg)[j]);
        ((short*)&qo)[j] = bfx(xv * gt + gv * (1.0f - gt));
      }
      *reinterpret_cast<short4n*>(&((short*)gatedA)[obase + (size_t)l * ND + d4]) = qo;
    }
  }
}

// ---------------------------------------------------------------- conv as bf16 MFMA GEMM
// output written TRANSPOSED: reT[b][(g*384+d)][l] at base outp + (b*SEQR+1)*ND
#define BKC 64
__global__ __launch_bounds__(256) void k_conv_mfma(
    const __hip_bfloat16* __restrict__ Abuf,
    const __hip_bfloat16* __restrict__ Wt2,
    const float* __restrict__ cb,
    float* __restrict__ outp) {
  int bid = blockIdx.x;
  int ct = bid % 3; int rest = bid / 3;
  int rt = rest % 8; int bg = rest / 8;
  int b = bg / NG, gg = bg % NG;
  int l0 = rt * 128;
  int n0 = ct * 128;
  int tid = threadIdx.x;
  int lane = tid & 63, wid = tid >> 6;
  int wr = wid >> 1, wc = wid & 1;
  int r15 = lane & 15, kc = lane >> 4;

  __shared__ short As[128 * BKC];
  __shared__ short Bs[128 * BKC];

  f32x4 acc[4][4];
#pragma unroll
  for (int m = 0; m < 4; m++)
#pragma unroll
    for (int n = 0; n < 4; n++) acc[m][n] = (f32x4){0.f, 0.f, 0.f, 0.f};

  for (int kh = 0; kh < 3; kh++) {
    int gs = gg + kh - 1;
    if (gs < 0 || gs >= NG) continue;
    const __hip_bfloat16* Ag = Abuf + (((size_t)b * NG + gs) * NL + l0) * ND;
    const __hip_bfloat16* Bg = Wt2 + ((size_t)kh * 384 + n0) * 384;
    for (int k0 = 0; k0 < 384; k0 += BKC) {
      __syncthreads();
#pragma unroll
      for (int p = 0; p < 4; p++) {
        int idx = p * 256 + tid;
        int row = idx >> 3, c = idx & 7;
        int csrc = c ^ (row & 7);
        __builtin_amdgcn_global_load_lds(
            (const __attribute__((address_space(1))) void*)(Ag + (size_t)row * ND + k0 + csrc * 8),
            (__attribute__((address_space(3))) void*)(&As[idx * 8]), 16, 0, 0);
      }
#pragma unroll
      for (int p = 0; p < 4; p++) {
        int idx = p * 256 + tid;
        int row = idx >> 3, c = idx & 7;
        int csrc = c ^ (row & 7);
        __builtin_amdgcn_global_load_lds(
            (const __attribute__((address_space(1))) void*)(Bg + (size_t)row * 384 + k0 + csrc * 8),
            (__attribute__((address_space(3))) void*)(&Bs[idx * 8]), 16, 0, 0);
      }
      __syncthreads();
#pragma unroll
      for (int ks = 0; ks < 2; ks++) {
        short8n af[4], bfr[4];
        int cdata = ks * 4 + kc;
#pragma unroll
        for (int m = 0; m < 4; m++) {
          int row = wr * 64 + m * 16 + r15;
          af[m] = *reinterpret_cast<const short8n*>(&As[row * 64 + (cdata ^ (row & 7)) * 8]);
          int col = wc * 64 + m * 16 + r15;
          bfr[m] = *reinterpret_cast<const short8n*>(&Bs[col * 64 + (cdata ^ (col & 7)) * 8]);
        }
#pragma unroll
        for (int m = 0; m < 4; m++)
#pragma unroll
          for (int n = 0; n < 4; n++)
            acc[m][n] = __builtin_amdgcn_mfma_f32_16x16x32_bf16(af[m], bfr[n], acc[m][n], 0, 0, 0);
      }
    }
  }
  // transposed epilogue: lane holds 4 consecutive l for fixed d -> float4 along l
  float cbv[4];
#pragma unroll
  for (int n = 0; n < 4; n++) cbv[n] = cb[n0 + wc * 64 + n * 16 + r15];
  size_t tbase = (size_t)(b * SEQR + 1) * ND;
#pragma unroll
  for (int n = 0; n < 4; n++) {
    int drow = gg * ND + n0 + wc * 64 + n * 16 + r15;
#pragma unroll
    for (int m = 0; m < 4; m++) {
      int lcol = l0 + wr * 64 + m * 16 + kc * 4;
      float4 v = {acc[m][n][0] + cbv[n], acc[m][n][1] + cbv[n],
                  acc[m][n][2] + cbv[n], acc[m][n][3] + cbv[n]};
      *reinterpret_cast<float4*>(&outp[tbase + (size_t)drow * NL + lcol]) = v;
    }
  }
}

// ---------------------------------------------------------------- FFT fwd: DIF, natural-in, bitrev-out
// interleaved complex LDS + swizzled addressing (bank-conflict-free), twiddles in LDS
__global__ __launch_bounds__(256) void k_fft_fwd(const float* __restrict__ twid,
                                                 float* __restrict__ outp,
                                                 float* __restrict__ imT) {
  int bid = blockIdx.x;
  int b = bid / 288;
  int rloc = (bid % 288) * 4;
  size_t rbase = (size_t)(b * SEQR + 1) * ND + (size_t)rloc * NL;
  size_t ibase = ((size_t)b * NG * ND + rloc) * NL;
  int tid = threadIdx.x;
  __shared__ float2 sc[4][1056];
  __shared__ float2 stw[544];
  for (int t = tid; t < 512; t += 256)
    stw[swzt(t)] = make_float2(twid[2 * t], twid[2 * t + 1]);
  for (int idx = tid; idx < 4096; idx += 256) {
    int line = idx >> 10, pos = idx & 1023;
    sc[line][swzd(pos)] = make_float2(outp[rbase + (size_t)line * NL + pos], 0.0f);
  }
  __syncthreads();
  for (int s = 9; s >= 0; s--) {
    int m = 1 << s;
    for (int bt = tid; bt < 2048; bt += 256) {
      int line = bt >> 9, j = bt & 511;
      int jj = j & (m - 1), grp = j >> s;
      int p0 = (grp << (s + 1)) + jj, p1 = p0 + m;
      float2 tw = stw[swzt(jj << (9 - s))];
      float2 A = sc[line][swzd(p0)];
      float2 B = sc[line][swzd(p1)];
      float dr = A.x - B.x, di = A.y - B.y;
      sc[line][swzd(p0)] = make_float2(A.x + B.x, A.y + B.y);
      sc[line][swzd(p1)] = make_float2(dr * tw.x - di * tw.y, dr * tw.y + di * tw.x);
    }
    __syncthreads();
  }
  for (int idx = tid; idx < 4096; idx += 256) {
    int line = idx >> 10, pos = idx & 1023;
    float2 v = sc[line][swzd(pos)];
    outp[rbase + (size_t)line * NL + pos] = v.x;
    imT[ibase + (size_t)line * NL + pos] = v.y;
  }
}

// ---------------------------------------------------------------- FFT inv: DIT, bitrev-in, natural-out
__global__ __launch_bounds__(256) void k_fft_inv(const float* __restrict__ twid,
                                                 const float* __restrict__ outp,
                                                 float* __restrict__ imT) {
  int bid = blockIdx.x;
  int b = bid / 288;
  int rloc = (bid % 288) * 4;
  size_t rbase = (size_t)(b * SEQR + 1) * ND + (size_t)rloc * NL;
  size_t ibase = ((size_t)b * NG * ND + rloc) * NL;
  int tid = threadIdx.x;
  __shared__ float2 sc[4][1056];
  __shared__ float2 stw[544];
  for (int t = tid; t < 512; t += 256)
    stw[swzt(t)] = make_float2(twid[2 * t], twid[2 * t + 1]);
  for (int idx = tid; idx < 4096; idx += 256) {
    int line = idx >> 10, pos = idx & 1023;
    sc[line][swzd(pos)] = make_float2(outp[rbase + (size_t)line * NL + pos],
                                      imT[ibase + (size_t)line * NL + pos]);
  }
  __syncthreads();
  for (int s = 0; s < 10; s++) {
    int m = 1 << s;
    for (int bt = tid; bt < 2048; bt += 256) {
      int line = bt >> 9, j = bt & 511;
      int jj = j & (m - 1), grp = j >> s;
      int p0 = (grp << (s + 1)) + jj, p1 = p0 + m;
      float2 tw = stw[swzt(jj << (9 - s))];
      float twr = tw.x, twi = -tw.y;      // conj for inverse
      float2 B = sc[line][swzd(p1)];
      float2 A = sc[line][swzd(p0)];
      float tr = B.x * twr - B.y * twi;
      float tq = B.x * twi + B.y * twr;
      sc[line][swzd(p1)] = make_float2(A.x - tr, A.y - tq);
      sc[line][swzd(p0)] = make_float2(A.x + tr, A.y + tq);
    }
    __syncthreads();
  }
  const float scf = 1.0f / 1024.0f;
  for (int idx = tid; idx < 4096; idx += 256) {
    int line = idx >> 10, pos = idx & 1023;
    imT[ibase + (size_t)line * NL + pos] = sc[line][swzd(pos)].x * scf;
  }
}

// ---------------------------------------------------------------- final transpose [d][l] -> [l][d]
__global__ __launch_bounds__(256) void k_tr(const float* __restrict__ src,
                                            float* __restrict__ dst) {
  int bid = blockIdx.x;
  int dt = bid % 6; int r1 = bid / 6;
  int lt = r1 % 16; int r2 = r1 / 16;
  int gg = r2 % NG; int b = r2 / NG;
  int tid = threadIdx.x;
  __shared__ float T[64][67];
  size_t sbase = ((size_t)b * NG * ND + gg * ND + dt * 64) * NL + lt * 64;
  for (int c = tid; c < 64 * 16; c += 256) {
    int r = c >> 4, cc = c & 15;
    float4 v = *reinterpret_cast<const float4*>(&src[sbase + (size_t)r * NL + cc * 4]);
    T[r][cc * 4 + 0] = v.x; T[r][cc * 4 + 1] = v.y;
    T[r][cc * 4 + 2] = v.z; T[r][cc * 4 + 3] = v.w;
  }
  __syncthreads();
  size_t dbase = ((size_t)b * SEQR + 1 + (size_t)gg * NL + lt * 64) * ND + dt * 64;
  for (int c = tid; c < 64 * 16; c += 256) {
    int r = c >> 4, cc = c & 15;
    float4 v = {T[cc * 4 + 0][r], T[cc * 4 + 1][r], T[cc * 4 + 2][r], T[cc * 4 + 3][r]};
    *reinterpret_cast<float4*>(&dst[dbase + (size_t)r * ND + cc * 4]) = v;
  }
}

// ---------------------------------------------------------------- band MLP (reads DC = storage pos 0)
__global__ __launch_bounds__(96) void k_bd(const float* __restrict__ outp,
    const float* __restrict__ W1, const float* __restrict__ b1,
    const float* __restrict__ gam, const float* __restrict__ bet,
    const float* __restrict__ W2, const float* __restrict__ b2,
    float* __restrict__ bwout) {
  int bid = blockIdx.x;
  int b = bid / NG, gg = bid % NG;
  int tid = threadIdx.x;
  __shared__ float xm[ND];
  __shared__ float hs[NH];
  __shared__ float o3[3];
  size_t dcbase = (size_t)(b * SEQR + 1) * ND + (size_t)(gg * ND) * NL;
  for (int i = tid; i < ND; i += NH) xm[i] = outp[dcbase + (size_t)i * NL] * (1.0f / NL);
  __syncthreads();
  float acc = b1[tid];
  for (int i = 0; i < ND; i++) acc += xm[i] * W1[i * NH + tid];
  hs[tid] = acc;
  __syncthreads();
  float s = 0, sq = 0;
  for (int i = 0; i < NH; i++) { float v = hs[i]; s += v; sq += v * v; }
  float m = s * (1.0f / NH), var = sq * (1.0f / NH) - m * m;
  float hn = fmaxf((acc - m) * rsqrtf(var + 1e-5f) * gam[tid] + bet[tid], 0.0f);
  __syncthreads();
  hs[tid] = hn;
  __syncthreads();
  if (tid < 3) {
    float o = b2[tid];
    for (int k = 0; k < NH; k++) o += hs[k] * W2[k * 3 + tid];
    o3[tid] = o;
  }
  __syncthreads();
  if (tid < 3) {
    float mx = fmaxf(o3[0], fmaxf(o3[1], o3[2]));
    float ssum = expf(o3[0] - mx) + expf(o3[1] - mx) + expf(o3[2] - mx);
    bwout[bid * 3 + tid] = expf(o3[tid] - mx) / ssum;
  }
}

// ---------------------------------------------------------------- mag/phase MLPs via MFMA + modulate
// AROW=32; waves 0-1 = mag, 2-3 = phase. LDS ~52.7KB -> 3 blocks/CU.
// GEMM1->GEMM2 hidden handoff is in-register via 4-lane-group shuffles (no ht LDS).
#define AROW 32
#define APAD 390
__global__ __launch_bounds__(256, 3) void k_att4(
    float* __restrict__ reT, float* __restrict__ imT,
    const __hip_bfloat16* __restrict__ W1A,
    const __hip_bfloat16* __restrict__ W2A,
    const float* __restrict__ mgb1, const float* __restrict__ mgg,
    const float* __restrict__ mgbe, const float* __restrict__ mgb2,
    const float* __restrict__ phb1, const float* __restrict__ phg,
    const float* __restrict__ phbe, const float* __restrict__ phb2,
    const float* __restrict__ bwp) {
  int bid = blockIdx.x;
  int bg = bid >> 5; int tile = bid & 31;
  int b = bg / NG, gg = bg % NG;
  int l0 = tile * AROW;                // storage-position base
  int tid = threadIdx.x;
  int lane = tid & 63, wid = tid >> 6;
  int r15 = lane & 15, kc = lane >> 4;
  int br = wid >> 1;                   // branch: 0=mag, 1=phase
  int wl = (wid & 1) * 16 + r15;       // this lane's column (pos in tile)

  __shared__ short Am[AROW * APAD];    // stage1: bf16 mag; stage3: fp16 ma
  __shared__ short Ap[AROW * APAD];    // stage1: bf16 phase; stage3: fp16 pa
  __shared__ short s_b1h[2][NH], s_gh[2][NH], s_beh[2][NH];
  __shared__ short s_b2h[2][ND];
  __shared__ float s_wm[AROW];

  size_t rb = (size_t)(b * SEQR + 1) * ND + (size_t)(gg * ND) * NL;
  size_t ib = ((size_t)b * NG * ND + gg * ND) * NL;

  if (tid < NH) {
    s_b1h[0][tid] = bfx(mgb1[tid]); s_b1h[1][tid] = bfx(phb1[tid]);
    s_gh[0][tid]  = bfx(mgg[tid]);  s_gh[1][tid]  = bfx(phg[tid]);
    s_beh[0][tid] = bfx(mgbe[tid]); s_beh[1][tid] = bfx(phbe[tid]);
  }
  for (int i = tid; i < ND; i += 256) { s_b2h[0][i] = bfx(mgb2[i]); s_b2h[1][i] = bfx(phb2[i]); }
  if (tid < AROW) {   // band weight per storage position (true bin = brev10(pos))
    int k = (int)(__brev((unsigned)(l0 + tid)) >> 22);
    int fr = (k <= 512) ? k : (1024 - k);
    int bwb = (b * NG + gg) * 3;
    s_wm[tid] = (fr <= 128) ? bwp[bwb] : ((fr <= 256) ? bwp[bwb + 1] : bwp[bwb + 2]);
  }

  // stage 1: coalesced [d][l] reads (4x unroll-and-jam), scatter bf16 into Am/Ap[pos][d]
  for (int u0 = 0; u0 < 12; u0 += 4) {
    float4 rv[4], iv[4];
#pragma unroll
    for (int u = 0; u < 4; u++) {
      int i = tid + (u0 + u) * 256;
      int d = i >> 3, lc = i & 7;
      size_t off = (size_t)d * NL + l0 + lc * 4;
      rv[u] = *reinterpret_cast<const float4*>(&reT[rb + off]);
      iv[u] = *reinterpret_cast<const float4*>(&imT[ib + off]);
    }
#pragma unroll
    for (int u = 0; u < 4; u++) {
      int i = tid + (u0 + u) * 256;
      int d = i >> 3, lc = i & 7;
      float rr[4] = {rv[u].x, rv[u].y, rv[u].z, rv[u].w};
      float ii[4] = {iv[u].x, iv[u].y, iv[u].z, iv[u].w};
#pragma unroll
      for (int j = 0; j < 4; j++) {
        int row = lc * 4 + j;
        Am[row * APAD + d] = bfx(sqrtf(rr[j] * rr[j] + ii[j] * ii[j]));
        Ap[row * APAD + d] = bfx(fast_atan2f(ii[j], rr[j]));
      }
    }
  }
  __syncthreads();

  // GEMM1 (this wave's branch) -> LN -> relu -> bf16 packs in registers
  unsigned pk[6][2];    // pk[f][p] = packed bf16 (h[f][2p], h[f][2p+1])
  {
    const short* Abuf = br ? Ap : Am;
    const __hip_bfloat16* W1b = W1A + (size_t)br * 36864;
    f32x4 hacc[6];
#pragma unroll
    for (int f = 0; f < 6; f++) {
#pragma unroll
      for (int j = 0; j < 4; j++) hacc[f][j] = xbf(s_b1h[br][f * 16 + kc * 4 + j]);
    }
    for (int kk = 0; kk < 12; kk++) {
      short8n bx = *reinterpret_cast<const short8n*>(&Abuf[wl * APAD + kk * 32 + kc * 8]);
#pragma unroll
      for (int f = 0; f < 6; f++) {
        short8n aw = *reinterpret_cast<const short8n*>(
            (const void*)(W1b + (((size_t)kk * 6 + f) * 64 + lane) * 8));
        hacc[f] = __builtin_amdgcn_mfma_f32_16x16x32_bf16(aw, bx, hacc[f], 0, 0, 0);
      }
    }
    float s = 0.f, sq = 0.f;
#pragma unroll
    for (int f = 0; f < 6; f++)
#pragma unroll
      for (int j = 0; j < 4; j++) { float v = hacc[f][j]; s += v; sq += v * v; }
    s += __shfl_xor(s, 16, 64); s += __shfl_xor(s, 32, 64);
    sq += __shfl_xor(sq, 16, 64); sq += __shfl_xor(sq, 32, 64);
    float mean = s * (1.0f / NH);
    float var = sq * (1.0f / NH) - mean * mean;
    float rstd = rsqrtf(var + 1e-5f);
#pragma unroll
    for (int f = 0; f < 6; f++) {
      float hn[4];
#pragma unroll
      for (int j = 0; j < 4; j++) {
        int m = f * 16 + kc * 4 + j;
        hn[j] = fmaxf((hacc[f][j] - mean) * rstd * xbf(s_gh[br][m]) + xbf(s_beh[br][m]), 0.0f);
      }
#pragma unroll
      for (int p = 0; p < 2; p++) {
        unsigned lo = (unsigned)(unsigned short)bfx(hn[2 * p]);
        unsigned hi = (unsigned)(unsigned short)bfx(hn[2 * p + 1]);
        pk[f][p] = lo | (hi << 16);
      }
    }
  }
  __syncthreads();   // all waves done reading Am/Ap before stash overwrites

  // in-register handoff: build GEMM2 B-frags bh[kk] via 4-lane-group shuffles.
  // element k=kk*32+kc*8+jj lives in lane kc_src=(2kc+(jj>=4))&3, f=2kk+(kc>>1), j=jj&3
  short8n bh[3];
  {
    int srcA = r15 + ((( 2 * kc )     & 3) << 4);
    int srcB = r15 + (((2 * kc + 1) & 3) << 4);
    int hiF = kc >> 1;
#pragma unroll
    for (int kk = 0; kk < 3; kk++) {
      int a0l = __shfl((int)pk[kk * 2][0], srcA, 64);
      int a0h = __shfl((int)pk[kk * 2 + 1][0], srcA, 64);
      int a1l = __shfl((int)pk[kk * 2][1], srcA, 64);
      int a1h = __shfl((int)pk[kk * 2 + 1][1], srcA, 64);
      int b0l = __shfl((int)pk[kk * 2][0], srcB, 64);
      int b0h = __shfl((int)pk[kk * 2 + 1][0], srcB, 64);
      int b1l = __shfl((int)pk[kk * 2][1], srcB, 64);
      int b1h = __shfl((int)pk[kk * 2 + 1][1], srcB, 64);
      int4 tv;
      tv.x = hiF ? a0h : a0l;
      tv.y = hiF ? a1h : a1l;
      tv.z = hiF ? b0h : b0l;
      tv.w = hiF ? b1h : b1l;
      bh[kk] = *reinterpret_cast<short8n*>(&tv);
    }
  }

  // GEMM2 (this wave's branch): 4 chunks over 384 d; stash fp16 act into Am/Ap
  {
    const __hip_bfloat16* W2b = W2A + (size_t)br * 36864;
    short* stash = br ? Ap : Am;
#pragma unroll
    for (int chunk = 0; chunk < 4; chunk++) {
      f32x4 aX[6];
#pragma unroll
      for (int f = 0; f < 6; f++) {
        int dbase = (chunk * 6 + f) * 16 + kc * 4;
#pragma unroll
        for (int j = 0; j < 4; j++) aX[f][j] = xbf(s_b2h[br][dbase + j]);
      }
#pragma unroll
      for (int kk = 0; kk < 3; kk++) {
#pragma unroll
        for (int f = 0; f < 6; f++) {
          int fg = chunk * 6 + f;
          short8n aw = *reinterpret_cast<const short8n*>(
              (const void*)(W2b + (((size_t)kk * 24 + fg) * 64 + lane) * 8));
          aX[f] = __builtin_amdgcn_mfma_f32_16x16x32_bf16(aw, bh[kk], aX[f], 0, 0, 0);
        }
      }
#pragma unroll
      for (int f = 0; f < 6; f++) {
        int dbase = (chunk * 6 + f) * 16 + kc * 4;
        short4n q;
#pragma unroll
        for (int j = 0; j < 4; j++) {
          float v = br ? fast_tanh(aX[f][j]) : fast_sigmoid(aX[f][j]);
          ((short*)&q)[j] = hfx(v);
        }
        *reinterpret_cast<short4n*>(&stash[wl * APAD + dbase]) = q;
      }
    }
  }
  __syncthreads();

  // final pass: coalesced modulate of reT/imT in place (4x unroll-and-jam)
  for (int u0 = 0; u0 < 12; u0 += 4) {
    float4 rv[4], iv[4];
#pragma unroll
    for (int u = 0; u < 4; u++) {
      int i = tid + (u0 + u) * 256;
      int d = i >> 3, lc = i & 7;
      size_t off = (size_t)d * NL + l0 + lc * 4;
      rv[u] = *reinterpret_cast<const float4*>(&reT[rb + off]);
      iv[u] = *reinterpret_cast<const float4*>(&imT[ib + off]);
    }
#pragma unroll
    for (int u = 0; u < 4; u++) {
      int i = tid + (u0 + u) * 256;
      int d = i >> 3, lc = i & 7;
      size_t off = (size_t)d * NL + l0 + lc * 4;
      float rr[4] = {rv[u].x, rv[u].y, rv[u].z, rv[u].w};
      float ii[4] = {iv[u].x, iv[u].y, iv[u].z, iv[u].w};
      float4 ro, io;
#pragma unroll
      for (int j = 0; j < 4; j++) {
        int row = lc * 4 + j;
        float ma = xhf(Am[row * APAD + d]);
        float pa = xhf(Ap[row * APAD + d]);
        float wm = s_wm[row];
        float mag = sqrtf(rr[j] * rr[j] + ii[j] * ii[j]);
        float ph = fast_atan2f(ii[j], rr[j]);
        float mago = mag * wm * ma;
        float pho = ph * wm + pa;
        float cs = __cosf(pho), sn = __sinf(pho);
        ((float*)&ro)[j] = mago * cs;
        ((float*)&io)[j] = mago * sn;
      }
      *reinterpret_cast<float4*>(&reT[rb + off]) = ro;
      *reinterpret_cast<float4*>(&imT[ib + off]) = io;
    }
  }
}

// ---------------------------------------------------------------- launch
extern "C" void kernel_launch(void* const* d_in, const int* in_sizes, int n_in,
                              void* d_out, int out_size, void* d_ws, size_t ws_size,
                              hipStream_t stream) {
  (void)in_sizes; (void)n_in; (void)out_size; (void)ws_size;
  const float* x     = (const float*)d_in[0];
  const float* mgW1  = (const float*)d_in[1];
  const float* mgb1  = (const float*)d_in[2];
  const float* mgg   = (const float*)d_in[3];
  const float* mgbe  = (const float*)d_in[4];
  const float* mgW2  = (const float*)d_in[5];
  const float* mgb2  = (const float*)d_in[6];
  const float* phW1  = (const float*)d_in[7];
  const float* phb1  = (const float*)d_in[8];
  const float* phg   = (const float*)d_in[9];
  const float* phbe  = (const float*)d_in[10];
  const float* phW2  = (const float*)d_in[11];
  const float* phb2  = (const float*)d_in[12];
  const float* bdW1  = (const float*)d_in[13];
  const float* bdb1  = (const float*)d_in[14];
  const float* bdg   = (const float*)d_in[15];
  const float* bdbe  = (const float*)d_in[16];
  const float* bdW2  = (const float*)d_in[17];
  const float* bdb2  = (const float*)d_in[18];
  const float* cgW1  = (const float*)d_in[19];
  const float* cgb1  = (const float*)d_in[20];
  const float* cgg   = (const float*)d_in[21];
  const float* cgbe  = (const float*)d_in[22];
  const float* cgW2  = (const float*)d_in[23];
  const float* cgb2  = (const float*)d_in[24];
  const float* convW = (const float*)d_in[25];
  const float* convB = (const float*)d_in[26];

  float* outp = (float*)d_out;
  float* wsf  = (float*)d_ws;
  // ws region0 (151MB): gatedA (bf16) during gate->conv, then imT (fp32) for FFT onward
  float* imT = wsf;
  __hip_bfloat16* gatedA = (__hip_bfloat16*)wsf;
  char* p = (char*)(wsf + (size_t)NB * NG * NL * ND);
  __hip_bfloat16* Wt2 = (__hip_bfloat16*)p;           p += (size_t)384 * 384 * 3 * 2;
  float* twid = (float*)p;                            p += 1024 * 4;
  float* bwp  = (float*)p;                            p += 512 * 4;
  __hip_bfloat16* W1A = (__hip_bfloat16*)p;           p += (size_t)2 * 36864 * 2;
  __hip_bfloat16* W2A = (__hip_bfloat16*)p;           p += (size_t)2 * 36864 * 2;
  __hip_bfloat16* W1G = (__hip_bfloat16*)p;           p += (size_t)147456 * 2;

  k_prep<<<dim3(2930), dim3(256), 0, stream>>>(convW, x, mgW1, phW1, mgW2, phW2, cgW1,
                                               Wt2, twid, W1A, W2A, W1G, outp);
  k_gate2<<<dim3(NB * 64), dim3(256), 0, stream>>>(x, W1G, cgb1, cgg, cgbe, cgW2, cgb2, gatedA);
  k_conv_mfma<<<dim3(NB * NG * 8 * 3), dim3(256), 0, stream>>>(gatedA, Wt2, convB, outp);
  k_fft_fwd<<<dim3(NB * 288), dim3(256), 0, stream>>>(twid, outp, imT);
  k_bd<<<dim3(NB * NG), dim3(96), 0, stream>>>(outp, bdW1, bdb1, bdg, bdbe, bdW2, bdb2, bwp);
  k_att4<<<dim3(NB * NG * 32), dim3(256), 0, stream>>>(outp, imT,
      W1A, W2A, mgb1, mgg, mgbe, mgb2, phb1, phg, phbe, phb2, bwp);
  k_fft_inv<<<dim3(NB * 288), dim3(256), 0, stream>>>(twid, outp, imT);
  k_tr<<<dim3(NB * NG * 16 * 6), dim3(256), 0, stream>>>(imT, outp);
}